// Round 1
// baseline (1828.046 us; speedup 1.0000x reference)
//
#include <hip/hip_runtime.h>

#define EPSF 1e-5f

static inline int cdiv(int a, int b) { return (a + b - 1) / b; }

// ---------------- column stats (sum, sumsq) ----------------
__global__ void col_stats_kernel(const float* __restrict__ X, float* __restrict__ sums,
                                 int N, int F, int rowsPer) {
  int c = threadIdx.x;
  if (c >= F) return;
  int r0 = blockIdx.x * rowsPer;
  int r1 = min(N, r0 + rowsPer);
  float s = 0.f, sq = 0.f;
  for (int r = r0; r < r1; ++r) {
    float v = X[(size_t)r * F + c];
    s += v; sq += v * v;
  }
  atomicAdd(&sums[c], s);
  atomicAdd(&sums[512 + c], sq);
}

// ---------------- BN apply (optionally relu) ----------------
__global__ void bn_apply_kernel(const float* __restrict__ X, float* __restrict__ Y,
                                const float* __restrict__ sums,
                                const float* __restrict__ g, const float* __restrict__ b,
                                int N, int F, int rowsPer, int relu) {
  int c = threadIdx.x;
  if (c >= F) return;
  float invN = 1.f / (float)N;
  float mu = sums[c] * invN;
  float var = sums[512 + c] * invN - mu * mu;
  float sc = g[c] * rsqrtf(var + EPSF);
  float bb = b[c] - mu * sc;
  int r0 = blockIdx.x * rowsPer, r1 = min(N, r0 + rowsPer);
  for (int r = r0; r < r1; ++r) {
    float v = X[(size_t)r * F + c] * sc + bb;
    if (relu) v = fmaxf(v, 0.f);
    Y[(size_t)r * F + c] = v;
  }
}

// ---------------- simple tiled fp32 GEMM: C(NxM) = A(NxK) @ W(KxM) ----------------
#define BM 64
#define BN 64
#define BK 16
__global__ __launch_bounds__(256) void gemm_kernel(const float* __restrict__ A,
                                                   const float* __restrict__ W,
                                                   float* __restrict__ C,
                                                   int N, int K, int M) {
  __shared__ float As[BK][BM + 1];
  __shared__ float Ws[BK][BN + 1];
  int tid = threadIdx.x;
  int brow = blockIdx.x * BM;
  int bcol = blockIdx.y * BN;
  int tr = tid >> 4;  // 0..15
  int tc = tid & 15;  // 0..15
  float acc[4][4] = {};
  for (int k0 = 0; k0 < K; k0 += BK) {
#pragma unroll
    for (int l = 0; l < 4; ++l) {
      int idx = tid + l * 256;   // 0..1023
      int m = idx >> 4;          // 0..63
      int k = idx & 15;
      int gr = brow + m, gk = k0 + k;
      As[k][m] = (gr < N && gk < K) ? A[(size_t)gr * K + gk] : 0.f;
    }
#pragma unroll
    for (int l = 0; l < 4; ++l) {
      int idx = tid + l * 256;
      int k = idx >> 6;          // 0..15
      int n = idx & 63;
      int gk = k0 + k, gc = bcol + n;
      Ws[k][n] = (gk < K && gc < M) ? W[(size_t)gk * M + gc] : 0.f;
    }
    __syncthreads();
#pragma unroll
    for (int k = 0; k < BK; ++k) {
      float a[4], w[4];
#pragma unroll
      for (int i = 0; i < 4; ++i) a[i] = As[k][tr * 4 + i];
#pragma unroll
      for (int j = 0; j < 4; ++j) w[j] = Ws[k][tc * 4 + j];
#pragma unroll
      for (int i = 0; i < 4; ++i)
#pragma unroll
        for (int j = 0; j < 4; ++j) acc[i][j] += a[i] * w[j];
    }
    __syncthreads();
  }
  for (int i = 0; i < 4; ++i) {
    int gr = brow + tr * 4 + i;
    if (gr >= N) continue;
    for (int j = 0; j < 4; ++j) {
      int gc = bcol + tc * 4 + j;
      if (gc < M) C[(size_t)gr * M + gc] = acc[i][j];
    }
  }
}

// ---------------- CSR build ----------------
__global__ void count_kernel(const int* __restrict__ dst, int* __restrict__ cnt, int E) {
  int e = blockIdx.x * blockDim.x + threadIdx.x;
  if (e < E) atomicAdd(&cnt[dst[e]], 1);
}

__global__ void scan_kernel(const int* __restrict__ cnt, int* __restrict__ row_ptr, int N) {
  __shared__ int lds[1024];
  __shared__ int carry;
  int tid = threadIdx.x;
  if (tid == 0) carry = 0;
  __syncthreads();
  for (int base = 0; base < N; base += 1024) {
    int i = base + tid;
    int v = (i < N) ? cnt[i] : 0;
    lds[tid] = v;
    __syncthreads();
    for (int o = 1; o < 1024; o <<= 1) {
      int t = (tid >= o) ? lds[tid - o] : 0;
      __syncthreads();
      lds[tid] += t;
      __syncthreads();
    }
    int incl = lds[tid];
    if (i < N) row_ptr[i] = carry + incl - v;   // exclusive
    __syncthreads();
    if (tid == 1023) carry += incl;             // chunk total
    __syncthreads();
  }
  if (tid == 0) row_ptr[N] = carry;
}

__global__ void copyint_kernel(const int* __restrict__ src, int* __restrict__ dst, int N) {
  int i = blockIdx.x * blockDim.x + threadIdx.x;
  if (i < N) dst[i] = src[i];
}

__global__ void scatter_kernel(const int* __restrict__ dst, int* __restrict__ fill,
                               int* __restrict__ elist, int E) {
  int e = blockIdx.x * blockDim.x + threadIdx.x;
  if (e < E) {
    int p = atomicAdd(&fill[dst[e]], 1);
    elist[p] = e;
  }
}

// ---------------- fused GATv2 edge pass, per-node CSR gather ----------------
// block = HEADS*128 threads, one block per dst node.
// out[n,c] = (sum_e exp(e_h) * xl[src_e,c]) / ((sum_e exp(e_h) + 1e-16) * max(deg,1)) + bias[c]
template <int HEADS>
__global__ __launch_bounds__(HEADS * 128) void gat_node_kernel(
    const float* __restrict__ xl, const float* __restrict__ xr,
    const float* __restrict__ edge_attr, const int* __restrict__ src_idx,
    const int* __restrict__ row_ptr, const int* __restrict__ elist,
    const float* __restrict__ We, const float* __restrict__ att,
    const float* __restrict__ bias, float* __restrict__ out, int Nn) {
  constexpr int D = HEADS * 128;
  __shared__ float sWe0[D], sWe1[D], sAtt[D];
  __shared__ float sRed[4];
  int n = blockIdx.x;
  int c = threadIdx.x;
  sWe0[c] = We[c];
  sWe1[c] = We[D + c];
  sAtt[c] = att[c];
  float xr_c = xr[(size_t)n * D + c];
  int head = c >> 7;
  int wave = c >> 6;
  int lane = c & 63;
  int start = row_ptr[n], end = row_ptr[n + 1];
  float acc = 0.f, sacc = 0.f;
  __syncthreads();
  for (int i = start; i < end; ++i) {
    int e = elist[i];
    int sv = src_idx[e];
    float ea0 = edge_attr[2 * (size_t)e];
    float ea1 = edge_attr[2 * (size_t)e + 1];
    float xl_c = xl[(size_t)sv * D + c];
    float z = xl_c + xr_c + ea0 * sWe0[c] + ea1 * sWe1[c];
    z = (z > 0.f) ? z : 0.2f * z;
    float part = z * sAtt[c];
#pragma unroll
    for (int o = 32; o > 0; o >>= 1) part += __shfl_xor(part, o);
    if (lane == 0) sRed[wave] = part;
    __syncthreads();
    float eh = sRed[2 * head] + sRed[2 * head + 1];
    float p = expf(eh);
    acc += p * xl_c;
    sacc += p;
    __syncthreads();
  }
  int deg = end - start;
  float denom = (sacc + 1e-16f) * (float)(deg > 0 ? deg : 1);
  out[(size_t)n * D + c] = acc / denom + bias[c];
}

// ---------------- layer-3 (ch=1): one wave per node ----------------
__global__ void gat3_kernel(const float* __restrict__ xl, const float* __restrict__ xr,
                            const float* __restrict__ edge_attr, const int* __restrict__ src_idx,
                            const int* __restrict__ row_ptr, const int* __restrict__ elist,
                            const float* __restrict__ We, const float* __restrict__ att,
                            const float* __restrict__ bias, float* __restrict__ out, int Nn) {
  int n = blockIdx.x * 4 + (threadIdx.x >> 6);
  int lane = threadIdx.x & 63;
  if (n >= Nn) return;
  float we0 = We[0], we1 = We[1], a = att[0];
  float xr_n = xr[n];
  int s0 = row_ptr[n], s1 = row_ptr[n + 1];
  float accp = 0.f, accs = 0.f;
  for (int i = s0 + lane; i < s1; i += 64) {
    int e = elist[i];
    int sv = src_idx[e];
    float xls = xl[sv];
    float z = xls + xr_n + edge_attr[2 * (size_t)e] * we0 + edge_attr[2 * (size_t)e + 1] * we1;
    z = (z > 0.f) ? z : 0.2f * z;
    float p = expf(z * a);
    accp += p * xls;
    accs += p;
  }
#pragma unroll
  for (int o = 32; o > 0; o >>= 1) {
    accp += __shfl_xor(accp, o);
    accs += __shfl_xor(accs, o);
  }
  int deg = s1 - s0;
  if (lane == 0) out[n] = accp / ((accs + 1e-16f) * (float)(deg > 0 ? deg : 1)) + bias[0];
}

// ---------------- row dot: out[n] = A[n,:K] . w ----------------
__global__ void rowdot_kernel(const float* __restrict__ A, const float* __restrict__ w,
                              float* __restrict__ out, int Nn, int K) {
  int n = blockIdx.x * 4 + (threadIdx.x >> 6);
  int lane = threadIdx.x & 63;
  if (n >= Nn) return;
  float p = 0.f;
  for (int k = lane; k < K; k += 64) p += A[(size_t)n * K + k] * w[k];
#pragma unroll
  for (int o = 32; o > 0; o >>= 1) p += __shfl_xor(p, o);
  if (lane == 0) out[n] = p;
}

extern "C" void kernel_launch(void* const* d_in, const int* in_sizes, int n_in,
                              void* d_out, int out_size, void* d_ws, size_t ws_size,
                              hipStream_t stream) {
  const float* x     = (const float*)d_in[0];
  const int*   ei    = (const int*)d_in[1];
  const float* ea    = (const float*)d_in[2];
  const float* bn0_g = (const float*)d_in[3];
  const float* bn0_b = (const float*)d_in[4];
  const float* Wl1   = (const float*)d_in[5];
  const float* Wr1   = (const float*)d_in[6];
  const float* We1   = (const float*)d_in[7];
  const float* att1  = (const float*)d_in[8];
  const float* b1    = (const float*)d_in[9];
  const float* bn1_g = (const float*)d_in[10];
  const float* bn1_b = (const float*)d_in[11];
  const float* Wl2   = (const float*)d_in[12];
  const float* Wr2   = (const float*)d_in[13];
  const float* We2   = (const float*)d_in[14];
  const float* att2  = (const float*)d_in[15];
  const float* b2    = (const float*)d_in[16];
  const float* bn2_g = (const float*)d_in[17];
  const float* bn2_b = (const float*)d_in[18];
  const float* Wl3   = (const float*)d_in[19];
  const float* Wr3   = (const float*)d_in[20];
  const float* We3   = (const float*)d_in[21];
  const float* att3  = (const float*)d_in[22];
  const float* b3    = (const float*)d_in[23];

  const int F = 301;
  const int N = in_sizes[0] / F;
  const int E = in_sizes[1] / 2;
  const int* srcv = ei;       // edge_index[0]
  const int* dstv = ei + E;   // edge_index[1]

  // workspace layout (floats)
  float* fws = (float*)d_ws;
  float* R0 = fws;                                 // N*301 : h0 -> out1 -> out2
  float* R1 = R0 + (size_t)N * F;                  // N*256 : xl1 -> h1 -> h2
  float* R2 = R1 + (size_t)N * 256;                // N*256 : xr1 -> xl2|xr2 -> xl3|xr3
  float* stats = R2 + (size_t)N * 256;             // 1024 floats (sum | sumsq)
  int* row_ptr = (int*)(stats + 1024);             // N+1
  int* fill    = row_ptr + (N + 1);                // N
  int* elist   = fill + N;                         // E

  // ---- CSR by dst (rebuilt each call; deterministic up to fp-assoc) ----
  hipMemsetAsync(fill, 0, (size_t)N * sizeof(int), stream);
  count_kernel<<<cdiv(E, 256), 256, 0, stream>>>(dstv, fill, E);
  scan_kernel<<<1, 1024, 0, stream>>>(fill, row_ptr, N);
  copyint_kernel<<<cdiv(N, 256), 256, 0, stream>>>(row_ptr, fill, N);
  scatter_kernel<<<cdiv(E, 256), 256, 0, stream>>>(dstv, fill, elist, E);

  int rows = cdiv(N, 256);

  // ---- BN0 ----
  hipMemsetAsync(stats, 0, 1024 * sizeof(float), stream);
  col_stats_kernel<<<256, 320, 0, stream>>>(x, stats, N, F, rows);
  bn_apply_kernel<<<256, 320, 0, stream>>>(x, R0, stats, bn0_g, bn0_b, N, F, rows, 0);

  // ---- layer 1: GEMMs + edge pass ----
  gemm_kernel<<<dim3(cdiv(N, 64), 4), 256, 0, stream>>>(R0, Wl1, R1, N, F, 256);
  gemm_kernel<<<dim3(cdiv(N, 64), 4), 256, 0, stream>>>(R0, Wr1, R2, N, F, 256);
  gat_node_kernel<2><<<N, 256, 0, stream>>>(R1, R2, ea, srcv, row_ptr, elist,
                                            We1, att1, b1, R0, N);
  // ---- BN1 + relu ----
  hipMemsetAsync(stats, 0, 1024 * sizeof(float), stream);
  col_stats_kernel<<<256, 256, 0, stream>>>(R0, stats, N, 256, rows);
  bn_apply_kernel<<<256, 256, 0, stream>>>(R0, R1, stats, bn1_g, bn1_b, N, 256, rows, 1);

  // ---- layer 2 ----
  gemm_kernel<<<dim3(cdiv(N, 64), 2), 256, 0, stream>>>(R1, Wl2, R2, N, 256, 128);
  gemm_kernel<<<dim3(cdiv(N, 64), 2), 256, 0, stream>>>(R1, Wr2, R2 + (size_t)N * 128, N, 256, 128);
  gat_node_kernel<1><<<N, 128, 0, stream>>>(R2, R2 + (size_t)N * 128, ea, srcv, row_ptr, elist,
                                            We2, att2, b2, R0, N);
  // ---- BN2 + relu ----
  hipMemsetAsync(stats, 0, 1024 * sizeof(float), stream);
  col_stats_kernel<<<256, 128, 0, stream>>>(R0, stats, N, 128, rows);
  bn_apply_kernel<<<256, 128, 0, stream>>>(R0, R1, stats, bn2_g, bn2_b, N, 128, rows, 1);

  // ---- layer 3 (ch=1) ----
  rowdot_kernel<<<cdiv(N, 4), 256, 0, stream>>>(R1, Wl3, R2, N, 128);
  rowdot_kernel<<<cdiv(N, 4), 256, 0, stream>>>(R1, Wr3, R2 + N, N, 128);
  gat3_kernel<<<cdiv(N, 4), 256, 0, stream>>>(R2, R2 + N, ea, srcv, row_ptr, elist,
                                              We3, att3, b3, (float*)d_out, N);
}

// Round 3
// 1456.365 us; speedup vs baseline: 1.2552x; 1.2552x over previous
//
#include <hip/hip_runtime.h>

#define EPSF 1e-5f

static inline int cdiv(int a, int b) { return (a + b - 1) / b; }

// ---------------- column stats (sum, sumsq) ----------------
__global__ void col_stats_kernel(const float* __restrict__ X, float* __restrict__ sums,
                                 int N, int F, int rowsPer) {
  int c = threadIdx.x;
  if (c >= F) return;
  int r0 = blockIdx.x * rowsPer;
  int r1 = min(N, r0 + rowsPer);
  float s = 0.f, sq = 0.f;
  for (int r = r0; r < r1; ++r) {
    float v = X[(size_t)r * F + c];
    s += v; sq += v * v;
  }
  atomicAdd(&sums[c], s);
  atomicAdd(&sums[512 + c], sq);
}

// ---------------- BN apply (optionally relu) ----------------
__global__ void bn_apply_kernel(const float* __restrict__ X, float* __restrict__ Y,
                                const float* __restrict__ sums,
                                const float* __restrict__ g, const float* __restrict__ b,
                                int N, int F, int rowsPer, int relu) {
  int c = threadIdx.x;
  if (c >= F) return;
  float invN = 1.f / (float)N;
  float mu = sums[c] * invN;
  float var = sums[512 + c] * invN - mu * mu;
  float sc = g[c] * rsqrtf(var + EPSF);
  float bb = b[c] - mu * sc;
  int r0 = blockIdx.x * rowsPer, r1 = min(N, r0 + rowsPer);
  for (int r = r0; r < r1; ++r) {
    float v = X[(size_t)r * F + c] * sc + bb;
    if (relu) v = fmaxf(v, 0.f);
    Y[(size_t)r * F + c] = v;
  }
}

// ---------------- simple tiled fp32 GEMM: C(NxM) = A(NxK) @ W(KxM) ----------------
#define BM 64
#define BN 64
#define BK 16
__global__ __launch_bounds__(256) void gemm_kernel(const float* __restrict__ A,
                                                   const float* __restrict__ W,
                                                   float* __restrict__ C,
                                                   int N, int K, int M) {
  __shared__ float As[BK][BM + 1];
  __shared__ float Ws[BK][BN + 1];
  int tid = threadIdx.x;
  int brow = blockIdx.x * BM;
  int bcol = blockIdx.y * BN;
  int tr = tid >> 4;  // 0..15
  int tc = tid & 15;  // 0..15
  float acc[4][4] = {};
  for (int k0 = 0; k0 < K; k0 += BK) {
#pragma unroll
    for (int l = 0; l < 4; ++l) {
      int idx = tid + l * 256;   // 0..1023
      int m = idx >> 4;          // 0..63
      int k = idx & 15;
      int gr = brow + m, gk = k0 + k;
      As[k][m] = (gr < N && gk < K) ? A[(size_t)gr * K + gk] : 0.f;
    }
#pragma unroll
    for (int l = 0; l < 4; ++l) {
      int idx = tid + l * 256;
      int k = idx >> 6;          // 0..15
      int n = idx & 63;
      int gk = k0 + k, gc = bcol + n;
      Ws[k][n] = (gk < K && gc < M) ? W[(size_t)gk * M + gc] : 0.f;
    }
    __syncthreads();
#pragma unroll
    for (int k = 0; k < BK; ++k) {
      float a[4], w[4];
#pragma unroll
      for (int i = 0; i < 4; ++i) a[i] = As[k][tr * 4 + i];
#pragma unroll
      for (int j = 0; j < 4; ++j) w[j] = Ws[k][tc * 4 + j];
#pragma unroll
      for (int i = 0; i < 4; ++i)
#pragma unroll
        for (int j = 0; j < 4; ++j) acc[i][j] += a[i] * w[j];
    }
    __syncthreads();
  }
  for (int i = 0; i < 4; ++i) {
    int gr = brow + tr * 4 + i;
    if (gr >= N) continue;
    for (int j = 0; j < 4; ++j) {
      int gc = bcol + tc * 4 + j;
      if (gc < M) C[(size_t)gr * M + gc] = acc[i][j];
    }
  }
}

// ---------------- CSR build ----------------
__global__ void count_kernel(const int* __restrict__ dst, int* __restrict__ cnt, int E) {
  int e = blockIdx.x * blockDim.x + threadIdx.x;
  if (e < E) atomicAdd(&cnt[dst[e]], 1);
}

__global__ void scan_kernel(const int* __restrict__ cnt, int* __restrict__ row_ptr, int N) {
  __shared__ int lds[1024];
  __shared__ int carry;
  int tid = threadIdx.x;
  if (tid == 0) carry = 0;
  __syncthreads();
  for (int base = 0; base < N; base += 1024) {
    int i = base + tid;
    int v = (i < N) ? cnt[i] : 0;
    lds[tid] = v;
    __syncthreads();
    for (int o = 1; o < 1024; o <<= 1) {
      int t = (tid >= o) ? lds[tid - o] : 0;
      __syncthreads();
      lds[tid] += t;
      __syncthreads();
    }
    int incl = lds[tid];
    if (i < N) row_ptr[i] = carry + incl - v;   // exclusive
    __syncthreads();
    if (tid == 1023) carry += incl;             // chunk total
    __syncthreads();
  }
  if (tid == 0) row_ptr[N] = carry;
}

__global__ void copyint_kernel(const int* __restrict__ src, int* __restrict__ dst, int N) {
  int i = blockIdx.x * blockDim.x + threadIdx.x;
  if (i < N) dst[i] = src[i];
}

__global__ void scatter_kernel(const int* __restrict__ dst, int* __restrict__ fill,
                               int* __restrict__ elist, int E) {
  int e = blockIdx.x * blockDim.x + threadIdx.x;
  if (e < E) {
    int p = atomicAdd(&fill[dst[e]], 1);
    elist[p] = e;
  }
}

// ---------------- GATv2 layer 1: H=2, D=256, one WAVE per node ----------------
// lane l owns channels [4l,4l+4); lanes 0..31 = head0, 32..63 = head1.
// No LDS, no __syncthreads: logit reduce is 5 shfl_xor within 32-lane groups.
__global__ __launch_bounds__(256) void gat1_kernel(
    const float* __restrict__ xl, const float* __restrict__ xr,
    const float* __restrict__ edge_attr, const int* __restrict__ src_idx,
    const int* __restrict__ row_ptr, const int* __restrict__ elist,
    const float* __restrict__ We, const float* __restrict__ att,
    const float* __restrict__ bias, float* __restrict__ out, int Nn) {
  int n = __builtin_amdgcn_readfirstlane(blockIdx.x * 4 + (threadIdx.x >> 6));
  if (n >= Nn) return;
  int lane = threadIdx.x & 63;
  int c4 = lane * 4;
  const float4 we0 = *(const float4*)(We + c4);        // We row 0
  const float4 we1 = *(const float4*)(We + 256 + c4);  // We row 1
  const float4 at4 = *(const float4*)(att + c4);
  const float4 xr4 = *(const float4*)(xr + (size_t)n * 256 + c4);
  int start = row_ptr[n], end = row_ptr[n + 1];
  float4 acc = {0.f, 0.f, 0.f, 0.f};
  float sacc = 0.f;

  int e, sv;
  float ea0, ea1;
  float4 xl4;
  if (start < end) {
    e = __builtin_amdgcn_readfirstlane(elist[start]);
    sv = __builtin_amdgcn_readfirstlane(src_idx[e]);
    ea0 = edge_attr[2 * (size_t)e];
    ea1 = edge_attr[2 * (size_t)e + 1];
    xl4 = *(const float4*)(xl + (size_t)sv * 256 + c4);
  }
  for (int i = start; i < end; ++i) {
    float4 xc = xl4;
    float e0 = ea0, e1 = ea1;
    if (i + 1 < end) {  // prefetch next edge before the reduce chain
      e = __builtin_amdgcn_readfirstlane(elist[i + 1]);
      sv = __builtin_amdgcn_readfirstlane(src_idx[e]);
      ea0 = edge_attr[2 * (size_t)e];
      ea1 = edge_attr[2 * (size_t)e + 1];
      xl4 = *(const float4*)(xl + (size_t)sv * 256 + c4);
    }
    float zx = xc.x + xr4.x + e0 * we0.x + e1 * we1.x;
    float zy = xc.y + xr4.y + e0 * we0.y + e1 * we1.y;
    float zz = xc.z + xr4.z + e0 * we0.z + e1 * we1.z;
    float zw = xc.w + xr4.w + e0 * we0.w + e1 * we1.w;
    zx = (zx > 0.f) ? zx : 0.2f * zx;
    zy = (zy > 0.f) ? zy : 0.2f * zy;
    zz = (zz > 0.f) ? zz : 0.2f * zz;
    zw = (zw > 0.f) ? zw : 0.2f * zw;
    float part = zx * at4.x + zy * at4.y + zz * at4.z + zw * at4.w;
#pragma unroll
    for (int o = 16; o > 0; o >>= 1) part += __shfl_xor(part, o, 32);
    float p = __expf(part);
    acc.x += p * xc.x;
    acc.y += p * xc.y;
    acc.z += p * xc.z;
    acc.w += p * xc.w;
    sacc += p;
  }
  int deg = end - start;
  float inv = 1.f / ((sacc + 1e-16f) * (float)(deg > 0 ? deg : 1));
  float4 o4;
  o4.x = acc.x * inv + bias[c4];
  o4.y = acc.y * inv + bias[c4 + 1];
  o4.z = acc.z * inv + bias[c4 + 2];
  o4.w = acc.w * inv + bias[c4 + 3];
  *(float4*)(out + (size_t)n * 256 + c4) = o4;
}

// ---------------- GATv2 layer 2: H=1, D=128, one WAVE per node ----------------
// lane l owns channels [2l,2l+2); logit reduce = 6 shfl_xor over full wave.
__global__ __launch_bounds__(256) void gat2_kernel(
    const float* __restrict__ xl, const float* __restrict__ xr,
    const float* __restrict__ edge_attr, const int* __restrict__ src_idx,
    const int* __restrict__ row_ptr, const int* __restrict__ elist,
    const float* __restrict__ We, const float* __restrict__ att,
    const float* __restrict__ bias, float* __restrict__ out, int Nn) {
  int n = __builtin_amdgcn_readfirstlane(blockIdx.x * 4 + (threadIdx.x >> 6));
  if (n >= Nn) return;
  int lane = threadIdx.x & 63;
  int c2 = lane * 2;
  const float2 we0 = *(const float2*)(We + c2);
  const float2 we1 = *(const float2*)(We + 128 + c2);
  const float2 at2 = *(const float2*)(att + c2);
  const float2 xr2 = *(const float2*)(xr + (size_t)n * 128 + c2);
  int start = row_ptr[n], end = row_ptr[n + 1];
  float2 acc = {0.f, 0.f};
  float sacc = 0.f;

  int e, sv;
  float ea0, ea1;
  float2 xl2;
  if (start < end) {
    e = __builtin_amdgcn_readfirstlane(elist[start]);
    sv = __builtin_amdgcn_readfirstlane(src_idx[e]);
    ea0 = edge_attr[2 * (size_t)e];
    ea1 = edge_attr[2 * (size_t)e + 1];
    xl2 = *(const float2*)(xl + (size_t)sv * 128 + c2);
  }
  for (int i = start; i < end; ++i) {
    float2 xc = xl2;
    float e0 = ea0, e1 = ea1;
    if (i + 1 < end) {
      e = __builtin_amdgcn_readfirstlane(elist[i + 1]);
      sv = __builtin_amdgcn_readfirstlane(src_idx[e]);
      ea0 = edge_attr[2 * (size_t)e];
      ea1 = edge_attr[2 * (size_t)e + 1];
      xl2 = *(const float2*)(xl + (size_t)sv * 128 + c2);
    }
    float zx = xc.x + xr2.x + e0 * we0.x + e1 * we1.x;
    float zy = xc.y + xr2.y + e0 * we0.y + e1 * we1.y;
    zx = (zx > 0.f) ? zx : 0.2f * zx;
    zy = (zy > 0.f) ? zy : 0.2f * zy;
    float part = zx * at2.x + zy * at2.y;
#pragma unroll
    for (int o = 32; o > 0; o >>= 1) part += __shfl_xor(part, o);
    float p = __expf(part);
    acc.x += p * xc.x;
    acc.y += p * xc.y;
    sacc += p;
  }
  int deg = end - start;
  float inv = 1.f / ((sacc + 1e-16f) * (float)(deg > 0 ? deg : 1));
  float2 o2;
  o2.x = acc.x * inv + bias[c2];
  o2.y = acc.y * inv + bias[c2 + 1];
  *(float2*)(out + (size_t)n * 128 + c2) = o2;
}

// ---------------- layer-3 (ch=1): one wave per node ----------------
__global__ void gat3_kernel(const float* __restrict__ xl, const float* __restrict__ xr,
                            const float* __restrict__ edge_attr, const int* __restrict__ src_idx,
                            const int* __restrict__ row_ptr, const int* __restrict__ elist,
                            const float* __restrict__ We, const float* __restrict__ att,
                            const float* __restrict__ bias, float* __restrict__ out, int Nn) {
  int n = blockIdx.x * 4 + (threadIdx.x >> 6);
  int lane = threadIdx.x & 63;
  if (n >= Nn) return;
  float we0 = We[0], we1 = We[1], a = att[0];
  float xr_n = xr[n];
  int s0 = row_ptr[n], s1 = row_ptr[n + 1];
  float accp = 0.f, accs = 0.f;
  for (int i = s0 + lane; i < s1; i += 64) {
    int e = elist[i];
    int sv = src_idx[e];
    float xls = xl[sv];
    float z = xls + xr_n + edge_attr[2 * (size_t)e] * we0 + edge_attr[2 * (size_t)e + 1] * we1;
    z = (z > 0.f) ? z : 0.2f * z;
    float p = __expf(z * a);
    accp += p * xls;
    accs += p;
  }
#pragma unroll
  for (int o = 32; o > 0; o >>= 1) {
    accp += __shfl_xor(accp, o);
    accs += __shfl_xor(accs, o);
  }
  int deg = s1 - s0;
  if (lane == 0) out[n] = accp / ((accs + 1e-16f) * (float)(deg > 0 ? deg : 1)) + bias[0];
}

// ---------------- row dot: out[n] = A[n,:K] . w ----------------
__global__ void rowdot_kernel(const float* __restrict__ A, const float* __restrict__ w,
                              float* __restrict__ out, int Nn, int K) {
  int n = blockIdx.x * 4 + (threadIdx.x >> 6);
  int lane = threadIdx.x & 63;
  if (n >= Nn) return;
  float p = 0.f;
  for (int k = lane; k < K; k += 64) p += A[(size_t)n * K + k] * w[k];
#pragma unroll
  for (int o = 32; o > 0; o >>= 1) p += __shfl_xor(p, o);
  if (lane == 0) out[n] = p;
}

extern "C" void kernel_launch(void* const* d_in, const int* in_sizes, int n_in,
                              void* d_out, int out_size, void* d_ws, size_t ws_size,
                              hipStream_t stream) {
  const float* x     = (const float*)d_in[0];
  const int*   ei    = (const int*)d_in[1];
  const float* ea    = (const float*)d_in[2];
  const float* bn0_g = (const float*)d_in[3];
  const float* bn0_b = (const float*)d_in[4];
  const float* Wl1   = (const float*)d_in[5];
  const float* Wr1   = (const float*)d_in[6];
  const float* We1   = (const float*)d_in[7];
  const float* att1  = (const float*)d_in[8];
  const float* b1    = (const float*)d_in[9];
  const float* bn1_g = (const float*)d_in[10];
  const float* bn1_b = (const float*)d_in[11];
  const float* Wl2   = (const float*)d_in[12];
  const float* Wr2   = (const float*)d_in[13];
  const float* We2   = (const float*)d_in[14];
  const float* att2  = (const float*)d_in[15];
  const float* b2    = (const float*)d_in[16];
  const float* bn2_g = (const float*)d_in[17];
  const float* bn2_b = (const float*)d_in[18];
  const float* Wl3   = (const float*)d_in[19];
  const float* Wr3   = (const float*)d_in[20];
  const float* We3   = (const float*)d_in[21];
  const float* att3  = (const float*)d_in[22];
  const float* b3    = (const float*)d_in[23];

  const int F = 301;
  const int N = in_sizes[0] / F;
  const int E = in_sizes[1] / 2;
  const int* srcv = ei;       // edge_index[0]
  const int* dstv = ei + E;   // edge_index[1]

  // workspace layout (floats)
  float* fws = (float*)d_ws;
  float* R0 = fws;                                 // N*301 : h0 -> out1 -> out2
  float* R1 = R0 + (size_t)N * F;                  // N*256 : xl1 -> h1 -> h2
  float* R2 = R1 + (size_t)N * 256;                // N*256 : xr1 -> xl2|xr2 -> xl3|xr3
  float* stats = R2 + (size_t)N * 256;             // 1024 floats (sum | sumsq)
  int* row_ptr = (int*)(stats + 1024);             // N+1
  int* fill    = row_ptr + (N + 1);                // N
  int* elist   = fill + N;                         // E

  // ---- CSR by dst ----
  hipMemsetAsync(fill, 0, (size_t)N * sizeof(int), stream);
  count_kernel<<<cdiv(E, 256), 256, 0, stream>>>(dstv, fill, E);
  scan_kernel<<<1, 1024, 0, stream>>>(fill, row_ptr, N);
  copyint_kernel<<<cdiv(N, 256), 256, 0, stream>>>(row_ptr, fill, N);
  scatter_kernel<<<cdiv(E, 256), 256, 0, stream>>>(dstv, fill, elist, E);

  int rows = cdiv(N, 256);

  // ---- BN0 ----
  hipMemsetAsync(stats, 0, 1024 * sizeof(float), stream);
  col_stats_kernel<<<256, 320, 0, stream>>>(x, stats, N, F, rows);
  bn_apply_kernel<<<256, 320, 0, stream>>>(x, R0, stats, bn0_g, bn0_b, N, F, rows, 0);

  // ---- layer 1: GEMMs + edge pass ----
  gemm_kernel<<<dim3(cdiv(N, 64), 4), 256, 0, stream>>>(R0, Wl1, R1, N, F, 256);
  gemm_kernel<<<dim3(cdiv(N, 64), 4), 256, 0, stream>>>(R0, Wr1, R2, N, F, 256);
  gat1_kernel<<<cdiv(N, 4), 256, 0, stream>>>(R1, R2, ea, srcv, row_ptr, elist,
                                              We1, att1, b1, R0, N);
  // ---- BN1 + relu ----
  hipMemsetAsync(stats, 0, 1024 * sizeof(float), stream);
  col_stats_kernel<<<256, 256, 0, stream>>>(R0, stats, N, 256, rows);
  bn_apply_kernel<<<256, 256, 0, stream>>>(R0, R1, stats, bn1_g, bn1_b, N, 256, rows, 1);

  // ---- layer 2 ----
  gemm_kernel<<<dim3(cdiv(N, 64), 2), 256, 0, stream>>>(R1, Wl2, R2, N, 256, 128);
  gemm_kernel<<<dim3(cdiv(N, 64), 2), 256, 0, stream>>>(R1, Wr2, R2 + (size_t)N * 128, N, 256, 128);
  gat2_kernel<<<cdiv(N, 4), 256, 0, stream>>>(R2, R2 + (size_t)N * 128, ea, srcv, row_ptr, elist,
                                              We2, att2, b2, R0, N);
  // ---- BN2 + relu ----
  hipMemsetAsync(stats, 0, 1024 * sizeof(float), stream);
  col_stats_kernel<<<256, 128, 0, stream>>>(R0, stats, N, 128, rows);
  bn_apply_kernel<<<256, 128, 0, stream>>>(R0, R1, stats, bn2_g, bn2_b, N, 128, rows, 1);

  // ---- layer 3 (ch=1) ----
  rowdot_kernel<<<cdiv(N, 4), 256, 0, stream>>>(R1, Wl3, R2, N, 128);
  rowdot_kernel<<<cdiv(N, 4), 256, 0, stream>>>(R1, Wr3, R2 + N, N, 128);
  gat3_kernel<<<cdiv(N, 4), 256, 0, stream>>>(R2, R2 + N, ea, srcv, row_ptr, elist,
                                              We3, att3, b3, (float*)d_out, N);
}

// Round 4
// 1097.020 us; speedup vs baseline: 1.6664x; 1.3276x over previous
//
#include <hip/hip_runtime.h>

#define EPSF 1e-5f

static inline int cdiv(int a, int b) { return (a + b - 1) / b; }

// ---------------- column stats (sum, sumsq); X stride == F ----------------
__global__ void col_stats_kernel(const float* __restrict__ X, float* __restrict__ sums,
                                 int N, int F, int rowsPer) {
  int c = threadIdx.x;
  if (c >= F) return;
  int r0 = blockIdx.x * rowsPer;
  int r1 = min(N, r0 + rowsPer);
  float s = 0.f, sq = 0.f;
  for (int r = r0; r < r1; ++r) {
    float v = X[(size_t)r * F + c];
    s += v; sq += v * v;
  }
  atomicAdd(&sums[c], s);
  atomicAdd(&sums[512 + c], sq);
}

// ---------------- BN apply, optional relu, optional zero-padded out width ----------------
__global__ void bn_apply_kernel(const float* __restrict__ X, float* __restrict__ Y,
                                const float* __restrict__ sums,
                                const float* __restrict__ g, const float* __restrict__ b,
                                int N, int F, int outW, int rowsPer, int relu) {
  int c = threadIdx.x;
  if (c >= outW) return;
  float sc = 0.f, bb = 0.f;
  if (c < F) {
    float invN = 1.f / (float)N;
    float mu = sums[c] * invN;
    float var = sums[512 + c] * invN - mu * mu;
    sc = g[c] * rsqrtf(var + EPSF);
    bb = b[c] - mu * sc;
  }
  int r0 = blockIdx.x * rowsPer, r1 = min(N, r0 + rowsPer);
  for (int r = r0; r < r1; ++r) {
    float v = (c < F) ? X[(size_t)r * F + c] * sc + bb : 0.f;
    if (relu) v = fmaxf(v, 0.f);
    Y[(size_t)r * outW + c] = v;
  }
}

// ---------------- pad+concat weights: out[Kpad][2M] = [Wa | Wb], zero rows K..Kpad ----------------
__global__ void pad_cat_kernel(const float* __restrict__ Wa, const float* __restrict__ Wb,
                               float* __restrict__ out, int K, int Kpad, int M) {
  int idx = blockIdx.x * blockDim.x + threadIdx.x;
  int tot = Kpad * 2 * M;
  if (idx >= tot) return;
  int k = idx / (2 * M);
  int c = idx - k * 2 * M;
  float v = 0.f;
  if (k < K) v = (c < M) ? Wa[(size_t)k * M + c] : Wb[(size_t)k * M + (c - M)];
  out[idx] = v;
}

// ---------------- fp32 GEMM 128x128x8, 8x8 per thread, conflict-free LDS ----------------
// A: N x K (row stride lda, K % 8 == 0, 16B-aligned rows), W: K x ldw, C: N x ldc.
__global__ __launch_bounds__(256) void gemm128(const float* __restrict__ A,
                                               const float* __restrict__ W,
                                               float* __restrict__ C,
                                               int N, int K, int lda, int ldw, int ldc) {
  __shared__ float As[8][128];   // [k][m]
  __shared__ float Ws[8][128];   // [k][n]
  int tid = threadIdx.x;
  int brow = blockIdx.x * 128;
  int bcol = blockIdx.y * 128;
  int ty = tid >> 4;             // 0..15
  int tx = tid & 15;             // 0..15
  // staging assignments
  int sa_row = tid >> 1;         // 0..127
  int sa_k = (tid & 1) * 4;      // 0 or 4
  int sw_k = tid >> 5;           // 0..7
  int sw_col = (tid & 31) * 4;   // 0..124
  const float* Ap = A + (size_t)(brow + sa_row) * lda + sa_k;
  const float* Wp = W + (size_t)sw_k * ldw + bcol + sw_col;
  bool aok = (brow + sa_row) < N;
  float4 av = aok ? *(const float4*)Ap : make_float4(0.f, 0.f, 0.f, 0.f);
  float4 wv = *(const float4*)Wp;
  float acc[8][8] = {};
  for (int k0 = 0; k0 < K; k0 += 8) {
    __syncthreads();
    As[sa_k + 0][sa_row] = av.x;
    As[sa_k + 1][sa_row] = av.y;
    As[sa_k + 2][sa_row] = av.z;
    As[sa_k + 3][sa_row] = av.w;
    *(float4*)&Ws[sw_k][sw_col] = wv;
    __syncthreads();
    if (k0 + 8 < K) {   // prefetch next k-slab; hidden under the 512-FMA body
      av = aok ? *(const float4*)(Ap + k0 + 8) : make_float4(0.f, 0.f, 0.f, 0.f);
      wv = *(const float4*)(Wp + (size_t)(k0 + 8) * ldw);
    }
#pragma unroll
    for (int k = 0; k < 8; ++k) {
      const float4 a0 = *(const float4*)&As[k][ty * 4];        // broadcast across 16 lanes
      const float4 a1 = *(const float4*)&As[k][64 + ty * 4];
      const float4 b0 = *(const float4*)&Ws[k][tx * 4];        // 2-way alias = free
      const float4 b1 = *(const float4*)&Ws[k][64 + tx * 4];
      float ar[8] = {a0.x, a0.y, a0.z, a0.w, a1.x, a1.y, a1.z, a1.w};
      float br[8] = {b0.x, b0.y, b0.z, b0.w, b1.x, b1.y, b1.z, b1.w};
#pragma unroll
      for (int i = 0; i < 8; ++i)
#pragma unroll
        for (int j = 0; j < 8; ++j) acc[i][j] = fmaf(ar[i], br[j], acc[i][j]);
    }
  }
#pragma unroll
  for (int i = 0; i < 8; ++i) {
    int r = (i < 4) ? (ty * 4 + i) : (60 + ty * 4 + i);
    int gr = brow + r;
    if (gr >= N) continue;
    float4 v0 = {acc[i][0], acc[i][1], acc[i][2], acc[i][3]};
    float4 v1 = {acc[i][4], acc[i][5], acc[i][6], acc[i][7]};
    *(float4*)&C[(size_t)gr * ldc + bcol + tx * 4] = v0;
    *(float4*)&C[(size_t)gr * ldc + bcol + 64 + tx * 4] = v1;
  }
}

// ---------------- CSR build ----------------
__global__ void count_kernel(const int* __restrict__ dst, int* __restrict__ cnt, int E) {
  int e = blockIdx.x * blockDim.x + threadIdx.x;
  if (e < E) atomicAdd(&cnt[dst[e]], 1);
}

__global__ void scan_kernel(const int* __restrict__ cnt, int* __restrict__ row_ptr, int N) {
  __shared__ int lds[1024];
  __shared__ int carry;
  int tid = threadIdx.x;
  if (tid == 0) carry = 0;
  __syncthreads();
  for (int base = 0; base < N; base += 1024) {
    int i = base + tid;
    int v = (i < N) ? cnt[i] : 0;
    lds[tid] = v;
    __syncthreads();
    for (int o = 1; o < 1024; o <<= 1) {
      int t = (tid >= o) ? lds[tid - o] : 0;
      __syncthreads();
      lds[tid] += t;
      __syncthreads();
    }
    int incl = lds[tid];
    if (i < N) row_ptr[i] = carry + incl - v;   // exclusive
    __syncthreads();
    if (tid == 1023) carry += incl;             // chunk total
    __syncthreads();
  }
  if (tid == 0) row_ptr[N] = carry;
}

__global__ void copyint_kernel(const int* __restrict__ src, int* __restrict__ dst, int N) {
  int i = blockIdx.x * blockDim.x + threadIdx.x;
  if (i < N) dst[i] = src[i];
}

__global__ void scatter_kernel(const int* __restrict__ dst, int* __restrict__ fill,
                               int* __restrict__ elist, int E) {
  int e = blockIdx.x * blockDim.x + threadIdx.x;
  if (e < E) {
    int p = atomicAdd(&fill[dst[e]], 1);
    elist[p] = e;
  }
}

// ---------------- GATv2 layer 1: H=2, D=256, one WAVE per node ----------------
__global__ __launch_bounds__(256) void gat1_kernel(
    const float* __restrict__ xl, const float* __restrict__ xr, int ldx,
    const float* __restrict__ edge_attr, const int* __restrict__ src_idx,
    const int* __restrict__ row_ptr, const int* __restrict__ elist,
    const float* __restrict__ We, const float* __restrict__ att,
    const float* __restrict__ bias, float* __restrict__ out, int Nn) {
  int n = __builtin_amdgcn_readfirstlane(blockIdx.x * 4 + (threadIdx.x >> 6));
  if (n >= Nn) return;
  int lane = threadIdx.x & 63;
  int c4 = lane * 4;
  const float4 we0 = *(const float4*)(We + c4);
  const float4 we1 = *(const float4*)(We + 256 + c4);
  const float4 at4 = *(const float4*)(att + c4);
  const float4 xr4 = *(const float4*)(xr + (size_t)n * ldx + c4);
  int start = row_ptr[n], end = row_ptr[n + 1];
  float4 acc = {0.f, 0.f, 0.f, 0.f};
  float sacc = 0.f;

  int e, sv;
  float ea0, ea1;
  float4 xl4;
  if (start < end) {
    e = __builtin_amdgcn_readfirstlane(elist[start]);
    sv = __builtin_amdgcn_readfirstlane(src_idx[e]);
    ea0 = edge_attr[2 * (size_t)e];
    ea1 = edge_attr[2 * (size_t)e + 1];
    xl4 = *(const float4*)(xl + (size_t)sv * ldx + c4);
  }
  for (int i = start; i < end; ++i) {
    float4 xc = xl4;
    float e0 = ea0, e1 = ea1;
    if (i + 1 < end) {
      e = __builtin_amdgcn_readfirstlane(elist[i + 1]);
      sv = __builtin_amdgcn_readfirstlane(src_idx[e]);
      ea0 = edge_attr[2 * (size_t)e];
      ea1 = edge_attr[2 * (size_t)e + 1];
      xl4 = *(const float4*)(xl + (size_t)sv * ldx + c4);
    }
    float zx = xc.x + xr4.x + e0 * we0.x + e1 * we1.x;
    float zy = xc.y + xr4.y + e0 * we0.y + e1 * we1.y;
    float zz = xc.z + xr4.z + e0 * we0.z + e1 * we1.z;
    float zw = xc.w + xr4.w + e0 * we0.w + e1 * we1.w;
    zx = (zx > 0.f) ? zx : 0.2f * zx;
    zy = (zy > 0.f) ? zy : 0.2f * zy;
    zz = (zz > 0.f) ? zz : 0.2f * zz;
    zw = (zw > 0.f) ? zw : 0.2f * zw;
    float part = zx * at4.x + zy * at4.y + zz * at4.z + zw * at4.w;
#pragma unroll
    for (int o = 16; o > 0; o >>= 1) part += __shfl_xor(part, o, 32);
    float p = __expf(part);
    acc.x += p * xc.x;
    acc.y += p * xc.y;
    acc.z += p * xc.z;
    acc.w += p * xc.w;
    sacc += p;
  }
  int deg = end - start;
  float inv = 1.f / ((sacc + 1e-16f) * (float)(deg > 0 ? deg : 1));
  float4 o4;
  o4.x = acc.x * inv + bias[c4];
  o4.y = acc.y * inv + bias[c4 + 1];
  o4.z = acc.z * inv + bias[c4 + 2];
  o4.w = acc.w * inv + bias[c4 + 3];
  *(float4*)(out + (size_t)n * 256 + c4) = o4;
}

// ---------------- GATv2 layer 2: H=1, D=128, one WAVE per node ----------------
__global__ __launch_bounds__(256) void gat2_kernel(
    const float* __restrict__ xl, const float* __restrict__ xr, int ldx,
    const float* __restrict__ edge_attr, const int* __restrict__ src_idx,
    const int* __restrict__ row_ptr, const int* __restrict__ elist,
    const float* __restrict__ We, const float* __restrict__ att,
    const float* __restrict__ bias, float* __restrict__ out, int Nn) {
  int n = __builtin_amdgcn_readfirstlane(blockIdx.x * 4 + (threadIdx.x >> 6));
  if (n >= Nn) return;
  int lane = threadIdx.x & 63;
  int c2 = lane * 2;
  const float2 we0 = *(const float2*)(We + c2);
  const float2 we1 = *(const float2*)(We + 128 + c2);
  const float2 at2 = *(const float2*)(att + c2);
  const float2 xr2 = *(const float2*)(xr + (size_t)n * ldx + c2);
  int start = row_ptr[n], end = row_ptr[n + 1];
  float2 acc = {0.f, 0.f};
  float sacc = 0.f;

  int e, sv;
  float ea0, ea1;
  float2 xl2;
  if (start < end) {
    e = __builtin_amdgcn_readfirstlane(elist[start]);
    sv = __builtin_amdgcn_readfirstlane(src_idx[e]);
    ea0 = edge_attr[2 * (size_t)e];
    ea1 = edge_attr[2 * (size_t)e + 1];
    xl2 = *(const float2*)(xl + (size_t)sv * ldx + c2);
  }
  for (int i = start; i < end; ++i) {
    float2 xc = xl2;
    float e0 = ea0, e1 = ea1;
    if (i + 1 < end) {
      e = __builtin_amdgcn_readfirstlane(elist[i + 1]);
      sv = __builtin_amdgcn_readfirstlane(src_idx[e]);
      ea0 = edge_attr[2 * (size_t)e];
      ea1 = edge_attr[2 * (size_t)e + 1];
      xl2 = *(const float2*)(xl + (size_t)sv * ldx + c2);
    }
    float zx = xc.x + xr2.x + e0 * we0.x + e1 * we1.x;
    float zy = xc.y + xr2.y + e0 * we0.y + e1 * we1.y;
    zx = (zx > 0.f) ? zx : 0.2f * zx;
    zy = (zy > 0.f) ? zy : 0.2f * zy;
    float part = zx * at2.x + zy * at2.y;
#pragma unroll
    for (int o = 32; o > 0; o >>= 1) part += __shfl_xor(part, o);
    float p = __expf(part);
    acc.x += p * xc.x;
    acc.y += p * xc.y;
    sacc += p;
  }
  int deg = end - start;
  float inv = 1.f / ((sacc + 1e-16f) * (float)(deg > 0 ? deg : 1));
  float2 o2;
  o2.x = acc.x * inv + bias[c2];
  o2.y = acc.y * inv + bias[c2 + 1];
  *(float2*)(out + (size_t)n * 128 + c2) = o2;
}

// ---------------- layer-3 (ch=1): one wave per node ----------------
__global__ void gat3_kernel(const float* __restrict__ xl, const float* __restrict__ xr,
                            const float* __restrict__ edge_attr, const int* __restrict__ src_idx,
                            const int* __restrict__ row_ptr, const int* __restrict__ elist,
                            const float* __restrict__ We, const float* __restrict__ att,
                            const float* __restrict__ bias, float* __restrict__ out, int Nn) {
  int n = blockIdx.x * 4 + (threadIdx.x >> 6);
  int lane = threadIdx.x & 63;
  if (n >= Nn) return;
  float we0 = We[0], we1 = We[1], a = att[0];
  float xr_n = xr[n];
  int s0 = row_ptr[n], s1 = row_ptr[n + 1];
  float accp = 0.f, accs = 0.f;
  for (int i = s0 + lane; i < s1; i += 64) {
    int e = elist[i];
    int sv = src_idx[e];
    float xls = xl[sv];
    float z = xls + xr_n + edge_attr[2 * (size_t)e] * we0 + edge_attr[2 * (size_t)e + 1] * we1;
    z = (z > 0.f) ? z : 0.2f * z;
    float p = __expf(z * a);
    accp += p * xls;
    accs += p;
  }
#pragma unroll
  for (int o = 32; o > 0; o >>= 1) {
    accp += __shfl_xor(accp, o);
    accs += __shfl_xor(accs, o);
  }
  int deg = s1 - s0;
  if (lane == 0) out[n] = accp / ((accs + 1e-16f) * (float)(deg > 0 ? deg : 1)) + bias[0];
}

// ---------------- row dot: out[n] = A[n,:K] . w ----------------
__global__ void rowdot_kernel(const float* __restrict__ A, const float* __restrict__ w,
                              float* __restrict__ out, int Nn, int K) {
  int n = blockIdx.x * 4 + (threadIdx.x >> 6);
  int lane = threadIdx.x & 63;
  if (n >= Nn) return;
  float p = 0.f;
  for (int k = lane; k < K; k += 64) p += A[(size_t)n * K + k] * w[k];
#pragma unroll
  for (int o = 32; o > 0; o >>= 1) p += __shfl_xor(p, o);
  if (lane == 0) out[n] = p;
}

extern "C" void kernel_launch(void* const* d_in, const int* in_sizes, int n_in,
                              void* d_out, int out_size, void* d_ws, size_t ws_size,
                              hipStream_t stream) {
  const float* x     = (const float*)d_in[0];
  const int*   ei    = (const int*)d_in[1];
  const float* ea    = (const float*)d_in[2];
  const float* bn0_g = (const float*)d_in[3];
  const float* bn0_b = (const float*)d_in[4];
  const float* Wl1   = (const float*)d_in[5];
  const float* Wr1   = (const float*)d_in[6];
  const float* We1   = (const float*)d_in[7];
  const float* att1  = (const float*)d_in[8];
  const float* b1    = (const float*)d_in[9];
  const float* bn1_g = (const float*)d_in[10];
  const float* bn1_b = (const float*)d_in[11];
  const float* Wl2   = (const float*)d_in[12];
  const float* Wr2   = (const float*)d_in[13];
  const float* We2   = (const float*)d_in[14];
  const float* att2  = (const float*)d_in[15];
  const float* b2    = (const float*)d_in[16];
  const float* bn2_g = (const float*)d_in[17];
  const float* bn2_b = (const float*)d_in[18];
  const float* Wl3   = (const float*)d_in[19];
  const float* Wr3   = (const float*)d_in[20];
  const float* We3   = (const float*)d_in[21];
  const float* att3  = (const float*)d_in[22];
  const float* b3    = (const float*)d_in[23];

  const int F = 301;
  const int Fp = 304;              // padded K for layer 1 (16B-aligned rows, K%8==0)
  const int N = in_sizes[0] / F;
  const int E = in_sizes[1] / 2;
  const int* srcv = ei;
  const int* dstv = ei + E;

  // workspace layout (floats)
  float* fws = (float*)d_ws;
  float* P0 = fws;                              // 304N: Apad -> gat1out -> gat2out -> xl3|xr3
  float* P1 = P0 + (size_t)N * Fp;              // 512N: xlr1 -> h1 | xlr2 -> h2
  float* stats = P1 + (size_t)N * 512;          // 1024
  float* Wcat1 = stats + 1024;                  // 304*512
  float* Wcat2 = Wcat1 + (size_t)Fp * 512;      // 256*256
  int* row_ptr = (int*)(Wcat2 + 256 * 256);     // N+1
  int* fill    = row_ptr + (N + 1);             // N
  int* elist   = fill + N;                      // E

  float* xlr2 = P1 + (size_t)N * 256;           // second half of P1

  // ---- CSR by dst ----
  hipMemsetAsync(fill, 0, (size_t)N * sizeof(int), stream);
  count_kernel<<<cdiv(E, 256), 256, 0, stream>>>(dstv, fill, E);
  scan_kernel<<<1, 1024, 0, stream>>>(fill, row_ptr, N);
  copyint_kernel<<<cdiv(N, 256), 256, 0, stream>>>(row_ptr, fill, N);
  scatter_kernel<<<cdiv(E, 256), 256, 0, stream>>>(dstv, fill, elist, E);

  // ---- weight prep ----
  pad_cat_kernel<<<cdiv(Fp * 512, 256), 256, 0, stream>>>(Wl1, Wr1, Wcat1, F, Fp, 256);
  pad_cat_kernel<<<cdiv(256 * 256, 256), 256, 0, stream>>>(Wl2, Wr2, Wcat2, 256, 256, 128);

  int rows = cdiv(N, 256);

  // ---- BN0 -> Apad (N x 304, zero-padded) ----
  hipMemsetAsync(stats, 0, 1024 * sizeof(float), stream);
  col_stats_kernel<<<256, 320, 0, stream>>>(x, stats, N, F, rows);
  bn_apply_kernel<<<256, 320, 0, stream>>>(x, P0, stats, bn0_g, bn0_b, N, F, Fp, rows, 0);

  // ---- layer 1: fused [xl|xr] GEMM + edge pass ----
  gemm128<<<dim3(cdiv(N, 128), 4), 256, 0, stream>>>(P0, Wcat1, P1, N, Fp, Fp, 512, 512);
  gat1_kernel<<<cdiv(N, 4), 256, 0, stream>>>(P1, P1 + 256, 512, ea, srcv, row_ptr, elist,
                                              We1, att1, b1, P0, N);
  // ---- BN1 + relu -> h1 (P1 first half, stride 256) ----
  hipMemsetAsync(stats, 0, 1024 * sizeof(float), stream);
  col_stats_kernel<<<256, 256, 0, stream>>>(P0, stats, N, 256, rows);
  bn_apply_kernel<<<256, 256, 0, stream>>>(P0, P1, stats, bn1_g, bn1_b, N, 256, 256, rows, 1);

  // ---- layer 2: fused [xl|xr] GEMM + edge pass ----
  gemm128<<<dim3(cdiv(N, 128), 2), 256, 0, stream>>>(P1, Wcat2, xlr2, N, 256, 256, 256, 256);
  gat2_kernel<<<cdiv(N, 4), 256, 0, stream>>>(xlr2, xlr2 + 128, 256, ea, srcv, row_ptr, elist,
                                              We2, att2, b2, P0, N);
  // ---- BN2 + relu -> h2 (P1 first half, stride 128) ----
  hipMemsetAsync(stats, 0, 1024 * sizeof(float), stream);
  col_stats_kernel<<<256, 128, 0, stream>>>(P0, stats, N, 128, rows);
  bn_apply_kernel<<<256, 128, 0, stream>>>(P0, P1, stats, bn2_g, bn2_b, N, 128, 128, rows, 1);

  // ---- layer 3 (ch=1) ----
  rowdot_kernel<<<cdiv(N, 4), 256, 0, stream>>>(P1, Wl3, P0, N, 128);
  rowdot_kernel<<<cdiv(N, 4), 256, 0, stream>>>(P1, Wr3, P0 + N, N, 128);
  gat3_kernel<<<cdiv(N, 4), 256, 0, stream>>>(P0, P0 + N, ea, srcv, row_ptr, elist,
                                              We3, att3, b3, (float*)d_out, N);
}

// Round 5
// 876.487 us; speedup vs baseline: 2.0856x; 1.2516x over previous
//
#include <hip/hip_runtime.h>

#define EPSF 1e-5f

typedef unsigned short u16;
typedef __attribute__((ext_vector_type(8))) short bf16x8s;  // 8 bf16 (4 VGPRs)
typedef __attribute__((ext_vector_type(4))) float f32x4;

static inline int cdiv(int a, int b) { return (a + b - 1) / b; }

// split v into hi (bit-truncated bf16) + lo (round-nearest bf16 of remainder)
__device__ inline void bf_split(float v, u16& h, u16& l) {
  unsigned u = __float_as_uint(v);
  h = (u16)(u >> 16);
  float hf = __uint_as_float(u & 0xffff0000u);
  float r = v - hf;
  unsigned ur = __float_as_uint(r);
  ur += 0x7fffu + ((ur >> 16) & 1u);
  l = (u16)(ur >> 16);
}

// ---------------- column stats (sum, sumsq); X stride == F ----------------
__global__ void col_stats_kernel(const float* __restrict__ X, float* __restrict__ sums,
                                 int N, int F, int rowsPer) {
  int c = threadIdx.x;
  if (c >= F) return;
  int r0 = blockIdx.x * rowsPer;
  int r1 = min(N, r0 + rowsPer);
  float s = 0.f, sq = 0.f;
  for (int r = r0; r < r1; ++r) {
    float v = X[(size_t)r * F + c];
    s += v; sq += v * v;
  }
  atomicAdd(&sums[c], s);
  atomicAdd(&sums[512 + c], sq);
}

// ---------------- BN apply -> fp32 (used for BN2) ----------------
__global__ void bn_apply_kernel(const float* __restrict__ X, float* __restrict__ Y,
                                const float* __restrict__ sums,
                                const float* __restrict__ g, const float* __restrict__ b,
                                int N, int F, int outW, int rowsPer, int relu) {
  int c = threadIdx.x;
  if (c >= outW) return;
  float sc = 0.f, bb = 0.f;
  if (c < F) {
    float invN = 1.f / (float)N;
    float mu = sums[c] * invN;
    float var = sums[512 + c] * invN - mu * mu;
    sc = g[c] * rsqrtf(var + EPSF);
    bb = b[c] - mu * sc;
  }
  int r0 = blockIdx.x * rowsPer, r1 = min(N, r0 + rowsPer);
  for (int r = r0; r < r1; ++r) {
    float v = (c < F) ? X[(size_t)r * F + c] * sc + bb : 0.f;
    if (relu) v = fmaxf(v, 0.f);
    Y[(size_t)r * outW + c] = v;
  }
}

// ---------------- BN apply -> split bf16 hi/lo planes (BN0, BN1) ----------------
__global__ void bn_split_kernel(const float* __restrict__ X,
                                u16* __restrict__ Yhi, u16* __restrict__ Ylo,
                                const float* __restrict__ sums,
                                const float* __restrict__ g, const float* __restrict__ b,
                                int N, int F, int outW, int rowsPer, int relu) {
  int c = threadIdx.x;
  if (c >= outW) return;
  float sc = 0.f, bb = 0.f;
  if (c < F) {
    float invN = 1.f / (float)N;
    float mu = sums[c] * invN;
    float var = sums[512 + c] * invN - mu * mu;
    sc = g[c] * rsqrtf(var + EPSF);
    bb = b[c] - mu * sc;
  }
  int r0 = blockIdx.x * rowsPer, r1 = min(N, r0 + rowsPer);
  for (int r = r0; r < r1; ++r) {
    float v = (c < F) ? X[(size_t)r * F + c] * sc + bb : 0.f;
    if (relu) v = fmaxf(v, 0.f);
    u16 h, l;
    bf_split(v, h, l);
    Yhi[(size_t)r * outW + c] = h;
    Ylo[(size_t)r * outW + c] = l;
  }
}

// ---------------- weights: transpose + concat + pad + split -> [2M][Kp] bf16 hi/lo ----------------
__global__ void wt_split_kernel(const float* __restrict__ Wa, const float* __restrict__ Wb,
                                u16* __restrict__ Whi, u16* __restrict__ Wlo,
                                int K, int Kp, int M) {
  int idx = blockIdx.x * blockDim.x + threadIdx.x;
  if (idx >= 2 * M * Kp) return;
  int col = idx / Kp;
  int k = idx - col * Kp;
  float v = 0.f;
  if (k < K) v = (col < M) ? Wa[(size_t)k * M + col] : Wb[(size_t)k * M + (col - M)];
  u16 h, l;
  bf_split(v, h, l);
  Whi[idx] = h;
  Wlo[idx] = l;
}

// ---------------- split-bf16 MFMA GEMM: C(NxMout) = (Ahi+Alo)(Whi+Wlo)^T ----------------
// A planes: [N][Kp] bf16; W planes: [Mout][Kp] bf16 (pre-transposed). 128x128x32 tile,
// 4 waves 2x2, 4x4 16x16x32 frags/wave, 3 MFMA per frag (hi*hi + hi*lo + lo*hi).
__global__ __launch_bounds__(256) void gemm_mfma(
    const u16* __restrict__ Ahi, const u16* __restrict__ Alo,
    const u16* __restrict__ Bhi, const u16* __restrict__ Blo,
    float* __restrict__ C, int N, int Kp, int ldc) {
  __shared__ u16 sAh[128 * 40], sAl[128 * 40], sBh[128 * 40], sBl[128 * 40];
  int tid = threadIdx.x;
  int brow = blockIdx.x * 128, bcol = blockIdx.y * 128;
  // staging: thread t -> row t>>1, k-chunks {(t&1)*2, (t&1)*2+1} (8 bf16 each)
  int stR = tid >> 1;
  int stC0 = (tid & 1) * 2;
  bool aok = (brow + stR) < N;
  const u16* pAh = Ahi + (size_t)(brow + stR) * Kp + stC0 * 8;
  const u16* pAl = Alo + (size_t)(brow + stR) * Kp + stC0 * 8;
  const u16* pBh = Bhi + (size_t)(bcol + stR) * Kp + stC0 * 8;
  const u16* pBl = Blo + (size_t)(bcol + stR) * Kp + stC0 * 8;
  const uint4 Z = make_uint4(0u, 0u, 0u, 0u);
  uint4 rah0 = aok ? *(const uint4*)(pAh) : Z;
  uint4 rah1 = aok ? *(const uint4*)(pAh + 8) : Z;
  uint4 ral0 = aok ? *(const uint4*)(pAl) : Z;
  uint4 ral1 = aok ? *(const uint4*)(pAl + 8) : Z;
  uint4 rbh0 = *(const uint4*)(pBh);
  uint4 rbh1 = *(const uint4*)(pBh + 8);
  uint4 rbl0 = *(const uint4*)(pBl);
  uint4 rbl1 = *(const uint4*)(pBl + 8);
  f32x4 acc[4][4] = {};
  int lane = tid & 63;
  int wv = tid >> 6, wr = wv >> 1, wc = wv & 1;
  int fr = lane & 15, kch = (lane >> 4) * 8;
  int ldsw = stR * 40 + stC0 * 8;
  for (int k0 = 0;;) {
    __syncthreads();
    *(uint4*)&sAh[ldsw] = rah0; *(uint4*)&sAh[ldsw + 8] = rah1;
    *(uint4*)&sAl[ldsw] = ral0; *(uint4*)&sAl[ldsw + 8] = ral1;
    *(uint4*)&sBh[ldsw] = rbh0; *(uint4*)&sBh[ldsw + 8] = rbh1;
    *(uint4*)&sBl[ldsw] = rbl0; *(uint4*)&sBl[ldsw + 8] = rbl1;
    __syncthreads();
    int kn = k0 + 32;
    if (kn < Kp) {  // prefetch next k-slab under the MFMA body
      rah0 = aok ? *(const uint4*)(pAh + kn) : Z;
      rah1 = aok ? *(const uint4*)(pAh + kn + 8) : Z;
      ral0 = aok ? *(const uint4*)(pAl + kn) : Z;
      ral1 = aok ? *(const uint4*)(pAl + kn + 8) : Z;
      rbh0 = *(const uint4*)(pBh + kn);
      rbh1 = *(const uint4*)(pBh + kn + 8);
      rbl0 = *(const uint4*)(pBl + kn);
      rbl1 = *(const uint4*)(pBl + kn + 8);
    }
    bf16x8s afh[4], afl[4], bfh[4], bfl[4];
#pragma unroll
    for (int i = 0; i < 4; ++i) {
      int ai = (wr * 64 + i * 16 + fr) * 40 + kch;
      afh[i] = *(const bf16x8s*)&sAh[ai];
      afl[i] = *(const bf16x8s*)&sAl[ai];
      int bi = (wc * 64 + i * 16 + fr) * 40 + kch;
      bfh[i] = *(const bf16x8s*)&sBh[bi];
      bfl[i] = *(const bf16x8s*)&sBl[bi];
    }
#pragma unroll
    for (int i = 0; i < 4; ++i)
#pragma unroll
      for (int j = 0; j < 4; ++j) {
        acc[i][j] = __builtin_amdgcn_mfma_f32_16x16x32_bf16(afh[i], bfh[j], acc[i][j], 0, 0, 0);
        acc[i][j] = __builtin_amdgcn_mfma_f32_16x16x32_bf16(afh[i], bfl[j], acc[i][j], 0, 0, 0);
        acc[i][j] = __builtin_amdgcn_mfma_f32_16x16x32_bf16(afl[i], bfh[j], acc[i][j], 0, 0, 0);
      }
    k0 = kn;
    if (k0 >= Kp) break;
  }
  // epilogue: C/D layout col=lane&15, row=(lane>>4)*4+r (m89-verified)
#pragma unroll
  for (int i = 0; i < 4; ++i) {
    int growb = brow + wr * 64 + i * 16 + (lane >> 4) * 4;
#pragma unroll
    for (int j = 0; j < 4; ++j) {
      int gcol = bcol + wc * 64 + j * 16 + fr;
#pragma unroll
      for (int r = 0; r < 4; ++r) {
        int grow = growb + r;
        if (grow < N) C[(size_t)grow * ldc + gcol] = acc[i][j][r];
      }
    }
  }
}

// ---------------- CSR build ----------------
__global__ void count_kernel(const int* __restrict__ dst, int* __restrict__ cnt, int E) {
  int e = blockIdx.x * blockDim.x + threadIdx.x;
  if (e < E) atomicAdd(&cnt[dst[e]], 1);
}

// per-1024-chunk exclusive scan + chunk totals
__global__ void scan_blk_kernel(const int* __restrict__ cnt, int* __restrict__ row_ptr,
                                int* __restrict__ bsum, int N) {
  __shared__ int lds[1024];
  int tid = threadIdx.x;
  int i = blockIdx.x * 1024 + tid;
  int v = (i < N) ? cnt[i] : 0;
  lds[tid] = v;
  __syncthreads();
  for (int o = 1; o < 1024; o <<= 1) {
    int t = (tid >= o) ? lds[tid - o] : 0;
    __syncthreads();
    lds[tid] += t;
    __syncthreads();
  }
  if (i < N) row_ptr[i] = lds[tid] - v;
  if (tid == 1023) bsum[blockIdx.x] = lds[1023];
}

// single-chunk scan (used for the <=1024 chunk totals): exclusive + total at [n]
__global__ void scan_kernel(const int* __restrict__ cnt, int* __restrict__ row_ptr, int N) {
  __shared__ int lds[1024];
  __shared__ int carry;
  int tid = threadIdx.x;
  if (tid == 0) carry = 0;
  __syncthreads();
  for (int base = 0; base < N; base += 1024) {
    int i = base + tid;
    int v = (i < N) ? cnt[i] : 0;
    lds[tid] = v;
    __syncthreads();
    for (int o = 1; o < 1024; o <<= 1) {
      int t = (tid >= o) ? lds[tid - o] : 0;
      __syncthreads();
      lds[tid] += t;
      __syncthreads();
    }
    int incl = lds[tid];
    if (i < N) row_ptr[i] = carry + incl - v;
    __syncthreads();
    if (tid == 1023) carry += incl;
    __syncthreads();
  }
  if (tid == 0) row_ptr[N] = carry;
}

__global__ void scan_add_kernel(int* __restrict__ row_ptr, const int* __restrict__ bexc,
                                int N, int nb) {
  int i = blockIdx.x * blockDim.x + threadIdx.x;
  if (i < N) row_ptr[i] += bexc[i >> 10];
  if (i == 0) row_ptr[N] = bexc[nb];
}

__global__ void copyint_kernel(const int* __restrict__ src, int* __restrict__ dst, int N) {
  int i = blockIdx.x * blockDim.x + threadIdx.x;
  if (i < N) dst[i] = src[i];
}

__global__ void scatter_kernel(const int* __restrict__ dst, int* __restrict__ fill,
                               int* __restrict__ elist, int E) {
  int e = blockIdx.x * blockDim.x + threadIdx.x;
  if (e < E) {
    int p = atomicAdd(&fill[dst[e]], 1);
    elist[p] = e;
  }
}

// ---------------- GATv2 layer 1: H=2, D=256, one WAVE per node ----------------
__global__ __launch_bounds__(256) void gat1_kernel(
    const float* __restrict__ xl, const float* __restrict__ xr, int ldx,
    const float* __restrict__ edge_attr, const int* __restrict__ src_idx,
    const int* __restrict__ row_ptr, const int* __restrict__ elist,
    const float* __restrict__ We, const float* __restrict__ att,
    const float* __restrict__ bias, float* __restrict__ out, int Nn) {
  int n = __builtin_amdgcn_readfirstlane(blockIdx.x * 4 + (threadIdx.x >> 6));
  if (n >= Nn) return;
  int lane = threadIdx.x & 63;
  int c4 = lane * 4;
  const float4 we0 = *(const float4*)(We + c4);
  const float4 we1 = *(const float4*)(We + 256 + c4);
  const float4 at4 = *(const float4*)(att + c4);
  const float4 xr4 = *(const float4*)(xr + (size_t)n * ldx + c4);
  int start = row_ptr[n], end = row_ptr[n + 1];
  float4 acc = {0.f, 0.f, 0.f, 0.f};
  float sacc = 0.f;

  int e, sv;
  float ea0, ea1;
  float4 xl4;
  if (start < end) {
    e = __builtin_amdgcn_readfirstlane(elist[start]);
    sv = __builtin_amdgcn_readfirstlane(src_idx[e]);
    ea0 = edge_attr[2 * (size_t)e];
    ea1 = edge_attr[2 * (size_t)e + 1];
    xl4 = *(const float4*)(xl + (size_t)sv * ldx + c4);
  }
  for (int i = start; i < end; ++i) {
    float4 xc = xl4;
    float e0 = ea0, e1 = ea1;
    if (i + 1 < end) {
      e = __builtin_amdgcn_readfirstlane(elist[i + 1]);
      sv = __builtin_amdgcn_readfirstlane(src_idx[e]);
      ea0 = edge_attr[2 * (size_t)e];
      ea1 = edge_attr[2 * (size_t)e + 1];
      xl4 = *(const float4*)(xl + (size_t)sv * ldx + c4);
    }
    float zx = xc.x + xr4.x + e0 * we0.x + e1 * we1.x;
    float zy = xc.y + xr4.y + e0 * we0.y + e1 * we1.y;
    float zz = xc.z + xr4.z + e0 * we0.z + e1 * we1.z;
    float zw = xc.w + xr4.w + e0 * we0.w + e1 * we1.w;
    zx = (zx > 0.f) ? zx : 0.2f * zx;
    zy = (zy > 0.f) ? zy : 0.2f * zy;
    zz = (zz > 0.f) ? zz : 0.2f * zz;
    zw = (zw > 0.f) ? zw : 0.2f * zw;
    float part = zx * at4.x + zy * at4.y + zz * at4.z + zw * at4.w;
#pragma unroll
    for (int o = 16; o > 0; o >>= 1) part += __shfl_xor(part, o, 32);
    float p = __expf(part);
    acc.x += p * xc.x;
    acc.y += p * xc.y;
    acc.z += p * xc.z;
    acc.w += p * xc.w;
    sacc += p;
  }
  int deg = end - start;
  float inv = 1.f / ((sacc + 1e-16f) * (float)(deg > 0 ? deg : 1));
  float4 o4;
  o4.x = acc.x * inv + bias[c4];
  o4.y = acc.y * inv + bias[c4 + 1];
  o4.z = acc.z * inv + bias[c4 + 2];
  o4.w = acc.w * inv + bias[c4 + 3];
  *(float4*)(out + (size_t)n * 256 + c4) = o4;
}

// ---------------- GATv2 layer 2: H=1, D=128, one WAVE per node ----------------
__global__ __launch_bounds__(256) void gat2_kernel(
    const float* __restrict__ xl, const float* __restrict__ xr, int ldx,
    const float* __restrict__ edge_attr, const int* __restrict__ src_idx,
    const int* __restrict__ row_ptr, const int* __restrict__ elist,
    const float* __restrict__ We, const float* __restrict__ att,
    const float* __restrict__ bias, float* __restrict__ out, int Nn) {
  int n = __builtin_amdgcn_readfirstlane(blockIdx.x * 4 + (threadIdx.x >> 6));
  if (n >= Nn) return;
  int lane = threadIdx.x & 63;
  int c2 = lane * 2;
  const float2 we0 = *(const float2*)(We + c2);
  const float2 we1 = *(const float2*)(We + 128 + c2);
  const float2 at2 = *(const float2*)(att + c2);
  const float2 xr2 = *(const float2*)(xr + (size_t)n * ldx + c2);
  int start = row_ptr[n], end = row_ptr[n + 1];
  float2 acc = {0.f, 0.f};
  float sacc = 0.f;

  int e, sv;
  float ea0, ea1;
  float2 xl2;
  if (start < end) {
    e = __builtin_amdgcn_readfirstlane(elist[start]);
    sv = __builtin_amdgcn_readfirstlane(src_idx[e]);
    ea0 = edge_attr[2 * (size_t)e];
    ea1 = edge_attr[2 * (size_t)e + 1];
    xl2 = *(const float2*)(xl + (size_t)sv * ldx + c2);
  }
  for (int i = start; i < end; ++i) {
    float2 xc = xl2;
    float e0 = ea0, e1 = ea1;
    if (i + 1 < end) {
      e = __builtin_amdgcn_readfirstlane(elist[i + 1]);
      sv = __builtin_amdgcn_readfirstlane(src_idx[e]);
      ea0 = edge_attr[2 * (size_t)e];
      ea1 = edge_attr[2 * (size_t)e + 1];
      xl2 = *(const float2*)(xl + (size_t)sv * ldx + c2);
    }
    float zx = xc.x + xr2.x + e0 * we0.x + e1 * we1.x;
    float zy = xc.y + xr2.y + e0 * we0.y + e1 * we1.y;
    zx = (zx > 0.f) ? zx : 0.2f * zx;
    zy = (zy > 0.f) ? zy : 0.2f * zy;
    float part = zx * at2.x + zy * at2.y;
#pragma unroll
    for (int o = 32; o > 0; o >>= 1) part += __shfl_xor(part, o);
    float p = __expf(part);
    acc.x += p * xc.x;
    acc.y += p * xc.y;
    sacc += p;
  }
  int deg = end - start;
  float inv = 1.f / ((sacc + 1e-16f) * (float)(deg > 0 ? deg : 1));
  float2 o2;
  o2.x = acc.x * inv + bias[c2];
  o2.y = acc.y * inv + bias[c2 + 1];
  *(float2*)(out + (size_t)n * 128 + c2) = o2;
}

// ---------------- layer-3 (ch=1): one wave per node ----------------
__global__ void gat3_kernel(const float* __restrict__ xl, const float* __restrict__ xr,
                            const float* __restrict__ edge_attr, const int* __restrict__ src_idx,
                            const int* __restrict__ row_ptr, const int* __restrict__ elist,
                            const float* __restrict__ We, const float* __restrict__ att,
                            const float* __restrict__ bias, float* __restrict__ out, int Nn) {
  int n = blockIdx.x * 4 + (threadIdx.x >> 6);
  int lane = threadIdx.x & 63;
  if (n >= Nn) return;
  float we0 = We[0], we1 = We[1], a = att[0];
  float xr_n = xr[n];
  int s0 = row_ptr[n], s1 = row_ptr[n + 1];
  float accp = 0.f, accs = 0.f;
  for (int i = s0 + lane; i < s1; i += 64) {
    int e = elist[i];
    int sv = src_idx[e];
    float xls = xl[sv];
    float z = xls + xr_n + edge_attr[2 * (size_t)e] * we0 + edge_attr[2 * (size_t)e + 1] * we1;
    z = (z > 0.f) ? z : 0.2f * z;
    float p = __expf(z * a);
    accp += p * xls;
    accs += p;
  }
#pragma unroll
  for (int o = 32; o > 0; o >>= 1) {
    accp += __shfl_xor(accp, o);
    accs += __shfl_xor(accs, o);
  }
  int deg = s1 - s0;
  if (lane == 0) out[n] = accp / ((accs + 1e-16f) * (float)(deg > 0 ? deg : 1)) + bias[0];
}

// ---------------- row dot: out[n] = A[n,:K] . w ----------------
__global__ void rowdot_kernel(const float* __restrict__ A, const float* __restrict__ w,
                              float* __restrict__ out, int Nn, int K) {
  int n = blockIdx.x * 4 + (threadIdx.x >> 6);
  int lane = threadIdx.x & 63;
  if (n >= Nn) return;
  float p = 0.f;
  for (int k = lane; k < K; k += 64) p += A[(size_t)n * K + k] * w[k];
#pragma unroll
  for (int o = 32; o > 0; o >>= 1) p += __shfl_xor(p, o);
  if (lane == 0) out[n] = p;
}

extern "C" void kernel_launch(void* const* d_in, const int* in_sizes, int n_in,
                              void* d_out, int out_size, void* d_ws, size_t ws_size,
                              hipStream_t stream) {
  const float* x     = (const float*)d_in[0];
  const int*   ei    = (const int*)d_in[1];
  const float* ea    = (const float*)d_in[2];
  const float* bn0_g = (const float*)d_in[3];
  const float* bn0_b = (const float*)d_in[4];
  const float* Wl1   = (const float*)d_in[5];
  const float* Wr1   = (const float*)d_in[6];
  const float* We1   = (const float*)d_in[7];
  const float* att1  = (const float*)d_in[8];
  const float* b1    = (const float*)d_in[9];
  const float* bn1_g = (const float*)d_in[10];
  const float* bn1_b = (const float*)d_in[11];
  const float* Wl2   = (const float*)d_in[12];
  const float* Wr2   = (const float*)d_in[13];
  const float* We2   = (const float*)d_in[14];
  const float* att2  = (const float*)d_in[15];
  const float* b2    = (const float*)d_in[16];
  const float* bn2_g = (const float*)d_in[17];
  const float* bn2_b = (const float*)d_in[18];
  const float* Wl3   = (const float*)d_in[19];
  const float* Wr3   = (const float*)d_in[20];
  const float* We3   = (const float*)d_in[21];
  const float* att3  = (const float*)d_in[22];
  const float* b3    = (const float*)d_in[23];

  const int F = 301;
  const int Kp1 = 320;             // layer-1 K padded to multiple of 32
  const int N = in_sizes[0] / F;
  const int E = in_sizes[1] / 2;
  const int* srcv = ei;
  const int* dstv = ei + E;

  // ---- workspace layout (float units), regions time-shared ----
  float* fws = (float*)d_ws;
  float* RA = fws;                              // N*320 f: {Ahi,Alo} -> gat1out -> {gat2out,h2}
  float* RB = RA + (size_t)N * 320;             // N*512 f: xlr1 -> {h1hi,h1lo, xlr2}
  float* stats = RB + (size_t)N * 512;          // 1024
  u16* wt1h = (u16*)(stats + 1024);             // 512*320
  u16* wt1l = wt1h + (size_t)512 * 320;
  u16* wt2h = wt1l + (size_t)512 * 320;         // 256*256
  u16* wt2l = wt2h + (size_t)256 * 256;
  float* xl3 = (float*)(wt2l + (size_t)256 * 256);
  float* xr3 = xl3 + N;
  int* row_ptr = (int*)(xr3 + N);               // N+1
  int* fill    = row_ptr + (N + 1);             // N
  int* elist   = fill + N;                      // E
  int* bsum    = elist + E;                     // nb (<=64)
  int* bexc    = bsum + 64;                     // nb+1

  // region aliases along the timeline
  u16* Ahi = (u16*)RA;
  u16* Alo = Ahi + (size_t)N * Kp1;
  float* xlr1 = RB;                             // N x 512 (xl1 | xr1)
  float* g1out = RA;                            // N x 256 (gat1 out)
  u16* h1h = (u16*)RB;                          // N x 256 bf16
  u16* h1l = h1h + (size_t)N * 256;
  float* xlr2 = RB + (size_t)N * 256;           // N x 256 (xl2 | xr2)
  float* g2out = RA;                            // N x 128
  float* h2 = RA + (size_t)N * 128;             // N x 128

  // ---- CSR by dst (parallel 3-phase scan) ----
  int nb = cdiv(N, 1024);
  hipMemsetAsync(fill, 0, (size_t)N * sizeof(int), stream);
  count_kernel<<<cdiv(E, 256), 256, 0, stream>>>(dstv, fill, E);
  scan_blk_kernel<<<nb, 1024, 0, stream>>>(fill, row_ptr, bsum, N);
  scan_kernel<<<1, 1024, 0, stream>>>(bsum, bexc, nb);
  scan_add_kernel<<<cdiv(N, 256), 256, 0, stream>>>(row_ptr, bexc, N, nb);
  copyint_kernel<<<cdiv(N, 256), 256, 0, stream>>>(row_ptr, fill, N);
  scatter_kernel<<<cdiv(E, 256), 256, 0, stream>>>(dstv, fill, elist, E);

  // ---- weight prep: [xl|xr] transposed + split ----
  wt_split_kernel<<<cdiv(512 * Kp1, 256), 256, 0, stream>>>(Wl1, Wr1, wt1h, wt1l, F, Kp1, 256);
  wt_split_kernel<<<cdiv(256 * 256, 256), 256, 0, stream>>>(Wl2, Wr2, wt2h, wt2l, 256, 256, 128);

  int rows = cdiv(N, 256);

  // ---- BN0 -> split bf16 A planes (N x 320, zero-padded) ----
  hipMemsetAsync(stats, 0, 1024 * sizeof(float), stream);
  col_stats_kernel<<<256, 320, 0, stream>>>(x, stats, N, F, rows);
  bn_split_kernel<<<256, 320, 0, stream>>>(x, Ahi, Alo, stats, bn0_g, bn0_b, N, F, Kp1, rows, 0);

  // ---- layer 1: fused [xl|xr] MFMA GEMM + edge pass ----
  gemm_mfma<<<dim3(cdiv(N, 128), 4), 256, 0, stream>>>(Ahi, Alo, wt1h, wt1l, xlr1, N, Kp1, 512);
  gat1_kernel<<<cdiv(N, 4), 256, 0, stream>>>(xlr1, xlr1 + 256, 512, ea, srcv, row_ptr, elist,
                                              We1, att1, b1, g1out, N);
  // ---- BN1 + relu -> split bf16 h1 planes ----
  hipMemsetAsync(stats, 0, 1024 * sizeof(float), stream);
  col_stats_kernel<<<256, 256, 0, stream>>>(g1out, stats, N, 256, rows);
  bn_split_kernel<<<256, 256, 0, stream>>>(g1out, h1h, h1l, stats, bn1_g, bn1_b, N, 256, 256, rows, 1);

  // ---- layer 2: fused [xl|xr] MFMA GEMM + edge pass ----
  gemm_mfma<<<dim3(cdiv(N, 128), 2), 256, 0, stream>>>(h1h, h1l, wt2h, wt2l, xlr2, N, 256, 256);
  gat2_kernel<<<cdiv(N, 4), 256, 0, stream>>>(xlr2, xlr2 + 128, 256, ea, srcv, row_ptr, elist,
                                              We2, att2, b2, g2out, N);
  // ---- BN2 + relu -> fp32 h2 ----
  hipMemsetAsync(stats, 0, 1024 * sizeof(float), stream);
  col_stats_kernel<<<256, 128, 0, stream>>>(g2out, stats, N, 128, rows);
  bn_apply_kernel<<<256, 128, 0, stream>>>(g2out, h2, stats, bn2_g, bn2_b, N, 128, 128, rows, 1);

  // ---- layer 3 (ch=1) ----
  rowdot_kernel<<<cdiv(N, 4), 256, 0, stream>>>(h2, Wl3, xl3, N, 128);
  rowdot_kernel<<<cdiv(N, 4), 256, 0, stream>>>(h2, Wr3, xr3, N, 128);
  gat3_kernel<<<cdiv(N, 4), 256, 0, stream>>>(xl3, xr3, ea, srcv, row_ptr, elist,
                                              We3, att3, b3, (float*)d_out, N);
}

// Round 6
// 854.035 us; speedup vs baseline: 2.1405x; 1.0263x over previous
//
#include <hip/hip_runtime.h>
#include <hip/hip_fp16.h>

#define EPSF 1e-5f

typedef unsigned short u16;
typedef __attribute__((ext_vector_type(8))) short bf16x8s;  // 8 bf16 (4 VGPRs)
typedef __attribute__((ext_vector_type(4))) float f32x4;

static inline int cdiv(int a, int b) { return (a + b - 1) / b; }

// split v into hi (bit-truncated bf16) + lo (round-nearest bf16 of remainder)
__device__ inline void bf_split(float v, u16& h, u16& l) {
  unsigned u = __float_as_uint(v);
  h = (u16)(u >> 16);
  float hf = __uint_as_float(u & 0xffff0000u);
  float r = v - hf;
  unsigned ur = __float_as_uint(r);
  ur += 0x7fffu + ((ur >> 16) & 1u);
  l = (u16)(ur >> 16);
}

__device__ inline float4 cvt_h4(uint2 r) {
  float2 a = __half22float2(*(__half2*)&r.x);
  float2 b = __half22float2(*(__half2*)&r.y);
  return make_float4(a.x, a.y, b.x, b.y);
}
__device__ inline float2 cvt_h2(unsigned r) { return __half22float2(*(__half2*)&r); }

__device__ inline void st_out(float* p, float v) { *p = v; }
__device__ inline void st_out(u16* p, float v) { *p = __half_as_ushort(__float2half(v)); }

// ---------------- column stats (sum, sumsq); X stride == F ----------------
__global__ void col_stats_kernel(const float* __restrict__ X, float* __restrict__ sums,
                                 int N, int F, int rowsPer) {
  int c = threadIdx.x;
  if (c >= F) return;
  int r0 = blockIdx.x * rowsPer;
  int r1 = min(N, r0 + rowsPer);
  float s = 0.f, sq = 0.f;
  for (int r = r0; r < r1; ++r) {
    float v = X[(size_t)r * F + c];
    s += v; sq += v * v;
  }
  atomicAdd(&sums[c], s);
  atomicAdd(&sums[512 + c], sq);
}

// ---------------- BN apply -> fp32 (BN2) ----------------
__global__ void bn_apply_kernel(const float* __restrict__ X, float* __restrict__ Y,
                                const float* __restrict__ sums,
                                const float* __restrict__ g, const float* __restrict__ b,
                                int N, int F, int outW, int rowsPer, int relu) {
  int c = threadIdx.x;
  if (c >= outW) return;
  float sc = 0.f, bb = 0.f;
  if (c < F) {
    float invN = 1.f / (float)N;
    float mu = sums[c] * invN;
    float var = sums[512 + c] * invN - mu * mu;
    sc = g[c] * rsqrtf(var + EPSF);
    bb = b[c] - mu * sc;
  }
  int r0 = blockIdx.x * rowsPer, r1 = min(N, r0 + rowsPer);
  for (int r = r0; r < r1; ++r) {
    float v = (c < F) ? X[(size_t)r * F + c] * sc + bb : 0.f;
    if (relu) v = fmaxf(v, 0.f);
    Y[(size_t)r * outW + c] = v;
  }
}

// ---------------- BN apply -> split bf16 hi/lo planes (BN0, BN1) ----------------
__global__ void bn_split_kernel(const float* __restrict__ X,
                                u16* __restrict__ Yhi, u16* __restrict__ Ylo,
                                const float* __restrict__ sums,
                                const float* __restrict__ g, const float* __restrict__ b,
                                int N, int F, int outW, int rowsPer, int relu) {
  int c = threadIdx.x;
  if (c >= outW) return;
  float sc = 0.f, bb = 0.f;
  if (c < F) {
    float invN = 1.f / (float)N;
    float mu = sums[c] * invN;
    float var = sums[512 + c] * invN - mu * mu;
    sc = g[c] * rsqrtf(var + EPSF);
    bb = b[c] - mu * sc;
  }
  int r0 = blockIdx.x * rowsPer, r1 = min(N, r0 + rowsPer);
  for (int r = r0; r < r1; ++r) {
    float v = (c < F) ? X[(size_t)r * F + c] * sc + bb : 0.f;
    if (relu) v = fmaxf(v, 0.f);
    u16 h, l;
    bf_split(v, h, l);
    Yhi[(size_t)r * outW + c] = h;
    Ylo[(size_t)r * outW + c] = l;
  }
}

// ---------------- weights: transpose + concat + pad + split -> [2M][Kp] bf16 hi/lo ----------------
__global__ void wt_split_kernel(const float* __restrict__ Wa, const float* __restrict__ Wb,
                                u16* __restrict__ Whi, u16* __restrict__ Wlo,
                                int K, int Kp, int M) {
  int idx = blockIdx.x * blockDim.x + threadIdx.x;
  if (idx >= 2 * M * Kp) return;
  int col = idx / Kp;
  int k = idx - col * Kp;
  float v = 0.f;
  if (k < K) v = (col < M) ? Wa[(size_t)k * M + col] : Wb[(size_t)k * M + (col - M)];
  u16 h, l;
  bf_split(v, h, l);
  Whi[idx] = h;
  Wlo[idx] = l;
}

// ---------------- split-bf16 MFMA GEMM: C(NxMout) = (Ahi+Alo)(Whi+Wlo)^T ----------------
template <typename OutT>
__global__ __launch_bounds__(256) void gemm_mfma(
    const u16* __restrict__ Ahi, const u16* __restrict__ Alo,
    const u16* __restrict__ Bhi, const u16* __restrict__ Blo,
    OutT* __restrict__ C, int N, int Kp, int ldc) {
  __shared__ u16 sAh[128 * 40], sAl[128 * 40], sBh[128 * 40], sBl[128 * 40];
  int tid = threadIdx.x;
  int brow = blockIdx.x * 128, bcol = blockIdx.y * 128;
  int stR = tid >> 1;
  int stC0 = (tid & 1) * 2;
  bool aok = (brow + stR) < N;
  const u16* pAh = Ahi + (size_t)(brow + stR) * Kp + stC0 * 8;
  const u16* pAl = Alo + (size_t)(brow + stR) * Kp + stC0 * 8;
  const u16* pBh = Bhi + (size_t)(bcol + stR) * Kp + stC0 * 8;
  const u16* pBl = Blo + (size_t)(bcol + stR) * Kp + stC0 * 8;
  const uint4 Z = make_uint4(0u, 0u, 0u, 0u);
  uint4 rah0 = aok ? *(const uint4*)(pAh) : Z;
  uint4 rah1 = aok ? *(const uint4*)(pAh + 8) : Z;
  uint4 ral0 = aok ? *(const uint4*)(pAl) : Z;
  uint4 ral1 = aok ? *(const uint4*)(pAl + 8) : Z;
  uint4 rbh0 = *(const uint4*)(pBh);
  uint4 rbh1 = *(const uint4*)(pBh + 8);
  uint4 rbl0 = *(const uint4*)(pBl);
  uint4 rbl1 = *(const uint4*)(pBl + 8);
  f32x4 acc[4][4] = {};
  int lane = tid & 63;
  int wv = tid >> 6, wr = wv >> 1, wc = wv & 1;
  int fr = lane & 15, kch = (lane >> 4) * 8;
  int ldsw = stR * 40 + stC0 * 8;
  for (int k0 = 0;;) {
    __syncthreads();
    *(uint4*)&sAh[ldsw] = rah0; *(uint4*)&sAh[ldsw + 8] = rah1;
    *(uint4*)&sAl[ldsw] = ral0; *(uint4*)&sAl[ldsw + 8] = ral1;
    *(uint4*)&sBh[ldsw] = rbh0; *(uint4*)&sBh[ldsw + 8] = rbh1;
    *(uint4*)&sBl[ldsw] = rbl0; *(uint4*)&sBl[ldsw + 8] = rbl1;
    __syncthreads();
    int kn = k0 + 32;
    if (kn < Kp) {  // prefetch next k-slab under the MFMA body
      rah0 = aok ? *(const uint4*)(pAh + kn) : Z;
      rah1 = aok ? *(const uint4*)(pAh + kn + 8) : Z;
      ral0 = aok ? *(const uint4*)(pAl + kn) : Z;
      ral1 = aok ? *(const uint4*)(pAl + kn + 8) : Z;
      rbh0 = *(const uint4*)(pBh + kn);
      rbh1 = *(const uint4*)(pBh + kn + 8);
      rbl0 = *(const uint4*)(pBl + kn);
      rbl1 = *(const uint4*)(pBl + kn + 8);
    }
    bf16x8s afh[4], afl[4], bfh[4], bfl[4];
#pragma unroll
    for (int i = 0; i < 4; ++i) {
      int ai = (wr * 64 + i * 16 + fr) * 40 + kch;
      afh[i] = *(const bf16x8s*)&sAh[ai];
      afl[i] = *(const bf16x8s*)&sAl[ai];
      int bi = (wc * 64 + i * 16 + fr) * 40 + kch;
      bfh[i] = *(const bf16x8s*)&sBh[bi];
      bfl[i] = *(const bf16x8s*)&sBl[bi];
    }
#pragma unroll
    for (int i = 0; i < 4; ++i)
#pragma unroll
      for (int j = 0; j < 4; ++j) {
        acc[i][j] = __builtin_amdgcn_mfma_f32_16x16x32_bf16(afh[i], bfh[j], acc[i][j], 0, 0, 0);
        acc[i][j] = __builtin_amdgcn_mfma_f32_16x16x32_bf16(afh[i], bfl[j], acc[i][j], 0, 0, 0);
        acc[i][j] = __builtin_amdgcn_mfma_f32_16x16x32_bf16(afl[i], bfh[j], acc[i][j], 0, 0, 0);
      }
    k0 = kn;
    if (k0 >= Kp) break;
  }
#pragma unroll
  for (int i = 0; i < 4; ++i) {
    int growb = brow + wr * 64 + i * 16 + (lane >> 4) * 4;
#pragma unroll
    for (int j = 0; j < 4; ++j) {
      int gcol = bcol + wc * 64 + j * 16 + fr;
#pragma unroll
      for (int r = 0; r < 4; ++r) {
        int grow = growb + r;
        if (grow < N) st_out(&C[(size_t)grow * ldc + gcol], acc[i][j][r]);
      }
    }
  }
}

// ---------------- CSR build ----------------
__global__ void count_kernel(const int* __restrict__ dst, int* __restrict__ cnt, int E) {
  int e = blockIdx.x * blockDim.x + threadIdx.x;
  if (e < E) atomicAdd(&cnt[dst[e]], 1);
}

__global__ void scan_blk_kernel(const int* __restrict__ cnt, int* __restrict__ row_ptr,
                                int* __restrict__ bsum, int N) {
  __shared__ int lds[1024];
  int tid = threadIdx.x;
  int i = blockIdx.x * 1024 + tid;
  int v = (i < N) ? cnt[i] : 0;
  lds[tid] = v;
  __syncthreads();
  for (int o = 1; o < 1024; o <<= 1) {
    int t = (tid >= o) ? lds[tid - o] : 0;
    __syncthreads();
    lds[tid] += t;
    __syncthreads();
  }
  if (i < N) row_ptr[i] = lds[tid] - v;
  if (tid == 1023) bsum[blockIdx.x] = lds[1023];
}

__global__ void scan_kernel(const int* __restrict__ cnt, int* __restrict__ row_ptr, int N) {
  __shared__ int lds[1024];
  __shared__ int carry;
  int tid = threadIdx.x;
  if (tid == 0) carry = 0;
  __syncthreads();
  for (int base = 0; base < N; base += 1024) {
    int i = base + tid;
    int v = (i < N) ? cnt[i] : 0;
    lds[tid] = v;
    __syncthreads();
    for (int o = 1; o < 1024; o <<= 1) {
      int t = (tid >= o) ? lds[tid - o] : 0;
      __syncthreads();
      lds[tid] += t;
      __syncthreads();
    }
    int incl = lds[tid];
    if (i < N) row_ptr[i] = carry + incl - v;
    __syncthreads();
    if (tid == 1023) carry += incl;
    __syncthreads();
  }
  if (tid == 0) row_ptr[N] = carry;
}

__global__ void scan_add_kernel(int* __restrict__ row_ptr, const int* __restrict__ bexc,
                                int N, int nb) {
  int i = blockIdx.x * blockDim.x + threadIdx.x;
  if (i < N) row_ptr[i] += bexc[i >> 10];
  if (i == 0) row_ptr[N] = bexc[nb];
}

__global__ void copyint_kernel(const int* __restrict__ src, int* __restrict__ dst, int N) {
  int i = blockIdx.x * blockDim.x + threadIdx.x;
  if (i < N) dst[i] = src[i];
}

__global__ void scatter_kernel(const int* __restrict__ dst, int* __restrict__ fill,
                               int* __restrict__ elist, int E) {
  int e = blockIdx.x * blockDim.x + threadIdx.x;
  if (e < E) {
    int p = atomicAdd(&fill[dst[e]], 1);
    elist[p] = e;
  }
}

// ---------------- GATv2 layer 1: H=2, D=256 (fp16 xlr), one WAVE per node ----------------
// lane l owns channels [4l,4l+4); lanes 0..31 head0, 32..63 head1.
// Depth-2 pipeline with statically named slots A/B (no runtime-indexed reg arrays).
__global__ __launch_bounds__(256) void gat1_kernel(
    const u16* __restrict__ xl, const u16* __restrict__ xr, int ldx,
    const float* __restrict__ edge_attr, const int* __restrict__ src_idx,
    const int* __restrict__ row_ptr, const int* __restrict__ elist,
    const float* __restrict__ We, const float* __restrict__ att,
    const float* __restrict__ bias, float* __restrict__ out, int Nn) {
  int n = __builtin_amdgcn_readfirstlane(blockIdx.x * 4 + (threadIdx.x >> 6));
  if (n >= Nn) return;
  int lane = threadIdx.x & 63;
  int c4 = lane * 4;
  const float4 we0 = *(const float4*)(We + c4);
  const float4 we1 = *(const float4*)(We + 256 + c4);
  const float4 at4 = *(const float4*)(att + c4);
  const float4 xr4 = cvt_h4(*(const uint2*)(xr + (size_t)n * ldx + c4));
  int start = row_ptr[n];
  int deg = row_ptr[n + 1] - start;
  float4 acc = {0.f, 0.f, 0.f, 0.f};
  float sacc = 0.f;

  uint2 rawA = {0, 0}, rawB = {0, 0};
  float a0 = 0.f, a1 = 0.f, b0 = 0.f, b1 = 0.f;
  if (deg > 0) {
    int e = __builtin_amdgcn_readfirstlane(elist[start]);
    int sv = __builtin_amdgcn_readfirstlane(src_idx[e]);
    a0 = edge_attr[2 * (size_t)e]; a1 = edge_attr[2 * (size_t)e + 1];
    rawA = *(const uint2*)(xl + (size_t)sv * ldx + c4);
  }
  if (deg > 1) {
    int e = __builtin_amdgcn_readfirstlane(elist[start + 1]);
    int sv = __builtin_amdgcn_readfirstlane(src_idx[e]);
    b0 = edge_attr[2 * (size_t)e]; b1 = edge_attr[2 * (size_t)e + 1];
    rawB = *(const uint2*)(xl + (size_t)sv * ldx + c4);
  }
  auto consume = [&](uint2 raw, float e0, float e1) {
    float4 xc = cvt_h4(raw);
    float zx = xc.x + xr4.x + e0 * we0.x + e1 * we1.x;
    float zy = xc.y + xr4.y + e0 * we0.y + e1 * we1.y;
    float zz = xc.z + xr4.z + e0 * we0.z + e1 * we1.z;
    float zw = xc.w + xr4.w + e0 * we0.w + e1 * we1.w;
    zx = (zx > 0.f) ? zx : 0.2f * zx;
    zy = (zy > 0.f) ? zy : 0.2f * zy;
    zz = (zz > 0.f) ? zz : 0.2f * zz;
    zw = (zw > 0.f) ? zw : 0.2f * zw;
    float part = zx * at4.x + zy * at4.y + zz * at4.z + zw * at4.w;
#pragma unroll
    for (int o = 16; o > 0; o >>= 1) part += __shfl_xor(part, o, 32);
    float p = __expf(part);
    acc.x += p * xc.x;
    acc.y += p * xc.y;
    acc.z += p * xc.z;
    acc.w += p * xc.w;
    sacc += p;
  };
  int j = 0;
  for (; j + 1 < deg; j += 2) {
    uint2 r = rawA; float r0 = a0, r1 = a1;
    if (j + 2 < deg) {
      int e = __builtin_amdgcn_readfirstlane(elist[start + j + 2]);
      int sv = __builtin_amdgcn_readfirstlane(src_idx[e]);
      a0 = edge_attr[2 * (size_t)e]; a1 = edge_attr[2 * (size_t)e + 1];
      rawA = *(const uint2*)(xl + (size_t)sv * ldx + c4);
    }
    consume(r, r0, r1);
    uint2 s = rawB; float s0 = b0, s1 = b1;
    if (j + 3 < deg) {
      int e = __builtin_amdgcn_readfirstlane(elist[start + j + 3]);
      int sv = __builtin_amdgcn_readfirstlane(src_idx[e]);
      b0 = edge_attr[2 * (size_t)e]; b1 = edge_attr[2 * (size_t)e + 1];
      rawB = *(const uint2*)(xl + (size_t)sv * ldx + c4);
    }
    consume(s, s0, s1);
  }
  if (j < deg) consume(rawA, a0, a1);

  float inv = 1.f / ((sacc + 1e-16f) * (float)(deg > 0 ? deg : 1));
  float4 o4;
  o4.x = acc.x * inv + bias[c4];
  o4.y = acc.y * inv + bias[c4 + 1];
  o4.z = acc.z * inv + bias[c4 + 2];
  o4.w = acc.w * inv + bias[c4 + 3];
  *(float4*)(out + (size_t)n * 256 + c4) = o4;
}

// ---------------- GATv2 layer 2: H=1, D=128 (fp16 xlr), one WAVE per node ----------------
__global__ __launch_bounds__(256) void gat2_kernel(
    const u16* __restrict__ xl, const u16* __restrict__ xr, int ldx,
    const float* __restrict__ edge_attr, const int* __restrict__ src_idx,
    const int* __restrict__ row_ptr, const int* __restrict__ elist,
    const float* __restrict__ We, const float* __restrict__ att,
    const float* __restrict__ bias, float* __restrict__ out, int Nn) {
  int n = __builtin_amdgcn_readfirstlane(blockIdx.x * 4 + (threadIdx.x >> 6));
  if (n >= Nn) return;
  int lane = threadIdx.x & 63;
  int c2 = lane * 2;
  const float2 we0 = *(const float2*)(We + c2);
  const float2 we1 = *(const float2*)(We + 128 + c2);
  const float2 at2 = *(const float2*)(att + c2);
  const float2 xr2 = cvt_h2(*(const unsigned*)(xr + (size_t)n * ldx + c2));
  int start = row_ptr[n];
  int deg = row_ptr[n + 1] - start;
  float2 acc = {0.f, 0.f};
  float sacc = 0.f;

  unsigned rawA = 0, rawB = 0;
  float a0 = 0.f, a1 = 0.f, b0 = 0.f, b1 = 0.f;
  if (deg > 0) {
    int e = __builtin_amdgcn_readfirstlane(elist[start]);
    int sv = __builtin_amdgcn_readfirstlane(src_idx[e]);
    a0 = edge_attr[2 * (size_t)e]; a1 = edge_attr[2 * (size_t)e + 1];
    rawA = *(const unsigned*)(xl + (size_t)sv * ldx + c2);
  }
  if (deg > 1) {
    int e = __builtin_amdgcn_readfirstlane(elist[start + 1]);
    int sv = __builtin_amdgcn_readfirstlane(src_idx[e]);
    b0 = edge_attr[2 * (size_t)e]; b1 = edge_attr[2 * (size_t)e + 1];
    rawB = *(const unsigned*)(xl + (size_t)sv * ldx + c2);
  }
  auto consume = [&](unsigned raw, float e0, float e1) {
    float2 xc = cvt_h2(raw);
    float zx = xc.x + xr2.x + e0 * we0.x + e1 * we1.x;
    float zy = xc.y + xr2.y + e0 * we0.y + e1 * we1.y;
    zx = (zx > 0.f) ? zx : 0.2f * zx;
    zy = (zy > 0.f) ? zy : 0.2f * zy;
    float part = zx * at2.x + zy * at2.y;
#pragma unroll
    for (int o = 32; o > 0; o >>= 1) part += __shfl_xor(part, o);
    float p = __expf(part);
    acc.x += p * xc.x;
    acc.y += p * xc.y;
    sacc += p;
  };
  int j = 0;
  for (; j + 1 < deg; j += 2) {
    unsigned r = rawA; float r0 = a0, r1 = a1;
    if (j + 2 < deg) {
      int e = __builtin_amdgcn_readfirstlane(elist[start + j + 2]);
      int sv = __builtin_amdgcn_readfirstlane(src_idx[e]);
      a0 = edge_attr[2 * (size_t)e]; a1 = edge_attr[2 * (size_t)e + 1];
      rawA = *(const unsigned*)(xl + (size_t)sv * ldx + c2);
    }
    consume(r, r0, r1);
    unsigned s = rawB; float s0 = b0, s1 = b1;
    if (j + 3 < deg) {
      int e = __builtin_amdgcn_readfirstlane(elist[start + j + 3]);
      int sv = __builtin_amdgcn_readfirstlane(src_idx[e]);
      b0 = edge_attr[2 * (size_t)e]; b1 = edge_attr[2 * (size_t)e + 1];
      rawB = *(const unsigned*)(xl + (size_t)sv * ldx + c2);
    }
    consume(s, s0, s1);
  }
  if (j < deg) consume(rawA, a0, a1);

  float inv = 1.f / ((sacc + 1e-16f) * (float)(deg > 0 ? deg : 1));
  float2 o2;
  o2.x = acc.x * inv + bias[c2];
  o2.y = acc.y * inv + bias[c2 + 1];
  *(float2*)(out + (size_t)n * 128 + c2) = o2;
}

// ---------------- layer-3 (ch=1): one wave per node ----------------
__global__ void gat3_kernel(const float* __restrict__ xl, const float* __restrict__ xr,
                            const float* __restrict__ edge_attr, const int* __restrict__ src_idx,
                            const int* __restrict__ row_ptr, const int* __restrict__ elist,
                            const float* __restrict__ We, const float* __restrict__ att,
                            const float* __restrict__ bias, float* __restrict__ out, int Nn) {
  int n = blockIdx.x * 4 + (threadIdx.x >> 6);
  int lane = threadIdx.x & 63;
  if (n >= Nn) return;
  float we0 = We[0], we1 = We[1], a = att[0];
  float xr_n = xr[n];
  int s0 = row_ptr[n], s1 = row_ptr[n + 1];
  float accp = 0.f, accs = 0.f;
  for (int i = s0 + lane; i < s1; i += 64) {
    int e = elist[i];
    int sv = src_idx[e];
    float xls = xl[sv];
    float z = xls + xr_n + edge_attr[2 * (size_t)e] * we0 + edge_attr[2 * (size_t)e + 1] * we1;
    z = (z > 0.f) ? z : 0.2f * z;
    float p = __expf(z * a);
    accp += p * xls;
    accs += p;
  }
#pragma unroll
  for (int o = 32; o > 0; o >>= 1) {
    accp += __shfl_xor(accp, o);
    accs += __shfl_xor(accs, o);
  }
  int deg = s1 - s0;
  if (lane == 0) out[n] = accp / ((accs + 1e-16f) * (float)(deg > 0 ? deg : 1)) + bias[0];
}

// ---------------- row dot: out[n] = A[n,:K] . w ----------------
__global__ void rowdot_kernel(const float* __restrict__ A, const float* __restrict__ w,
                              float* __restrict__ out, int Nn, int K) {
  int n = blockIdx.x * 4 + (threadIdx.x >> 6);
  int lane = threadIdx.x & 63;
  if (n >= Nn) return;
  float p = 0.f;
  for (int k = lane; k < K; k += 64) p += A[(size_t)n * K + k] * w[k];
#pragma unroll
  for (int o = 32; o > 0; o >>= 1) p += __shfl_xor(p, o);
  if (lane == 0) out[n] = p;
}

extern "C" void kernel_launch(void* const* d_in, const int* in_sizes, int n_in,
                              void* d_out, int out_size, void* d_ws, size_t ws_size,
                              hipStream_t stream) {
  const float* x     = (const float*)d_in[0];
  const int*   ei    = (const int*)d_in[1];
  const float* ea    = (const float*)d_in[2];
  const float* bn0_g = (const float*)d_in[3];
  const float* bn0_b = (const float*)d_in[4];
  const float* Wl1   = (const float*)d_in[5];
  const float* Wr1   = (const float*)d_in[6];
  const float* We1   = (const float*)d_in[7];
  const float* att1  = (const float*)d_in[8];
  const float* b1    = (const float*)d_in[9];
  const float* bn1_g = (const float*)d_in[10];
  const float* bn1_b = (const float*)d_in[11];
  const float* Wl2   = (const float*)d_in[12];
  const float* Wr2   = (const float*)d_in[13];
  const float* We2   = (const float*)d_in[14];
  const float* att2  = (const float*)d_in[15];
  const float* b2    = (const float*)d_in[16];
  const float* bn2_g = (const float*)d_in[17];
  const float* bn2_b = (const float*)d_in[18];
  const float* Wl3   = (const float*)d_in[19];
  const float* Wr3   = (const float*)d_in[20];
  const float* We3   = (const float*)d_in[21];
  const float* att3  = (const float*)d_in[22];
  const float* b3    = (const float*)d_in[23];

  const int F = 301;
  const int Kp1 = 320;
  const int N = in_sizes[0] / F;
  const int E = in_sizes[1] / 2;
  const int* srcv = ei;
  const int* dstv = ei + E;

  // ---- workspace layout (float units), regions time-shared ----
  float* fws = (float*)d_ws;
  float* RA = fws;                              // N*320 f
  float* RB = RA + (size_t)N * 320;             // N*512 f
  float* stats = RB + (size_t)N * 512;          // 1024
  u16* wt1h = (u16*)(stats + 1024);             // 512*320
  u16* wt1l = wt1h + (size_t)512 * 320;
  u16* wt2h = wt1l + (size_t)512 * 320;         // 256*256
  u16* wt2l = wt2h + (size_t)256 * 256;
  float* xl3 = (float*)(wt2l + (size_t)256 * 256);
  float* xr3 = xl3 + N;
  int* row_ptr = (int*)(xr3 + N);               // N+1
  int* fill    = row_ptr + (N + 1);             // N
  int* elist   = fill + N;                      // E
  int* bsum    = elist + E;                     // nb (<=64)
  int* bexc    = bsum + 64;                     // nb+1

  // region aliases along the timeline
  u16* Ahi = (u16*)RA;                          // N x 320 bf16
  u16* Alo = Ahi + (size_t)N * Kp1;
  u16* xlr1 = (u16*)RB;                         // N x 512 fp16 (xl1 | xr1)
  float* g1out = RA;                            // N x 256 f (gat1 out)
  u16* h1h = (u16*)RB;                          // N x 256 bf16
  u16* h1l = h1h + (size_t)N * 256;
  u16* xlr2 = h1l + (size_t)N * 256;            // N x 256 fp16 (xl2 | xr2)
  float* g2out = RA;                            // N x 128 f
  float* h2 = RA + (size_t)N * 128;             // N x 128 f

  // ---- CSR by dst (parallel 3-phase scan) ----
  int nb = cdiv(N, 1024);
  hipMemsetAsync(fill, 0, (size_t)N * sizeof(int), stream);
  count_kernel<<<cdiv(E, 256), 256, 0, stream>>>(dstv, fill, E);
  scan_blk_kernel<<<nb, 1024, 0, stream>>>(fill, row_ptr, bsum, N);
  scan_kernel<<<1, 1024, 0, stream>>>(bsum, bexc, nb);
  scan_add_kernel<<<cdiv(N, 256), 256, 0, stream>>>(row_ptr, bexc, N, nb);
  copyint_kernel<<<cdiv(N, 256), 256, 0, stream>>>(row_ptr, fill, N);
  scatter_kernel<<<cdiv(E, 256), 256, 0, stream>>>(dstv, fill, elist, E);

  // ---- weight prep ----
  wt_split_kernel<<<cdiv(512 * Kp1, 256), 256, 0, stream>>>(Wl1, Wr1, wt1h, wt1l, F, Kp1, 256);
  wt_split_kernel<<<cdiv(256 * 256, 256), 256, 0, stream>>>(Wl2, Wr2, wt2h, wt2l, 256, 256, 128);

  int rows = cdiv(N, 256);

  // ---- BN0 -> split bf16 A planes ----
  hipMemsetAsync(stats, 0, 1024 * sizeof(float), stream);
  col_stats_kernel<<<256, 320, 0, stream>>>(x, stats, N, F, rows);
  bn_split_kernel<<<256, 320, 0, stream>>>(x, Ahi, Alo, stats, bn0_g, bn0_b, N, F, Kp1, rows, 0);

  // ---- layer 1: fused [xl|xr] MFMA GEMM (fp16 out) + edge pass ----
  gemm_mfma<u16><<<dim3(cdiv(N, 128), 4), 256, 0, stream>>>(Ahi, Alo, wt1h, wt1l, xlr1, N, Kp1, 512);
  gat1_kernel<<<cdiv(N, 4), 256, 0, stream>>>(xlr1, xlr1 + 256, 512, ea, srcv, row_ptr, elist,
                                              We1, att1, b1, g1out, N);
  // ---- BN1 + relu -> split bf16 h1 planes ----
  hipMemsetAsync(stats, 0, 1024 * sizeof(float), stream);
  col_stats_kernel<<<256, 256, 0, stream>>>(g1out, stats, N, 256, rows);
  bn_split_kernel<<<256, 256, 0, stream>>>(g1out, h1h, h1l, stats, bn1_g, bn1_b, N, 256, 256, rows, 1);

  // ---- layer 2: fused [xl|xr] MFMA GEMM (fp16 out) + edge pass ----
  gemm_mfma<u16><<<dim3(cdiv(N, 128), 2), 256, 0, stream>>>(h1h, h1l, wt2h, wt2l, xlr2, N, 256, 256);
  gat2_kernel<<<cdiv(N, 4), 256, 0, stream>>>(xlr2, xlr2 + 128, 256, ea, srcv, row_ptr, elist,
                                              We2, att2, b2, g2out, N);
  // ---- BN2 + relu -> fp32 h2 ----
  hipMemsetAsync(stats, 0, 1024 * sizeof(float), stream);
  col_stats_kernel<<<256, 128, 0, stream>>>(g2out, stats, N, 128, rows);
  bn_apply_kernel<<<256, 128, 0, stream>>>(g2out, h2, stats, bn2_g, bn2_b, N, 128, 128, rows, 1);

  // ---- layer 3 (ch=1) ----
  rowdot_kernel<<<cdiv(N, 4), 256, 0, stream>>>(h2, Wl3, xl3, N, 128);
  rowdot_kernel<<<cdiv(N, 4), 256, 0, stream>>>(h2, Wr3, xr3, N, 128);
  gat3_kernel<<<cdiv(N, 4), 256, 0, stream>>>(xl3, xr3, ea, srcv, row_ptr, elist,
                                              We3, att3, b3, (float*)d_out, N);
}

// Round 7
// 735.082 us; speedup vs baseline: 2.4869x; 1.1618x over previous
//
#include <hip/hip_runtime.h>
#include <hip/hip_fp16.h>

#define EPSF 1e-5f

typedef unsigned short u16;
typedef __attribute__((ext_vector_type(8))) short bf16x8s;  // 8 bf16 (4 VGPRs)
typedef __attribute__((ext_vector_type(4))) float f32x4;

static inline int cdiv(int a, int b) { return (a + b - 1) / b; }

// split v into hi (bit-truncated bf16) + lo (round-nearest bf16 of remainder)
__device__ inline void bf_split(float v, u16& h, u16& l) {
  unsigned u = __float_as_uint(v);
  h = (u16)(u >> 16);
  float hf = __uint_as_float(u & 0xffff0000u);
  float r = v - hf;
  unsigned ur = __float_as_uint(r);
  ur += 0x7fffu + ((ur >> 16) & 1u);
  l = (u16)(ur >> 16);
}

__device__ inline float4 cvt_h4(uint2 r) {
  float2 a = __half22float2(*(__half2*)&r.x);
  float2 b = __half22float2(*(__half2*)&r.y);
  return make_float4(a.x, a.y, b.x, b.y);
}
__device__ inline float2 cvt_h2(unsigned r) { return __half22float2(*(__half2*)&r); }

__device__ inline void st_out(float* p, float v) { *p = v; }
__device__ inline void st_out(u16* p, float v) { *p = __half_as_ushort(__float2half(v)); }

// ---------------- column stats (sum, sumsq); X stride == F ----------------
__global__ void col_stats_kernel(const float* __restrict__ X, float* __restrict__ sums,
                                 int N, int F, int rowsPer) {
  int c = threadIdx.x;
  if (c >= F) return;
  int r0 = blockIdx.x * rowsPer;
  int r1 = min(N, r0 + rowsPer);
  float s = 0.f, sq = 0.f;
  for (int r = r0; r < r1; ++r) {
    float v = X[(size_t)r * F + c];
    s += v; sq += v * v;
  }
  atomicAdd(&sums[c], s);
  atomicAdd(&sums[512 + c], sq);
}

// ---------------- BN apply -> fp32 (BN2) ----------------
__global__ void bn_apply_kernel(const float* __restrict__ X, float* __restrict__ Y,
                                const float* __restrict__ sums,
                                const float* __restrict__ g, const float* __restrict__ b,
                                int N, int F, int outW, int rowsPer, int relu) {
  int c = threadIdx.x;
  if (c >= outW) return;
  float sc = 0.f, bb = 0.f;
  if (c < F) {
    float invN = 1.f / (float)N;
    float mu = sums[c] * invN;
    float var = sums[512 + c] * invN - mu * mu;
    sc = g[c] * rsqrtf(var + EPSF);
    bb = b[c] - mu * sc;
  }
  int r0 = blockIdx.x * rowsPer, r1 = min(N, r0 + rowsPer);
  for (int r = r0; r < r1; ++r) {
    float v = (c < F) ? X[(size_t)r * F + c] * sc + bb : 0.f;
    if (relu) v = fmaxf(v, 0.f);
    Y[(size_t)r * outW + c] = v;
  }
}

// ---------------- BN apply -> split bf16 hi/lo planes (BN0, BN1) ----------------
__global__ void bn_split_kernel(const float* __restrict__ X,
                                u16* __restrict__ Yhi, u16* __restrict__ Ylo,
                                const float* __restrict__ sums,
                                const float* __restrict__ g, const float* __restrict__ b,
                                int N, int F, int outW, int rowsPer, int relu) {
  int c = threadIdx.x;
  if (c >= outW) return;
  float sc = 0.f, bb = 0.f;
  if (c < F) {
    float invN = 1.f / (float)N;
    float mu = sums[c] * invN;
    float var = sums[512 + c] * invN - mu * mu;
    sc = g[c] * rsqrtf(var + EPSF);
    bb = b[c] - mu * sc;
  }
  int r0 = blockIdx.x * rowsPer, r1 = min(N, r0 + rowsPer);
  for (int r = r0; r < r1; ++r) {
    float v = (c < F) ? X[(size_t)r * F + c] * sc + bb : 0.f;
    if (relu) v = fmaxf(v, 0.f);
    u16 h, l;
    bf_split(v, h, l);
    Yhi[(size_t)r * outW + c] = h;
    Ylo[(size_t)r * outW + c] = l;
  }
}

// ---------------- weights: transpose + concat + pad + split -> [2M][Kp] bf16 hi/lo ----------------
__global__ void wt_split_kernel(const float* __restrict__ Wa, const float* __restrict__ Wb,
                                u16* __restrict__ Whi, u16* __restrict__ Wlo,
                                int K, int Kp, int M) {
  int idx = blockIdx.x * blockDim.x + threadIdx.x;
  if (idx >= 2 * M * Kp) return;
  int col = idx / Kp;
  int k = idx - col * Kp;
  float v = 0.f;
  if (k < K) v = (col < M) ? Wa[(size_t)k * M + col] : Wb[(size_t)k * M + (col - M)];
  u16 h, l;
  bf_split(v, h, l);
  Whi[idx] = h;
  Wlo[idx] = l;
}

// ---------------- split-bf16 MFMA GEMM: C(NxMout) = (Ahi+Alo)(Whi+Wlo)^T ----------------
template <typename OutT>
__global__ __launch_bounds__(256) void gemm_mfma(
    const u16* __restrict__ Ahi, const u16* __restrict__ Alo,
    const u16* __restrict__ Bhi, const u16* __restrict__ Blo,
    OutT* __restrict__ C, int N, int Kp, int ldc) {
  __shared__ u16 sAh[128 * 40], sAl[128 * 40], sBh[128 * 40], sBl[128 * 40];
  int tid = threadIdx.x;
  int brow = blockIdx.x * 128, bcol = blockIdx.y * 128;
  int stR = tid >> 1;
  int stC0 = (tid & 1) * 2;
  bool aok = (brow + stR) < N;
  const u16* pAh = Ahi + (size_t)(brow + stR) * Kp + stC0 * 8;
  const u16* pAl = Alo + (size_t)(brow + stR) * Kp + stC0 * 8;
  const u16* pBh = Bhi + (size_t)(bcol + stR) * Kp + stC0 * 8;
  const u16* pBl = Blo + (size_t)(bcol + stR) * Kp + stC0 * 8;
  const uint4 Z = make_uint4(0u, 0u, 0u, 0u);
  uint4 rah0 = aok ? *(const uint4*)(pAh) : Z;
  uint4 rah1 = aok ? *(const uint4*)(pAh + 8) : Z;
  uint4 ral0 = aok ? *(const uint4*)(pAl) : Z;
  uint4 ral1 = aok ? *(const uint4*)(pAl + 8) : Z;
  uint4 rbh0 = *(const uint4*)(pBh);
  uint4 rbh1 = *(const uint4*)(pBh + 8);
  uint4 rbl0 = *(const uint4*)(pBl);
  uint4 rbl1 = *(const uint4*)(pBl + 8);
  f32x4 acc[4][4] = {};
  int lane = tid & 63;
  int wv = tid >> 6, wr = wv >> 1, wc = wv & 1;
  int fr = lane & 15, kch = (lane >> 4) * 8;
  int ldsw = stR * 40 + stC0 * 8;
  for (int k0 = 0;;) {
    __syncthreads();
    *(uint4*)&sAh[ldsw] = rah0; *(uint4*)&sAh[ldsw + 8] = rah1;
    *(uint4*)&sAl[ldsw] = ral0; *(uint4*)&sAl[ldsw + 8] = ral1;
    *(uint4*)&sBh[ldsw] = rbh0; *(uint4*)&sBh[ldsw + 8] = rbh1;
    *(uint4*)&sBl[ldsw] = rbl0; *(uint4*)&sBl[ldsw + 8] = rbl1;
    __syncthreads();
    int kn = k0 + 32;
    if (kn < Kp) {  // prefetch next k-slab under the MFMA body
      rah0 = aok ? *(const uint4*)(pAh + kn) : Z;
      rah1 = aok ? *(const uint4*)(pAh + kn + 8) : Z;
      ral0 = aok ? *(const uint4*)(pAl + kn) : Z;
      ral1 = aok ? *(const uint4*)(pAl + kn + 8) : Z;
      rbh0 = *(const uint4*)(pBh + kn);
      rbh1 = *(const uint4*)(pBh + kn + 8);
      rbl0 = *(const uint4*)(pBl + kn);
      rbl1 = *(const uint4*)(pBl + kn + 8);
    }
    bf16x8s afh[4], afl[4], bfh[4], bfl[4];
#pragma unroll
    for (int i = 0; i < 4; ++i) {
      int ai = (wr * 64 + i * 16 + fr) * 40 + kch;
      afh[i] = *(const bf16x8s*)&sAh[ai];
      afl[i] = *(const bf16x8s*)&sAl[ai];
      int bi = (wc * 64 + i * 16 + fr) * 40 + kch;
      bfh[i] = *(const bf16x8s*)&sBh[bi];
      bfl[i] = *(const bf16x8s*)&sBl[bi];
    }
#pragma unroll
    for (int i = 0; i < 4; ++i)
#pragma unroll
      for (int j = 0; j < 4; ++j) {
        acc[i][j] = __builtin_amdgcn_mfma_f32_16x16x32_bf16(afh[i], bfh[j], acc[i][j], 0, 0, 0);
        acc[i][j] = __builtin_amdgcn_mfma_f32_16x16x32_bf16(afh[i], bfl[j], acc[i][j], 0, 0, 0);
        acc[i][j] = __builtin_amdgcn_mfma_f32_16x16x32_bf16(afl[i], bfh[j], acc[i][j], 0, 0, 0);
      }
    k0 = kn;
    if (k0 >= Kp) break;
  }
#pragma unroll
  for (int i = 0; i < 4; ++i) {
    int growb = brow + wr * 64 + i * 16 + (lane >> 4) * 4;
#pragma unroll
    for (int j = 0; j < 4; ++j) {
      int gcol = bcol + wc * 64 + j * 16 + fr;
#pragma unroll
      for (int r = 0; r < 4; ++r) {
        int grow = growb + r;
        if (grow < N) st_out(&C[(size_t)grow * ldc + gcol], acc[i][j][r]);
      }
    }
  }
}

// ---------------- CSR build ----------------
__global__ void count_kernel(const int* __restrict__ dst, int* __restrict__ cnt, int E) {
  int e = blockIdx.x * blockDim.x + threadIdx.x;
  if (e < E) atomicAdd(&cnt[dst[e]], 1);
}

__global__ void scan_blk_kernel(const int* __restrict__ cnt, int* __restrict__ row_ptr,
                                int* __restrict__ bsum, int N) {
  __shared__ int lds[1024];
  int tid = threadIdx.x;
  int i = blockIdx.x * 1024 + tid;
  int v = (i < N) ? cnt[i] : 0;
  lds[tid] = v;
  __syncthreads();
  for (int o = 1; o < 1024; o <<= 1) {
    int t = (tid >= o) ? lds[tid - o] : 0;
    __syncthreads();
    lds[tid] += t;
    __syncthreads();
  }
  if (i < N) row_ptr[i] = lds[tid] - v;
  if (tid == 1023) bsum[blockIdx.x] = lds[1023];
}

__global__ void scan_kernel(const int* __restrict__ cnt, int* __restrict__ row_ptr, int N) {
  __shared__ int lds[1024];
  __shared__ int carry;
  int tid = threadIdx.x;
  if (tid == 0) carry = 0;
  __syncthreads();
  for (int base = 0; base < N; base += 1024) {
    int i = base + tid;
    int v = (i < N) ? cnt[i] : 0;
    lds[tid] = v;
    __syncthreads();
    for (int o = 1; o < 1024; o <<= 1) {
      int t = (tid >= o) ? lds[tid - o] : 0;
      __syncthreads();
      lds[tid] += t;
      __syncthreads();
    }
    int incl = lds[tid];
    if (i < N) row_ptr[i] = carry + incl - v;
    __syncthreads();
    if (tid == 1023) carry += incl;
    __syncthreads();
  }
  if (tid == 0) row_ptr[N] = carry;
}

__global__ void scan_add_kernel(int* __restrict__ row_ptr, const int* __restrict__ bexc,
                                int N, int nb) {
  int i = blockIdx.x * blockDim.x + threadIdx.x;
  if (i < N) row_ptr[i] += bexc[i >> 10];
  if (i == 0) row_ptr[N] = bexc[nb];
}

__global__ void copyint_kernel(const int* __restrict__ src, int* __restrict__ dst, int N) {
  int i = blockIdx.x * blockDim.x + threadIdx.x;
  if (i < N) dst[i] = src[i];
}

// edge records in CSR order: {src, ea0_bits, ea1_bits, 0}
__global__ void scatter_rec_kernel(const int* __restrict__ dst, const int* __restrict__ src,
                                   const float* __restrict__ ea, int* __restrict__ fill,
                                   int4* __restrict__ recs, int E) {
  int e = blockIdx.x * blockDim.x + threadIdx.x;
  if (e < E) {
    int p = atomicAdd(&fill[dst[e]], 1);
    int4 r;
    r.x = src[e];
    r.y = __float_as_int(ea[2 * (size_t)e]);
    r.z = __float_as_int(ea[2 * (size_t)e + 1]);
    r.w = 0;
    recs[p] = r;
  }
}

// ---------------- GATv2 layer 1: H=2, D=256 (fp16 xlr), one WAVE per node ----------------
// Edge records (sequential 16B) + 4-edge batched consume: 4 interleaved shfl chains.
struct Edge1 { uint2 raw; float e0, e1; };

__global__ __launch_bounds__(256) void gat1_kernel(
    const u16* __restrict__ xl, const u16* __restrict__ xr, int ldx,
    const int4* __restrict__ recs, const int* __restrict__ row_ptr,
    const float* __restrict__ We, const float* __restrict__ att,
    const float* __restrict__ bias, float* __restrict__ out, int Nn) {
  int n = __builtin_amdgcn_readfirstlane(blockIdx.x * 4 + (threadIdx.x >> 6));
  if (n >= Nn) return;
  int lane = threadIdx.x & 63;
  int c4 = lane * 4;
  const float4 we0 = *(const float4*)(We + c4);
  const float4 we1 = *(const float4*)(We + 256 + c4);
  const float4 at4 = *(const float4*)(att + c4);
  const float4 xr4 = cvt_h4(*(const uint2*)(xr + (size_t)n * ldx + c4));
  int start = row_ptr[n];
  int deg = row_ptr[n + 1] - start;
  float4 acc = {0.f, 0.f, 0.f, 0.f};
  float sacc = 0.f;

  auto lde = [&](int i) {
    int4 r = recs[start + i];
    Edge1 t;
    int sv = __builtin_amdgcn_readfirstlane(r.x);
    t.e0 = __int_as_float(r.y);
    t.e1 = __int_as_float(r.z);
    t.raw = *(const uint2*)(xl + (size_t)sv * ldx + c4);
    return t;
  };
  auto zpart = [&](const Edge1& t) {
    float4 xc = cvt_h4(t.raw);
    float zx = xc.x + xr4.x + t.e0 * we0.x + t.e1 * we1.x;
    float zy = xc.y + xr4.y + t.e0 * we0.y + t.e1 * we1.y;
    float zz = xc.z + xr4.z + t.e0 * we0.z + t.e1 * we1.z;
    float zw = xc.w + xr4.w + t.e0 * we0.w + t.e1 * we1.w;
    zx = (zx > 0.f) ? zx : 0.2f * zx;
    zy = (zy > 0.f) ? zy : 0.2f * zy;
    zz = (zz > 0.f) ? zz : 0.2f * zz;
    zw = (zw > 0.f) ? zw : 0.2f * zw;
    return zx * at4.x + zy * at4.y + zz * at4.z + zw * at4.w;
  };
  auto accum = [&](const Edge1& t, float p) {
    float4 xc = cvt_h4(t.raw);
    acc.x += p * xc.x;
    acc.y += p * xc.y;
    acc.z += p * xc.z;
    acc.w += p * xc.w;
    sacc += p;
  };

  int full = deg & ~3;
  if (full >= 4) {
    Edge1 A = lde(0), B = lde(1), C = lde(2), D = lde(3);
    int j = 0;
    while (j + 8 <= full) {
      Edge1 nA = lde(j + 4), nB = lde(j + 5), nC = lde(j + 6), nD = lde(j + 7);
      float p0 = zpart(A), p1 = zpart(B), p2 = zpart(C), p3 = zpart(D);
#pragma unroll
      for (int o = 16; o > 0; o >>= 1) {
        p0 += __shfl_xor(p0, o, 32);
        p1 += __shfl_xor(p1, o, 32);
        p2 += __shfl_xor(p2, o, 32);
        p3 += __shfl_xor(p3, o, 32);
      }
      p0 = __expf(p0); p1 = __expf(p1); p2 = __expf(p2); p3 = __expf(p3);
      accum(A, p0); accum(B, p1); accum(C, p2); accum(D, p3);
      A = nA; B = nB; C = nC; D = nD;
      j += 4;
    }
    float p0 = zpart(A), p1 = zpart(B), p2 = zpart(C), p3 = zpart(D);
#pragma unroll
    for (int o = 16; o > 0; o >>= 1) {
      p0 += __shfl_xor(p0, o, 32);
      p1 += __shfl_xor(p1, o, 32);
      p2 += __shfl_xor(p2, o, 32);
      p3 += __shfl_xor(p3, o, 32);
    }
    p0 = __expf(p0); p1 = __expf(p1); p2 = __expf(p2); p3 = __expf(p3);
    accum(A, p0); accum(B, p1); accum(C, p2); accum(D, p3);
  }
  for (int t = full; t < deg; ++t) {
    Edge1 T = lde(t);
    float p = zpart(T);
#pragma unroll
    for (int o = 16; o > 0; o >>= 1) p += __shfl_xor(p, o, 32);
    accum(T, __expf(p));
  }

  float inv = 1.f / ((sacc + 1e-16f) * (float)(deg > 0 ? deg : 1));
  float4 o4;
  o4.x = acc.x * inv + bias[c4];
  o4.y = acc.y * inv + bias[c4 + 1];
  o4.z = acc.z * inv + bias[c4 + 2];
  o4.w = acc.w * inv + bias[c4 + 3];
  *(float4*)(out + (size_t)n * 256 + c4) = o4;
}

// ---------------- GATv2 layer 2: H=1, D=128 (fp16 xlr), one WAVE per node ----------------
struct Edge2 { unsigned raw; float e0, e1; };

__global__ __launch_bounds__(256) void gat2_kernel(
    const u16* __restrict__ xl, const u16* __restrict__ xr, int ldx,
    const int4* __restrict__ recs, const int* __restrict__ row_ptr,
    const float* __restrict__ We, const float* __restrict__ att,
    const float* __restrict__ bias, float* __restrict__ out, int Nn) {
  int n = __builtin_amdgcn_readfirstlane(blockIdx.x * 4 + (threadIdx.x >> 6));
  if (n >= Nn) return;
  int lane = threadIdx.x & 63;
  int c2 = lane * 2;
  const float2 we0 = *(const float2*)(We + c2);
  const float2 we1 = *(const float2*)(We + 128 + c2);
  const float2 at2 = *(const float2*)(att + c2);
  const float2 xr2 = cvt_h2(*(const unsigned*)(xr + (size_t)n * ldx + c2));
  int start = row_ptr[n];
  int deg = row_ptr[n + 1] - start;
  float2 acc = {0.f, 0.f};
  float sacc = 0.f;

  auto lde = [&](int i) {
    int4 r = recs[start + i];
    Edge2 t;
    int sv = __builtin_amdgcn_readfirstlane(r.x);
    t.e0 = __int_as_float(r.y);
    t.e1 = __int_as_float(r.z);
    t.raw = *(const unsigned*)(xl + (size_t)sv * ldx + c2);
    return t;
  };
  auto zpart = [&](const Edge2& t) {
    float2 xc = cvt_h2(t.raw);
    float zx = xc.x + xr2.x + t.e0 * we0.x + t.e1 * we1.x;
    float zy = xc.y + xr2.y + t.e0 * we0.y + t.e1 * we1.y;
    zx = (zx > 0.f) ? zx : 0.2f * zx;
    zy = (zy > 0.f) ? zy : 0.2f * zy;
    return zx * at2.x + zy * at2.y;
  };
  auto accum = [&](const Edge2& t, float p) {
    float2 xc = cvt_h2(t.raw);
    acc.x += p * xc.x;
    acc.y += p * xc.y;
    sacc += p;
  };

  int full = deg & ~3;
  if (full >= 4) {
    Edge2 A = lde(0), B = lde(1), C = lde(2), D = lde(3);
    int j = 0;
    while (j + 8 <= full) {
      Edge2 nA = lde(j + 4), nB = lde(j + 5), nC = lde(j + 6), nD = lde(j + 7);
      float p0 = zpart(A), p1 = zpart(B), p2 = zpart(C), p3 = zpart(D);
#pragma unroll
      for (int o = 32; o > 0; o >>= 1) {
        p0 += __shfl_xor(p0, o);
        p1 += __shfl_xor(p1, o);
        p2 += __shfl_xor(p2, o);
        p3 += __shfl_xor(p3, o);
      }
      p0 = __expf(p0); p1 = __expf(p1); p2 = __expf(p2); p3 = __expf(p3);
      accum(A, p0); accum(B, p1); accum(C, p2); accum(D, p3);
      A = nA; B = nB; C = nC; D = nD;
      j += 4;
    }
    float p0 = zpart(A), p1 = zpart(B), p2 = zpart(C), p3 = zpart(D);
#pragma unroll
    for (int o = 32; o > 0; o >>= 1) {
      p0 += __shfl_xor(p0, o);
      p1 += __shfl_xor(p1, o);
      p2 += __shfl_xor(p2, o);
      p3 += __shfl_xor(p3, o);
    }
    p0 = __expf(p0); p1 = __expf(p1); p2 = __expf(p2); p3 = __expf(p3);
    accum(A, p0); accum(B, p1); accum(C, p2); accum(D, p3);
  }
  for (int t = full; t < deg; ++t) {
    Edge2 T = lde(t);
    float p = zpart(T);
#pragma unroll
    for (int o = 32; o > 0; o >>= 1) p += __shfl_xor(p, o);
    accum(T, __expf(p));
  }

  float inv = 1.f / ((sacc + 1e-16f) * (float)(deg > 0 ? deg : 1));
  float2 o2;
  o2.x = acc.x * inv + bias[c2];
  o2.y = acc.y * inv + bias[c2 + 1];
  *(float2*)(out + (size_t)n * 128 + c2) = o2;
}

// ---------------- layer-3 (ch=1): one wave per node, edge-parallel lanes ----------------
__global__ void gat3_kernel(const float* __restrict__ xl, const float* __restrict__ xr,
                            const int4* __restrict__ recs, const int* __restrict__ row_ptr,
                            const float* __restrict__ We, const float* __restrict__ att,
                            const float* __restrict__ bias, float* __restrict__ out, int Nn) {
  int n = blockIdx.x * 4 + (threadIdx.x >> 6);
  int lane = threadIdx.x & 63;
  if (n >= Nn) return;
  float we0 = We[0], we1 = We[1], a = att[0];
  float xr_n = xr[n];
  int s0 = row_ptr[n], s1 = row_ptr[n + 1];
  float accp = 0.f, accs = 0.f;
  for (int i = s0 + lane; i < s1; i += 64) {
    int4 r = recs[i];
    float xls = xl[r.x];
    float z = xls + xr_n + __int_as_float(r.y) * we0 + __int_as_float(r.z) * we1;
    z = (z > 0.f) ? z : 0.2f * z;
    float p = __expf(z * a);
    accp += p * xls;
    accs += p;
  }
#pragma unroll
  for (int o = 32; o > 0; o >>= 1) {
    accp += __shfl_xor(accp, o);
    accs += __shfl_xor(accs, o);
  }
  int deg = s1 - s0;
  if (lane == 0) out[n] = accp / ((accs + 1e-16f) * (float)(deg > 0 ? deg : 1)) + bias[0];
}

// ---------------- row dot: out[n] = A[n,:K] . w ----------------
__global__ void rowdot_kernel(const float* __restrict__ A, const float* __restrict__ w,
                              float* __restrict__ out, int Nn, int K) {
  int n = blockIdx.x * 4 + (threadIdx.x >> 6);
  int lane = threadIdx.x & 63;
  if (n >= Nn) return;
  float p = 0.f;
  for (int k = lane; k < K; k += 64) p += A[(size_t)n * K + k] * w[k];
#pragma unroll
  for (int o = 32; o > 0; o >>= 1) p += __shfl_xor(p, o);
  if (lane == 0) out[n] = p;
}

extern "C" void kernel_launch(void* const* d_in, const int* in_sizes, int n_in,
                              void* d_out, int out_size, void* d_ws, size_t ws_size,
                              hipStream_t stream) {
  const float* x     = (const float*)d_in[0];
  const int*   ei    = (const int*)d_in[1];
  const float* ea    = (const float*)d_in[2];
  const float* bn0_g = (const float*)d_in[3];
  const float* bn0_b = (const float*)d_in[4];
  const float* Wl1   = (const float*)d_in[5];
  const float* Wr1   = (const float*)d_in[6];
  const float* We1   = (const float*)d_in[7];
  const float* att1  = (const float*)d_in[8];
  const float* b1    = (const float*)d_in[9];
  const float* bn1_g = (const float*)d_in[10];
  const float* bn1_b = (const float*)d_in[11];
  const float* Wl2   = (const float*)d_in[12];
  const float* Wr2   = (const float*)d_in[13];
  const float* We2   = (const float*)d_in[14];
  const float* att2  = (const float*)d_in[15];
  const float* b2    = (const float*)d_in[16];
  const float* bn2_g = (const float*)d_in[17];
  const float* bn2_b = (const float*)d_in[18];
  const float* Wl3   = (const float*)d_in[19];
  const float* Wr3   = (const float*)d_in[20];
  const float* We3   = (const float*)d_in[21];
  const float* att3  = (const float*)d_in[22];
  const float* b3    = (const float*)d_in[23];

  const int F = 301;
  const int Kp1 = 320;
  const int N = in_sizes[0] / F;
  const int E = in_sizes[1] / 2;
  const int* srcv = ei;
  const int* dstv = ei + E;

  // ---- workspace layout, regions time-shared ----
  float* fws = (float*)d_ws;
  float* RA = fws;                              // N*320 f
  float* RB = RA + (size_t)N * 320;             // N*384 f
  float* stats = RB + (size_t)N * 384;          // 1024
  u16* wt1h = (u16*)(stats + 1024);             // 512*320
  u16* wt1l = wt1h + (size_t)512 * 320;
  u16* wt2h = wt1l + (size_t)512 * 320;         // 256*256
  u16* wt2l = wt2h + (size_t)256 * 256;
  float* xl3 = (float*)(wt2l + (size_t)256 * 256);
  float* xr3 = xl3 + N;
  char* pi = (char*)(xr3 + N);
  pi += (16 - ((size_t)pi & 15)) & 15;          // 16B-align records
  int4* recs = (int4*)pi;                       // E records
  int* row_ptr = (int*)(recs + E);              // N+1
  int* fill    = row_ptr + (N + 1);             // N
  int* bsum    = fill + N;                      // nb (<=64)
  int* bexc    = bsum + 64;                     // nb+1

  // region aliases along the timeline
  u16* Ahi = (u16*)RA;                          // N x 320 bf16
  u16* Alo = Ahi + (size_t)N * Kp1;
  u16* xlr1 = (u16*)RB;                         // N x 512 fp16 (xl1 | xr1)
  float* g1out = RA;                            // N x 256 f (gat1 out)
  u16* h1h = (u16*)RB;                          // N x 256 bf16
  u16* h1l = h1h + (size_t)N * 256;
  u16* xlr2 = h1l + (size_t)N * 256;            // N x 256 fp16 (xl2 | xr2)
  float* g2out = RA;                            // N x 128 f
  float* h2 = RA + (size_t)N * 128;             // N x 128 f

  // ---- CSR by dst (parallel 3-phase scan), edge records ----
  int nb = cdiv(N, 1024);
  hipMemsetAsync(fill, 0, (size_t)N * sizeof(int), stream);
  count_kernel<<<cdiv(E, 256), 256, 0, stream>>>(dstv, fill, E);
  scan_blk_kernel<<<nb, 1024, 0, stream>>>(fill, row_ptr, bsum, N);
  scan_kernel<<<1, 1024, 0, stream>>>(bsum, bexc, nb);
  scan_add_kernel<<<cdiv(N, 256), 256, 0, stream>>>(row_ptr, bexc, N, nb);
  copyint_kernel<<<cdiv(N, 256), 256, 0, stream>>>(row_ptr, fill, N);
  scatter_rec_kernel<<<cdiv(E, 256), 256, 0, stream>>>(dstv, srcv, ea, fill, recs, E);

  // ---- weight prep ----
  wt_split_kernel<<<cdiv(512 * Kp1, 256), 256, 0, stream>>>(Wl1, Wr1, wt1h, wt1l, F, Kp1, 256);
  wt_split_kernel<<<cdiv(256 * 256, 256), 256, 0, stream>>>(Wl2, Wr2, wt2h, wt2l, 256, 256, 128);

  int rows = cdiv(N, 256);

  // ---- BN0 -> split bf16 A planes ----
  hipMemsetAsync(stats, 0, 1024 * sizeof(float), stream);
  col_stats_kernel<<<256, 320, 0, stream>>>(x, stats, N, F, rows);
  bn_split_kernel<<<256, 320, 0, stream>>>(x, Ahi, Alo, stats, bn0_g, bn0_b, N, F, Kp1, rows, 0);

  // ---- layer 1: fused [xl|xr] MFMA GEMM (fp16 out) + edge pass ----
  gemm_mfma<u16><<<dim3(cdiv(N, 128), 4), 256, 0, stream>>>(Ahi, Alo, wt1h, wt1l, xlr1, N, Kp1, 512);
  gat1_kernel<<<cdiv(N, 4), 256, 0, stream>>>(xlr1, xlr1 + 256, 512, recs, row_ptr,
                                              We1, att1, b1, g1out, N);
  // ---- BN1 + relu -> split bf16 h1 planes ----
  hipMemsetAsync(stats, 0, 1024 * sizeof(float), stream);
  col_stats_kernel<<<256, 256, 0, stream>>>(g1out, stats, N, 256, rows);
  bn_split_kernel<<<256, 256, 0, stream>>>(g1out, h1h, h1l, stats, bn1_g, bn1_b, N, 256, 256, rows, 1);

  // ---- layer 2: fused [xl|xr] MFMA GEMM (fp16 out) + edge pass ----
  gemm_mfma<u16><<<dim3(cdiv(N, 128), 2), 256, 0, stream>>>(h1h, h1l, wt2h, wt2l, xlr2, N, 256, 256);
  gat2_kernel<<<cdiv(N, 4), 256, 0, stream>>>(xlr2, xlr2 + 128, 256, recs, row_ptr,
                                              We2, att2, b2, g2out, N);
  // ---- BN2 + relu -> fp32 h2 ----
  hipMemsetAsync(stats, 0, 1024 * sizeof(float), stream);
  col_stats_kernel<<<256, 128, 0, stream>>>(g2out, stats, N, 128, rows);
  bn_apply_kernel<<<256, 128, 0, stream>>>(g2out, h2, stats, bn2_g, bn2_b, N, 128, 128, rows, 1);

  // ---- layer 3 (ch=1) ----
  rowdot_kernel<<<cdiv(N, 4), 256, 0, stream>>>(h2, Wl3, xl3, N, 128);
  rowdot_kernel<<<cdiv(N, 4), 256, 0, stream>>>(h2, Wr3, xr3, N, 128);
  gat3_kernel<<<cdiv(N, 4), 256, 0, stream>>>(xl3, xr3, recs, row_ptr,
                                              We3, att3, b3, (float*)d_out, N);
}

// Round 8
// 586.304 us; speedup vs baseline: 3.1179x; 1.2538x over previous
//
#include <hip/hip_runtime.h>
#include <hip/hip_fp16.h>

#define EPSF 1e-5f
#define GRID_BN 1024

typedef unsigned short u16;
typedef __attribute__((ext_vector_type(8))) short bf16x8s;  // 8 bf16 (4 VGPRs)
typedef __attribute__((ext_vector_type(4))) float f32x4;

static inline int cdiv(int a, int b) { return (a + b - 1) / b; }

// split v into hi (bit-truncated bf16) + lo (round-nearest bf16 of remainder)
__device__ inline void bf_split(float v, u16& h, u16& l) {
  unsigned u = __float_as_uint(v);
  h = (u16)(u >> 16);
  float hf = __uint_as_float(u & 0xffff0000u);
  float r = v - hf;
  unsigned ur = __float_as_uint(r);
  ur += 0x7fffu + ((ur >> 16) & 1u);
  l = (u16)(ur >> 16);
}

__device__ inline float4 cvt_h4(uint2 r) {
  float2 a = __half22float2(*(__half2*)&r.x);
  float2 b = __half22float2(*(__half2*)&r.y);
  return make_float4(a.x, a.y, b.x, b.y);
}
__device__ inline float2 cvt_h2(unsigned r) { return __half22float2(*(__half2*)&r); }

__device__ inline void st_out(float* p, float v) { *p = v; }
__device__ inline void st_out(u16* p, float v) { *p = __half_as_ushort(__float2half(v)); }

// ---------------- column stats (sum, sumsq); X stride == F ----------------
__global__ void col_stats_kernel(const float* __restrict__ X, float* __restrict__ sums,
                                 int N, int F, int rowsPer) {
  int c = threadIdx.x;
  if (c >= F) return;
  int r0 = blockIdx.x * rowsPer;
  int r1 = min(N, r0 + rowsPer);
  float s = 0.f, sq = 0.f;
  for (int r = r0; r < r1; ++r) {
    float v = X[(size_t)r * F + c];
    s += v; sq += v * v;
  }
  atomicAdd(&sums[c], s);
  atomicAdd(&sums[512 + c], sq);
}

// ---------------- BN apply -> fp32 (BN2) ----------------
__global__ void bn_apply_kernel(const float* __restrict__ X, float* __restrict__ Y,
                                const float* __restrict__ sums,
                                const float* __restrict__ g, const float* __restrict__ b,
                                int N, int F, int outW, int rowsPer, int relu) {
  int c = threadIdx.x;
  if (c >= outW) return;
  float sc = 0.f, bb = 0.f;
  if (c < F) {
    float invN = 1.f / (float)N;
    float mu = sums[c] * invN;
    float var = sums[512 + c] * invN - mu * mu;
    sc = g[c] * rsqrtf(var + EPSF);
    bb = b[c] - mu * sc;
  }
  int r0 = blockIdx.x * rowsPer, r1 = min(N, r0 + rowsPer);
  for (int r = r0; r < r1; ++r) {
    float v = (c < F) ? X[(size_t)r * F + c] * sc + bb : 0.f;
    if (relu) v = fmaxf(v, 0.f);
    Y[(size_t)r * outW + c] = v;
  }
}

// ---------------- BN apply -> split bf16 hi/lo planes (BN0, BN1) ----------------
__global__ void bn_split_kernel(const float* __restrict__ X,
                                u16* __restrict__ Yhi, u16* __restrict__ Ylo,
                                const float* __restrict__ sums,
                                const float* __restrict__ g, const float* __restrict__ b,
                                int N, int F, int outW, int rowsPer, int relu) {
  int c = threadIdx.x;
  if (c >= outW) return;
  float sc = 0.f, bb = 0.f;
  if (c < F) {
    float invN = 1.f / (float)N;
    float mu = sums[c] * invN;
    float var = sums[512 + c] * invN - mu * mu;
    sc = g[c] * rsqrtf(var + EPSF);
    bb = b[c] - mu * sc;
  }
  int r0 = blockIdx.x * rowsPer, r1 = min(N, r0 + rowsPer);
  for (int r = r0; r < r1; ++r) {
    float v = (c < F) ? X[(size_t)r * F + c] * sc + bb : 0.f;
    if (relu) v = fmaxf(v, 0.f);
    u16 h, l;
    bf_split(v, h, l);
    Yhi[(size_t)r * outW + c] = h;
    Ylo[(size_t)r * outW + c] = l;
  }
}

// ---------------- weights: transpose + concat + pad + split -> [2M][Kp] bf16 hi/lo ----------------
__global__ void wt_split_kernel(const float* __restrict__ Wa, const float* __restrict__ Wb,
                                u16* __restrict__ Whi, u16* __restrict__ Wlo,
                                int K, int Kp, int M) {
  int idx = blockIdx.x * blockDim.x + threadIdx.x;
  if (idx >= 2 * M * Kp) return;
  int col = idx / Kp;
  int k = idx - col * Kp;
  float v = 0.f;
  if (k < K) v = (col < M) ? Wa[(size_t)k * M + col] : Wb[(size_t)k * M + (col - M)];
  u16 h, l;
  bf_split(v, h, l);
  Whi[idx] = h;
  Wlo[idx] = l;
}

// ---------------- split-bf16 MFMA GEMM: C(NxMout) = (Ahi+Alo)(Whi+Wlo)^T ----------------
template <typename OutT>
__global__ __launch_bounds__(256) void gemm_mfma(
    const u16* __restrict__ Ahi, const u16* __restrict__ Alo,
    const u16* __restrict__ Bhi, const u16* __restrict__ Blo,
    OutT* __restrict__ C, int N, int Kp, int ldc) {
  __shared__ u16 sAh[128 * 40], sAl[128 * 40], sBh[128 * 40], sBl[128 * 40];
  int tid = threadIdx.x;
  int brow = blockIdx.x * 128, bcol = blockIdx.y * 128;
  int stR = tid >> 1;
  int stC0 = (tid & 1) * 2;
  bool aok = (brow + stR) < N;
  const u16* pAh = Ahi + (size_t)(brow + stR) * Kp + stC0 * 8;
  const u16* pAl = Alo + (size_t)(brow + stR) * Kp + stC0 * 8;
  const u16* pBh = Bhi + (size_t)(bcol + stR) * Kp + stC0 * 8;
  const u16* pBl = Blo + (size_t)(bcol + stR) * Kp + stC0 * 8;
  const uint4 Z = make_uint4(0u, 0u, 0u, 0u);
  uint4 rah0 = aok ? *(const uint4*)(pAh) : Z;
  uint4 rah1 = aok ? *(const uint4*)(pAh + 8) : Z;
  uint4 ral0 = aok ? *(const uint4*)(pAl) : Z;
  uint4 ral1 = aok ? *(const uint4*)(pAl + 8) : Z;
  uint4 rbh0 = *(const uint4*)(pBh);
  uint4 rbh1 = *(const uint4*)(pBh + 8);
  uint4 rbl0 = *(const uint4*)(pBl);
  uint4 rbl1 = *(const uint4*)(pBl + 8);
  f32x4 acc[4][4] = {};
  int lane = tid & 63;
  int wv = tid >> 6, wr = wv >> 1, wc = wv & 1;
  int fr = lane & 15, kch = (lane >> 4) * 8;
  int ldsw = stR * 40 + stC0 * 8;
  for (int k0 = 0;;) {
    __syncthreads();
    *(uint4*)&sAh[ldsw] = rah0; *(uint4*)&sAh[ldsw + 8] = rah1;
    *(uint4*)&sAl[ldsw] = ral0; *(uint4*)&sAl[ldsw + 8] = ral1;
    *(uint4*)&sBh[ldsw] = rbh0; *(uint4*)&sBh[ldsw + 8] = rbh1;
    *(uint4*)&sBl[ldsw] = rbl0; *(uint4*)&sBl[ldsw + 8] = rbl1;
    __syncthreads();
    int kn = k0 + 32;
    if (kn < Kp) {  // prefetch next k-slab under the MFMA body
      rah0 = aok ? *(const uint4*)(pAh + kn) : Z;
      rah1 = aok ? *(const uint4*)(pAh + kn + 8) : Z;
      ral0 = aok ? *(const uint4*)(pAl + kn) : Z;
      ral1 = aok ? *(const uint4*)(pAl + kn + 8) : Z;
      rbh0 = *(const uint4*)(pBh + kn);
      rbh1 = *(const uint4*)(pBh + kn + 8);
      rbl0 = *(const uint4*)(pBl + kn);
      rbl1 = *(const uint4*)(pBl + kn + 8);
    }
    bf16x8s afh[4], afl[4], bfh[4], bfl[4];
#pragma unroll
    for (int i = 0; i < 4; ++i) {
      int ai = (wr * 64 + i * 16 + fr) * 40 + kch;
      afh[i] = *(const bf16x8s*)&sAh[ai];
      afl[i] = *(const bf16x8s*)&sAl[ai];
      int bi = (wc * 64 + i * 16 + fr) * 40 + kch;
      bfh[i] = *(const bf16x8s*)&sBh[bi];
      bfl[i] = *(const bf16x8s*)&sBl[bi];
    }
#pragma unroll
    for (int i = 0; i < 4; ++i)
#pragma unroll
      for (int j = 0; j < 4; ++j) {
        acc[i][j] = __builtin_amdgcn_mfma_f32_16x16x32_bf16(afh[i], bfh[j], acc[i][j], 0, 0, 0);
        acc[i][j] = __builtin_amdgcn_mfma_f32_16x16x32_bf16(afh[i], bfl[j], acc[i][j], 0, 0, 0);
        acc[i][j] = __builtin_amdgcn_mfma_f32_16x16x32_bf16(afl[i], bfh[j], acc[i][j], 0, 0, 0);
      }
    k0 = kn;
    if (k0 >= Kp) break;
  }
#pragma unroll
  for (int i = 0; i < 4; ++i) {
    int growb = brow + wr * 64 + i * 16 + (lane >> 4) * 4;
#pragma unroll
    for (int j = 0; j < 4; ++j) {
      int gcol = bcol + wc * 64 + j * 16 + fr;
#pragma unroll
      for (int r = 0; r < 4; ++r) {
        int grow = growb + r;
        if (grow < N) st_out(&C[(size_t)grow * ldc + gcol], acc[i][j][r]);
      }
    }
  }
}

// ---------------- CSR build ----------------
__global__ void count_kernel(const int* __restrict__ dst, int* __restrict__ cnt, int E) {
  int e = blockIdx.x * blockDim.x + threadIdx.x;
  if (e < E) atomicAdd(&cnt[dst[e]], 1);
}

__global__ void scan_blk_kernel(const int* __restrict__ cnt, int* __restrict__ row_ptr,
                                int* __restrict__ bsum, int N) {
  __shared__ int lds[1024];
  int tid = threadIdx.x;
  int i = blockIdx.x * 1024 + tid;
  int v = (i < N) ? cnt[i] : 0;
  lds[tid] = v;
  __syncthreads();
  for (int o = 1; o < 1024; o <<= 1) {
    int t = (tid >= o) ? lds[tid - o] : 0;
    __syncthreads();
    lds[tid] += t;
    __syncthreads();
  }
  if (i < N) row_ptr[i] = lds[tid] - v;
  if (tid == 1023) bsum[blockIdx.x] = lds[1023];
}

__global__ void scan_kernel(const int* __restrict__ cnt, int* __restrict__ row_ptr, int N) {
  __shared__ int lds[1024];
  __shared__ int carry;
  int tid = threadIdx.x;
  if (tid == 0) carry = 0;
  __syncthreads();
  for (int base = 0; base < N; base += 1024) {
    int i = base + tid;
    int v = (i < N) ? cnt[i] : 0;
    lds[tid] = v;
    __syncthreads();
    for (int o = 1; o < 1024; o <<= 1) {
      int t = (tid >= o) ? lds[tid - o] : 0;
      __syncthreads();
      lds[tid] += t;
      __syncthreads();
    }
    int incl = lds[tid];
    if (i < N) row_ptr[i] = carry + incl - v;
    __syncthreads();
    if (tid == 1023) carry += incl;
    __syncthreads();
  }
  if (tid == 0) row_ptr[N] = carry;
}

__global__ void scan_add_kernel(int* __restrict__ row_ptr, const int* __restrict__ bexc,
                                int N, int nb) {
  int i = blockIdx.x * blockDim.x + threadIdx.x;
  if (i < N) row_ptr[i] += bexc[i >> 10];
  if (i == 0) row_ptr[N] = bexc[nb];
}

__global__ void copyint_kernel(const int* __restrict__ src, int* __restrict__ dst, int N) {
  int i = blockIdx.x * blockDim.x + threadIdx.x;
  if (i < N) dst[i] = src[i];
}

// edge records in CSR order: {src, ea0_bits, ea1_bits, 0}
__global__ void scatter_rec_kernel(const int* __restrict__ dst, const int* __restrict__ src,
                                   const float* __restrict__ ea, int* __restrict__ fill,
                                   int4* __restrict__ recs, int E) {
  int e = blockIdx.x * blockDim.x + threadIdx.x;
  if (e < E) {
    int p = atomicAdd(&fill[dst[e]], 1);
    int4 r;
    r.x = src[e];
    r.y = __float_as_int(ea[2 * (size_t)e]);
    r.z = __float_as_int(ea[2 * (size_t)e + 1]);
    r.w = 0;
    recs[p] = r;
  }
}

// ---------------- GATv2 layer 1: H=2, D=256 (fp16 xlr), one WAVE per node ----------------
// Edge records (sequential 16B) + 4-edge batched consume: 4 interleaved shfl chains.
struct Edge1 { uint2 raw; float e0, e1; };

__global__ __launch_bounds__(256) void gat1_kernel(
    const u16* __restrict__ xl, const u16* __restrict__ xr, int ldx,
    const int4* __restrict__ recs, const int* __restrict__ row_ptr,
    const float* __restrict__ We, const float* __restrict__ att,
    const float* __restrict__ bias, float* __restrict__ out, int Nn) {
  int n = __builtin_amdgcn_readfirstlane(blockIdx.x * 4 + (threadIdx.x >> 6));
  if (n >= Nn) return;
  int lane = threadIdx.x & 63;
  int c4 = lane * 4;
  const float4 we0 = *(const float4*)(We + c4);
  const float4 we1 = *(const float4*)(We + 256 + c4);
  const float4 at4 = *(const float4*)(att + c4);
  const float4 xr4 = cvt_h4(*(const uint2*)(xr + (size_t)n * ldx + c4));
  int start = row_ptr[n];
  int deg = row_ptr[n + 1] - start;
  float4 acc = {0.f, 0.f, 0.f, 0.f};
  float sacc = 0.f;

  auto lde = [&](int i) {
    int4 r = recs[start + i];
    Edge1 t;
    int sv = __builtin_amdgcn_readfirstlane(r.x);
    t.e0 = __int_as_float(r.y);
    t.e1 = __int_as_float(r.z);
    t.raw = *(const uint2*)(xl + (size_t)sv * ldx + c4);
    return t;
  };
  auto zpart = [&](const Edge1& t) {
    float4 xc = cvt_h4(t.raw);
    float zx = xc.x + xr4.x + t.e0 * we0.x + t.e1 * we1.x;
    float zy = xc.y + xr4.y + t.e0 * we0.y + t.e1 * we1.y;
    float zz = xc.z + xr4.z + t.e0 * we0.z + t.e1 * we1.z;
    float zw = xc.w + xr4.w + t.e0 * we0.w + t.e1 * we1.w;
    zx = (zx > 0.f) ? zx : 0.2f * zx;
    zy = (zy > 0.f) ? zy : 0.2f * zy;
    zz = (zz > 0.f) ? zz : 0.2f * zz;
    zw = (zw > 0.f) ? zw : 0.2f * zw;
    return zx * at4.x + zy * at4.y + zz * at4.z + zw * at4.w;
  };
  auto accum = [&](const Edge1& t, float p) {
    float4 xc = cvt_h4(t.raw);
    acc.x += p * xc.x;
    acc.y += p * xc.y;
    acc.z += p * xc.z;
    acc.w += p * xc.w;
    sacc += p;
  };

  int full = deg & ~3;
  if (full >= 4) {
    Edge1 A = lde(0), B = lde(1), C = lde(2), D = lde(3);
    int j = 0;
    while (j + 8 <= full) {
      Edge1 nA = lde(j + 4), nB = lde(j + 5), nC = lde(j + 6), nD = lde(j + 7);
      float p0 = zpart(A), p1 = zpart(B), p2 = zpart(C), p3 = zpart(D);
#pragma unroll
      for (int o = 16; o > 0; o >>= 1) {
        p0 += __shfl_xor(p0, o, 32);
        p1 += __shfl_xor(p1, o, 32);
        p2 += __shfl_xor(p2, o, 32);
        p3 += __shfl_xor(p3, o, 32);
      }
      p0 = __expf(p0); p1 = __expf(p1); p2 = __expf(p2); p3 = __expf(p3);
      accum(A, p0); accum(B, p1); accum(C, p2); accum(D, p3);
      A = nA; B = nB; C = nC; D = nD;
      j += 4;
    }
    float p0 = zpart(A), p1 = zpart(B), p2 = zpart(C), p3 = zpart(D);
#pragma unroll
    for (int o = 16; o > 0; o >>= 1) {
      p0 += __shfl_xor(p0, o, 32);
      p1 += __shfl_xor(p1, o, 32);
      p2 += __shfl_xor(p2, o, 32);
      p3 += __shfl_xor(p3, o, 32);
    }
    p0 = __expf(p0); p1 = __expf(p1); p2 = __expf(p2); p3 = __expf(p3);
    accum(A, p0); accum(B, p1); accum(C, p2); accum(D, p3);
  }
  for (int t = full; t < deg; ++t) {
    Edge1 T = lde(t);
    float p = zpart(T);
#pragma unroll
    for (int o = 16; o > 0; o >>= 1) p += __shfl_xor(p, o, 32);
    accum(T, __expf(p));
  }

  float inv = 1.f / ((sacc + 1e-16f) * (float)(deg > 0 ? deg : 1));
  float4 o4;
  o4.x = acc.x * inv + bias[c4];
  o4.y = acc.y * inv + bias[c4 + 1];
  o4.z = acc.z * inv + bias[c4 + 2];
  o4.w = acc.w * inv + bias[c4 + 3];
  *(float4*)(out + (size_t)n * 256 + c4) = o4;
}

// ---------------- GATv2 layer 2: H=1, D=128 (fp16 xlr), one WAVE per node ----------------
struct Edge2 { unsigned raw; float e0, e1; };

__global__ __launch_bounds__(256) void gat2_kernel(
    const u16* __restrict__ xl, const u16* __restrict__ xr, int ldx,
    const int4* __restrict__ recs, const int* __restrict__ row_ptr,
    const float* __restrict__ We, const float* __restrict__ att,
    const float* __restrict__ bias, float* __restrict__ out, int Nn) {
  int n = __builtin_amdgcn_readfirstlane(blockIdx.x * 4 + (threadIdx.x >> 6));
  if (n >= Nn) return;
  int lane = threadIdx.x & 63;
  int c2 = lane * 2;
  const float2 we0 = *(const float2*)(We + c2);
  const float2 we1 = *(const float2*)(We + 128 + c2);
  const float2 at2 = *(const float2*)(att + c2);
  const float2 xr2 = cvt_h2(*(const unsigned*)(xr + (size_t)n * ldx + c2));
  int start = row_ptr[n];
  int deg = row_ptr[n + 1] - start;
  float2 acc = {0.f, 0.f};
  float sacc = 0.f;

  auto lde = [&](int i) {
    int4 r = recs[start + i];
    Edge2 t;
    int sv = __builtin_amdgcn_readfirstlane(r.x);
    t.e0 = __int_as_float(r.y);
    t.e1 = __int_as_float(r.z);
    t.raw = *(const unsigned*)(xl + (size_t)sv * ldx + c2);
    return t;
  };
  auto zpart = [&](const Edge2& t) {
    float2 xc = cvt_h2(t.raw);
    float zx = xc.x + xr2.x + t.e0 * we0.x + t.e1 * we1.x;
    float zy = xc.y + xr2.y + t.e0 * we0.y + t.e1 * we1.y;
    zx = (zx > 0.f) ? zx : 0.2f * zx;
    zy = (zy > 0.f) ? zy : 0.2f * zy;
    return zx * at2.x + zy * at2.y;
  };
  auto accum = [&](const Edge2& t, float p) {
    float2 xc = cvt_h2(t.raw);
    acc.x += p * xc.x;
    acc.y += p * xc.y;
    sacc += p;
  };

  int full = deg & ~3;
  if (full >= 4) {
    Edge2 A = lde(0), B = lde(1), C = lde(2), D = lde(3);
    int j = 0;
    while (j + 8 <= full) {
      Edge2 nA = lde(j + 4), nB = lde(j + 5), nC = lde(j + 6), nD = lde(j + 7);
      float p0 = zpart(A), p1 = zpart(B), p2 = zpart(C), p3 = zpart(D);
#pragma unroll
      for (int o = 32; o > 0; o >>= 1) {
        p0 += __shfl_xor(p0, o);
        p1 += __shfl_xor(p1, o);
        p2 += __shfl_xor(p2, o);
        p3 += __shfl_xor(p3, o);
      }
      p0 = __expf(p0); p1 = __expf(p1); p2 = __expf(p2); p3 = __expf(p3);
      accum(A, p0); accum(B, p1); accum(C, p2); accum(D, p3);
      A = nA; B = nB; C = nC; D = nD;
      j += 4;
    }
    float p0 = zpart(A), p1 = zpart(B), p2 = zpart(C), p3 = zpart(D);
#pragma unroll
    for (int o = 32; o > 0; o >>= 1) {
      p0 += __shfl_xor(p0, o);
      p1 += __shfl_xor(p1, o);
      p2 += __shfl_xor(p2, o);
      p3 += __shfl_xor(p3, o);
    }
    p0 = __expf(p0); p1 = __expf(p1); p2 = __expf(p2); p3 = __expf(p3);
    accum(A, p0); accum(B, p1); accum(C, p2); accum(D, p3);
  }
  for (int t = full; t < deg; ++t) {
    Edge2 T = lde(t);
    float p = zpart(T);
#pragma unroll
    for (int o = 32; o > 0; o >>= 1) p += __shfl_xor(p, o);
    accum(T, __expf(p));
  }

  float inv = 1.f / ((sacc + 1e-16f) * (float)(deg > 0 ? deg : 1));
  float2 o2;
  o2.x = acc.x * inv + bias[c2];
  o2.y = acc.y * inv + bias[c2 + 1];
  *(float2*)(out + (size_t)n * 128 + c2) = o2;
}

// ---------------- layer-3 (ch=1): one wave per node, edge-parallel lanes ----------------
__global__ void gat3_kernel(const float* __restrict__ xl, const float* __restrict__ xr,
                            const int4* __restrict__ recs, const int* __restrict__ row_ptr,
                            const float* __restrict__ We, const float* __restrict__ att,
                            const float* __restrict__ bias, float* __restrict__ out, int Nn) {
  int n = blockIdx.x * 4 + (threadIdx.x >> 6);
  int lane = threadIdx.x & 63;
  if (n >= Nn) return;
  float we0 = We[0], we1 = We[1], a = att[0];
  float xr_n = xr[n];
  int s0 = row_ptr[n], s1 = row_ptr[n + 1];
  float accp = 0.f, accs = 0.f;
  for (int i = s0 + lane; i < s1; i += 64) {
    int4 r = recs[i];
    float xls = xl[r.x];
    float z = xls + xr_n + __int_as_float(r.y) * we0 + __int_as_float(r.z) * we1;
    z = (z > 0.f) ? z : 0.2f * z;
    float p = __expf(z * a);
    accp += p * xls;
    accs += p;
  }
#pragma unroll
  for (int o = 32; o > 0; o >>= 1) {
    accp += __shfl_xor(accp, o);
    accs += __shfl_xor(accs, o);
  }
  int deg = s1 - s0;
  if (lane == 0) out[n] = accp / ((accs + 1e-16f) * (float)(deg > 0 ? deg : 1)) + bias[0];
}

// ---------------- row dot: out[n] = A[n,:K] . w ----------------
__global__ void rowdot_kernel(const float* __restrict__ A, const float* __restrict__ w,
                              float* __restrict__ out, int Nn, int K) {
  int n = blockIdx.x * 4 + (threadIdx.x >> 6);
  int lane = threadIdx.x & 63;
  if (n >= Nn) return;
  float p = 0.f;
  for (int k = lane; k < K; k += 64) p += A[(size_t)n * K + k] * w[k];
#pragma unroll
  for (int o = 32; o > 0; o >>= 1) p += __shfl_xor(p, o);
  if (lane == 0) out[n] = p;
}

extern "C" void kernel_launch(void* const* d_in, const int* in_sizes, int n_in,
                              void* d_out, int out_size, void* d_ws, size_t ws_size,
                              hipStream_t stream) {
  const float* x     = (const float*)d_in[0];
  const int*   ei    = (const int*)d_in[1];
  const float* ea    = (const float*)d_in[2];
  const float* bn0_g = (const float*)d_in[3];
  const float* bn0_b = (const float*)d_in[4];
  const float* Wl1   = (const float*)d_in[5];
  const float* Wr1   = (const float*)d_in[6];
  const float* We1   = (const float*)d_in[7];
  const float* att1  = (const float*)d_in[8];
  const float* b1    = (const float*)d_in[9];
  const float* bn1_g = (const float*)d_in[10];
  const float* bn1_b = (const float*)d_in[11];
  const float* Wl2   = (const float*)d_in[12];
  const float* Wr2   = (const float*)d_in[13];
  const float* We2   = (const float*)d_in[14];
  const float* att2  = (const float*)d_in[15];
  const float* b2    = (const float*)d_in[16];
  const float* bn2_g = (const float*)d_in[17];
  const float* bn2_b = (const float*)d_in[18];
  const float* Wl3   = (const float*)d_in[19];
  const float* Wr3   = (const float*)d_in[20];
  const float* We3   = (const float*)d_in[21];
  const float* att3  = (const float*)d_in[22];
  const float* b3    = (const float*)d_in[23];

  const int F = 301;
  const int Kp1 = 320;
  const int N = in_sizes[0] / F;
  const int E = in_sizes[1] / 2;
  const int* srcv = ei;
  const int* dstv = ei + E;

  // ---- workspace layout, regions time-shared ----
  float* fws = (float*)d_ws;
  float* RA = fws;                              // N*320 f
  float* RB = RA + (size_t)N * 320;             // N*384 f
  float* stats = RB + (size_t)N * 384;          // 1024
  u16* wt1h = (u16*)(stats + 1024);             // 512*320
  u16* wt1l = wt1h + (size_t)512 * 320;
  u16* wt2h = wt1l + (size_t)512 * 320;         // 256*256
  u16* wt2l = wt2h + (size_t)256 * 256;
  float* xl3 = (float*)(wt2l + (size_t)256 * 256);
  float* xr3 = xl3 + N;
  char* pi = (char*)(xr3 + N);
  pi += (16 - ((size_t)pi & 15)) & 15;          // 16B-align records
  int4* recs = (int4*)pi;                       // E records
  int* row_ptr = (int*)(recs + E);              // N+1
  int* fill    = row_ptr + (N + 1);             // N
  int* bsum    = fill + N;                      // nb (<=64)
  int* bexc    = bsum + 64;                     // nb+1

  // region aliases along the timeline
  u16* Ahi = (u16*)RA;                          // N x 320 bf16
  u16* Alo = Ahi + (size_t)N * Kp1;
  u16* xlr1 = (u16*)RB;                         // N x 512 fp16 (xl1 | xr1)
  float* g1out = RA;                            // N x 256 f (gat1 out)
  u16* h1h = (u16*)RB;                          // N x 256 bf16
  u16* h1l = h1h + (size_t)N * 256;
  u16* xlr2 = h1l + (size_t)N * 256;            // N x 256 fp16 (xl2 | xr2)
  float* g2out = RA;                            // N x 128 f
  float* h2 = RA + (size_t)N * 128;             // N x 128 f

  // ---- CSR by dst (parallel 3-phase scan), edge records ----
  int nb = cdiv(N, 1024);
  hipMemsetAsync(fill, 0, (size_t)N * sizeof(int), stream);
  count_kernel<<<cdiv(E, 256), 256, 0, stream>>>(dstv, fill, E);
  scan_blk_kernel<<<nb, 1024, 0, stream>>>(fill, row_ptr, bsum, N);
  scan_kernel<<<1, 1024, 0, stream>>>(bsum, bexc, nb);
  scan_add_kernel<<<cdiv(N, 256), 256, 0, stream>>>(row_ptr, bexc, N, nb);
  copyint_kernel<<<cdiv(N, 256), 256, 0, stream>>>(row_ptr, fill, N);
  scatter_rec_kernel<<<cdiv(E, 256), 256, 0, stream>>>(dstv, srcv, ea, fill, recs, E);

  // ---- weight prep ----
  wt_split_kernel<<<cdiv(512 * Kp1, 256), 256, 0, stream>>>(Wl1, Wr1, wt1h, wt1l, F, Kp1, 256);
  wt_split_kernel<<<cdiv(256 * 256, 256), 256, 0, stream>>>(Wl2, Wr2, wt2h, wt2l, 256, 256, 128);

  int rows = cdiv(N, GRID_BN);  // high-occupancy BN grids (was 256 blocks -> 13% occ, latency-bound)

  // ---- BN0 -> split bf16 A planes ----
  hipMemsetAsync(stats, 0, 1024 * sizeof(float), stream);
  col_stats_kernel<<<GRID_BN, 320, 0, stream>>>(x, stats, N, F, rows);
  bn_split_kernel<<<GRID_BN, 320, 0, stream>>>(x, Ahi, Alo, stats, bn0_g, bn0_b, N, F, Kp1, rows, 0);

  // ---- layer 1: fused [xl|xr] MFMA GEMM (fp16 out) + edge pass ----
  gemm_mfma<u16><<<dim3(cdiv(N, 128), 4), 256, 0, stream>>>(Ahi, Alo, wt1h, wt1l, xlr1, N, Kp1, 512);
  gat1_kernel<<<cdiv(N, 4), 256, 0, stream>>>(xlr1, xlr1 + 256, 512, recs, row_ptr,
                                              We1, att1, b1, g1out, N);
  // ---- BN1 + relu -> split bf16 h1 planes ----
  hipMemsetAsync(stats, 0, 1024 * sizeof(float), stream);
  col_stats_kernel<<<GRID_BN, 256, 0, stream>>>(g1out, stats, N, 256, rows);
  bn_split_kernel<<<GRID_BN, 256, 0, stream>>>(g1out, h1h, h1l, stats, bn1_g, bn1_b, N, 256, 256, rows, 1);

  // ---- layer 2: fused [xl|xr] MFMA GEMM (fp16 out) + edge pass ----
  gemm_mfma<u16><<<dim3(cdiv(N, 128), 2), 256, 0, stream>>>(h1h, h1l, wt2h, wt2l, xlr2, N, 256, 256);
  gat2_kernel<<<cdiv(N, 4), 256, 0, stream>>>(xlr2, xlr2 + 128, 256, recs, row_ptr,
                                              We2, att2, b2, g2out, N);
  // ---- BN2 + relu -> fp32 h2 ----
  hipMemsetAsync(stats, 0, 1024 * sizeof(float), stream);
  col_stats_kernel<<<GRID_BN, 128, 0, stream>>>(g2out, stats, N, 128, rows);
  bn_apply_kernel<<<GRID_BN, 128, 0, stream>>>(g2out, h2, stats, bn2_g, bn2_b, N, 128, 128, rows, 1);

  // ---- layer 3 (ch=1) ----
  rowdot_kernel<<<cdiv(N, 4), 256, 0, stream>>>(h2, Wl3, xl3, N, 128);
  rowdot_kernel<<<cdiv(N, 4), 256, 0, stream>>>(h2, Wr3, xr3, N, 128);
  gat3_kernel<<<cdiv(N, 4), 256, 0, stream>>>(xl3, xr3, recs, row_ptr,
                                              We3, att3, b3, (float*)d_out, N);
}

// Round 11
// 572.359 us; speedup vs baseline: 3.1939x; 1.0244x over previous
//
#include <hip/hip_runtime.h>
#include <hip/hip_fp16.h>

#define EPSF 1e-5f
#define GRID_BN 1024

typedef unsigned short u16;
typedef __attribute__((ext_vector_type(8))) short bf16x8s;  // 8 bf16 (4 VGPRs)
typedef __attribute__((ext_vector_type(4))) float f32x4;
typedef _Float16 f16x2v __attribute__((ext_vector_type(2)));

static inline int cdiv(int a, int b) { return (a + b - 1) / b; }

// split v into hi (bit-truncated bf16) + lo (round-nearest bf16 of remainder)
__device__ inline void bf_split(float v, u16& h, u16& l) {
  unsigned u = __float_as_uint(v);
  h = (u16)(u >> 16);
  float hf = __uint_as_float(u & 0xffff0000u);
  float r = v - hf;
  unsigned ur = __float_as_uint(r);
  ur += 0x7fffu + ((ur >> 16) & 1u);
  l = (u16)(ur >> 16);
}

__device__ inline float4 cvt_h4(uint2 r) {
  float2 a = __half22float2(*(__half2*)&r.x);
  float2 b = __half22float2(*(__half2*)&r.y);
  return make_float4(a.x, a.y, b.x, b.y);
}
__device__ inline float2 cvt_h2(unsigned r) { return __half22float2(*(__half2*)&r); }

// native packed-fp16 helpers (no __h*2 header intrinsics; clang emits v_pk_*)
__device__ inline f16x2v mk2(float x, float y) {
  f16x2v v; v[0] = (_Float16)x; v[1] = (_Float16)y; return v;
}
__device__ inline f16x2v splat2(float x) { return mk2(x, x); }
__device__ inline f16x2v bc2(unsigned r) { return __builtin_bit_cast(f16x2v, r); }

// fp16 pair dot with f32 accumulate (v_dot2_f32_f16); products exact in f32
__device__ inline float fdot2(f16x2v a, f16x2v b, float c) {
#if __has_builtin(__builtin_amdgcn_fdot2)
  return __builtin_amdgcn_fdot2(a, b, c, false);
#else
  return fmaf((float)a[0], (float)b[0], fmaf((float)a[1], (float)b[1], c));
#endif
}

__device__ inline void st_out(float* p, float v) { *p = v; }
__device__ inline void st_out(u16* p, float v) { *p = __half_as_ushort(__float2half(v)); }

// ---------------- column stats (sum, sumsq); X stride == F ----------------
__global__ void col_stats_kernel(const float* __restrict__ X, float* __restrict__ sums,
                                 int N, int F, int rowsPer) {
  int c = threadIdx.x;
  if (c >= F) return;
  int r0 = blockIdx.x * rowsPer;
  int r1 = min(N, r0 + rowsPer);
  float s = 0.f, sq = 0.f;
  for (int r = r0; r < r1; ++r) {
    float v = X[(size_t)r * F + c];
    s += v; sq += v * v;
  }
  atomicAdd(&sums[c], s);
  atomicAdd(&sums[512 + c], sq);
}

// ---------------- BN apply -> fp32 (BN2) ----------------
__global__ void bn_apply_kernel(const float* __restrict__ X, float* __restrict__ Y,
                                const float* __restrict__ sums,
                                const float* __restrict__ g, const float* __restrict__ b,
                                int N, int F, int outW, int rowsPer, int relu) {
  int c = threadIdx.x;
  if (c >= outW) return;
  float sc = 0.f, bb = 0.f;
  if (c < F) {
    float invN = 1.f / (float)N;
    float mu = sums[c] * invN;
    float var = sums[512 + c] * invN - mu * mu;
    sc = g[c] * rsqrtf(var + EPSF);
    bb = b[c] - mu * sc;
  }
  int r0 = blockIdx.x * rowsPer, r1 = min(N, r0 + rowsPer);
  for (int r = r0; r < r1; ++r) {
    float v = (c < F) ? X[(size_t)r * F + c] * sc + bb : 0.f;
    if (relu) v = fmaxf(v, 0.f);
    Y[(size_t)r * outW + c] = v;
  }
}

// ---------------- BN apply -> split bf16 hi/lo planes (BN0, BN1) ----------------
__global__ void bn_split_kernel(const float* __restrict__ X,
                                u16* __restrict__ Yhi, u16* __restrict__ Ylo,
                                const float* __restrict__ sums,
                                const float* __restrict__ g, const float* __restrict__ b,
                                int N, int F, int outW, int rowsPer, int relu) {
  int c = threadIdx.x;
  if (c >= outW) return;
  float sc = 0.f, bb = 0.f;
  if (c < F) {
    float invN = 1.f / (float)N;
    float mu = sums[c] * invN;
    float var = sums[512 + c] * invN - mu * mu;
    sc = g[c] * rsqrtf(var + EPSF);
    bb = b[c] - mu * sc;
  }
  int r0 = blockIdx.x * rowsPer, r1 = min(N, r0 + rowsPer);
  for (int r = r0; r < r1; ++r) {
    float v = (c < F) ? X[(size_t)r * F + c] * sc + bb : 0.f;
    if (relu) v = fmaxf(v, 0.f);
    u16 h, l;
    bf_split(v, h, l);
    Yhi[(size_t)r * outW + c] = h;
    Ylo[(size_t)r * outW + c] = l;
  }
}

// ---------------- weights: transpose + concat + pad + split -> [2M][Kp] bf16 hi/lo ----------------
__global__ void wt_split_kernel(const float* __restrict__ Wa, const float* __restrict__ Wb,
                                u16* __restrict__ Whi, u16* __restrict__ Wlo,
                                int K, int Kp, int M) {
  int idx = blockIdx.x * blockDim.x + threadIdx.x;
  if (idx >= 2 * M * Kp) return;
  int col = idx / Kp;
  int k = idx - col * Kp;
  float v = 0.f;
  if (k < K) v = (col < M) ? Wa[(size_t)k * M + col] : Wb[(size_t)k * M + (col - M)];
  u16 h, l;
  bf_split(v, h, l);
  Whi[idx] = h;
  Wlo[idx] = l;
}

// ---------------- split-bf16 MFMA GEMM: C(NxMout) = (Ahi+Alo)(Whi+Wlo)^T ----------------
template <typename OutT>
__global__ __launch_bounds__(256) void gemm_mfma(
    const u16* __restrict__ Ahi, const u16* __restrict__ Alo,
    const u16* __restrict__ Bhi, const u16* __restrict__ Blo,
    OutT* __restrict__ C, int N, int Kp, int ldc) {
  __shared__ u16 sAh[128 * 40], sAl[128 * 40], sBh[128 * 40], sBl[128 * 40];
  int tid = threadIdx.x;
  int brow = blockIdx.x * 128, bcol = blockIdx.y * 128;
  int stR = tid >> 1;
  int stC0 = (tid & 1) * 2;
  bool aok = (brow + stR) < N;
  const u16* pAh = Ahi + (size_t)(brow + stR) * Kp + stC0 * 8;
  const u16* pAl = Alo + (size_t)(brow + stR) * Kp + stC0 * 8;
  const u16* pBh = Bhi + (size_t)(bcol + stR) * Kp + stC0 * 8;
  const u16* pBl = Blo + (size_t)(bcol + stR) * Kp + stC0 * 8;
  const uint4 Z = make_uint4(0u, 0u, 0u, 0u);
  uint4 rah0 = aok ? *(const uint4*)(pAh) : Z;
  uint4 rah1 = aok ? *(const uint4*)(pAh + 8) : Z;
  uint4 ral0 = aok ? *(const uint4*)(pAl) : Z;
  uint4 ral1 = aok ? *(const uint4*)(pAl + 8) : Z;
  uint4 rbh0 = *(const uint4*)(pBh);
  uint4 rbh1 = *(const uint4*)(pBh + 8);
  uint4 rbl0 = *(const uint4*)(pBl);
  uint4 rbl1 = *(const uint4*)(pBl + 8);
  f32x4 acc[4][4] = {};
  int lane = tid & 63;
  int wv = tid >> 6, wr = wv >> 1, wc = wv & 1;
  int fr = lane & 15, kch = (lane >> 4) * 8;
  int ldsw = stR * 40 + stC0 * 8;
  for (int k0 = 0;;) {
    __syncthreads();
    *(uint4*)&sAh[ldsw] = rah0; *(uint4*)&sAh[ldsw + 8] = rah1;
    *(uint4*)&sAl[ldsw] = ral0; *(uint4*)&sAl[ldsw + 8] = ral1;
    *(uint4*)&sBh[ldsw] = rbh0; *(uint4*)&sBh[ldsw + 8] = rbh1;
    *(uint4*)&sBl[ldsw] = rbl0; *(uint4*)&sBl[ldsw + 8] = rbl1;
    __syncthreads();
    int kn = k0 + 32;
    if (kn < Kp) {  // prefetch next k-slab under the MFMA body
      rah0 = aok ? *(const uint4*)(pAh + kn) : Z;
      rah1 = aok ? *(const uint4*)(pAh + kn + 8) : Z;
      ral0 = aok ? *(const uint4*)(pAl + kn) : Z;
      ral1 = aok ? *(const uint4*)(pAl + kn + 8) : Z;
      rbh0 = *(const uint4*)(pBh + kn);
      rbh1 = *(const uint4*)(pBh + kn + 8);
      rbl0 = *(const uint4*)(pBl + kn);
      rbl1 = *(const uint4*)(pBl + kn + 8);
    }
    bf16x8s afh[4], afl[4], bfh[4], bfl[4];
#pragma unroll
    for (int i = 0; i < 4; ++i) {
      int ai = (wr * 64 + i * 16 + fr) * 40 + kch;
      afh[i] = *(const bf16x8s*)&sAh[ai];
      afl[i] = *(const bf16x8s*)&sAl[ai];
      int bi = (wc * 64 + i * 16 + fr) * 40 + kch;
      bfh[i] = *(const bf16x8s*)&sBh[bi];
      bfl[i] = *(const bf16x8s*)&sBl[bi];
    }
#pragma unroll
    for (int i = 0; i < 4; ++i)
#pragma unroll
      for (int j = 0; j < 4; ++j) {
        acc[i][j] = __builtin_amdgcn_mfma_f32_16x16x32_bf16(afh[i], bfh[j], acc[i][j], 0, 0, 0);
        acc[i][j] = __builtin_amdgcn_mfma_f32_16x16x32_bf16(afh[i], bfl[j], acc[i][j], 0, 0, 0);
        acc[i][j] = __builtin_amdgcn_mfma_f32_16x16x32_bf16(afl[i], bfh[j], acc[i][j], 0, 0, 0);
      }
    k0 = kn;
    if (k0 >= Kp) break;
  }
#pragma unroll
  for (int i = 0; i < 4; ++i) {
    int growb = brow + wr * 64 + i * 16 + (lane >> 4) * 4;
#pragma unroll
    for (int j = 0; j < 4; ++j) {
      int gcol = bcol + wc * 64 + j * 16 + fr;
#pragma unroll
      for (int r = 0; r < 4; ++r) {
        int grow = growb + r;
        if (grow < N) st_out(&C[(size_t)grow * ldc + gcol], acc[i][j][r]);
      }
    }
  }
}

// ---------------- CSR build ----------------
__global__ void count_kernel(const int* __restrict__ dst, int* __restrict__ cnt, int E) {
  int e = blockIdx.x * blockDim.x + threadIdx.x;
  if (e < E) atomicAdd(&cnt[dst[e]], 1);
}

__global__ void scan_blk_kernel(const int* __restrict__ cnt, int* __restrict__ row_ptr,
                                int* __restrict__ bsum, int N) {
  __shared__ int lds[1024];
  int tid = threadIdx.x;
  int i = blockIdx.x * 1024 + tid;
  int v = (i < N) ? cnt[i] : 0;
  lds[tid] = v;
  __syncthreads();
  for (int o = 1; o < 1024; o <<= 1) {
    int t = (tid >= o) ? lds[tid - o] : 0;
    __syncthreads();
    lds[tid] += t;
    __syncthreads();
  }
  if (i < N) row_ptr[i] = lds[tid] - v;
  if (tid == 1023) bsum[blockIdx.x] = lds[1023];
}

__global__ void scan_kernel(const int* __restrict__ cnt, int* __restrict__ row_ptr, int N) {
  __shared__ int lds[1024];
  __shared__ int carry;
  int tid = threadIdx.x;
  if (tid == 0) carry = 0;
  __syncthreads();
  for (int base = 0; base < N; base += 1024) {
    int i = base + tid;
    int v = (i < N) ? cnt[i] : 0;
    lds[tid] = v;
    __syncthreads();
    for (int o = 1; o < 1024; o <<= 1) {
      int t = (tid >= o) ? lds[tid - o] : 0;
      __syncthreads();
      lds[tid] += t;
      __syncthreads();
    }
    int incl = lds[tid];
    if (i < N) row_ptr[i] = carry + incl - v;
    __syncthreads();
    if (tid == 1023) carry += incl;
    __syncthreads();
  }
  if (tid == 0) row_ptr[N] = carry;
}

// adds chunk offsets AND writes the fill[] copy (replaces separate copyint pass)
__global__ void scan_add_kernel(int* __restrict__ row_ptr, int* __restrict__ fill,
                                const int* __restrict__ bexc, int N, int nb) {
  int i = blockIdx.x * blockDim.x + threadIdx.x;
  if (i < N) {
    int v = row_ptr[i] + bexc[i >> 10];
    row_ptr[i] = v;
    fill[i] = v;
  }
  if (i == 0) row_ptr[N] = bexc[nb];
}

// edge records in CSR order: {src, ea0_bits, ea1_bits, 0}
__global__ void scatter_rec_kernel(const int* __restrict__ dst, const int* __restrict__ src,
                                   const float* __restrict__ ea, int* __restrict__ fill,
                                   int4* __restrict__ recs, int E) {
  int e = blockIdx.x * blockDim.x + threadIdx.x;
  if (e < E) {
    int p = atomicAdd(&fill[dst[e]], 1);
    int4 r;
    r.x = src[e];
    r.y = __float_as_int(ea[2 * (size_t)e]);
    r.z = __float_as_int(ea[2 * (size_t)e + 1]);
    r.w = 0;
    recs[p] = r;
  }
}

// ---------------- GATv2 layer 1: H=2, D=256 (fp16 xlr), one WAVE per node ----------------
// Native packed-fp16 z path (v_pk_fma/v_pk_max) + v_dot2_f32_f16 dot; messages f32.
struct Edge1 { uint2 raw; f16x2v e0h, e1h; };

__global__ __launch_bounds__(256) void gat1_kernel(
    const u16* __restrict__ xl, const u16* __restrict__ xr, int ldx,
    const int4* __restrict__ recs, const int* __restrict__ row_ptr,
    const float* __restrict__ We, const float* __restrict__ att,
    const float* __restrict__ bias, float* __restrict__ out, int Nn) {
  int n = __builtin_amdgcn_readfirstlane(blockIdx.x * 4 + (threadIdx.x >> 6));
  if (n >= Nn) return;
  int lane = threadIdx.x & 63;
  int c4 = lane * 4;
  const float4 we0f = *(const float4*)(We + c4);
  const float4 we1f = *(const float4*)(We + 256 + c4);
  const float4 atf = *(const float4*)(att + c4);
  const f16x2v we0a = mk2(we0f.x, we0f.y), we0b = mk2(we0f.z, we0f.w);
  const f16x2v we1a = mk2(we1f.x, we1f.y), we1b = mk2(we1f.z, we1f.w);
  const f16x2v atta = mk2(atf.x, atf.y), attb = mk2(atf.z, atf.w);
  const f16x2v k02 = splat2(0.2f);
  uint2 xrr = *(const uint2*)(xr + (size_t)n * ldx + c4);
  const f16x2v xra = bc2(xrr.x), xrb = bc2(xrr.y);
  int start = row_ptr[n];
  int deg = row_ptr[n + 1] - start;
  float4 acc = {0.f, 0.f, 0.f, 0.f};
  float sacc = 0.f;

  auto lde = [&](int i) {
    int4 r = recs[start + i];
    Edge1 t;
    int sv = __builtin_amdgcn_readfirstlane(r.x);
    t.e0h = splat2(__int_as_float(r.y));
    t.e1h = splat2(__int_as_float(r.z));
    t.raw = *(const uint2*)(xl + (size_t)sv * ldx + c4);
    return t;
  };
  auto zpart = [&](const Edge1& t) {
    f16x2v ra = bc2(t.raw.x), rb = bc2(t.raw.y);
    f16x2v za = t.e1h * we1a + (t.e0h * we0a + (ra + xra));
    f16x2v zb = t.e1h * we1b + (t.e0h * we0b + (rb + xrb));
    za = __builtin_elementwise_max(za, za * k02);   // leaky for both signs
    zb = __builtin_elementwise_max(zb, zb * k02);
    return fdot2(zb, attb, fdot2(za, atta, 0.f));
  };
  auto accum = [&](const Edge1& t, float p) {
    float4 xc = cvt_h4(t.raw);
    acc.x += p * xc.x;
    acc.y += p * xc.y;
    acc.z += p * xc.z;
    acc.w += p * xc.w;
    sacc += p;
  };

  int full = deg & ~3;
  if (full >= 4) {
    Edge1 A = lde(0), B = lde(1), C = lde(2), D = lde(3);
    int j = 0;
    while (j + 8 <= full) {
      Edge1 nA = lde(j + 4), nB = lde(j + 5), nC = lde(j + 6), nD = lde(j + 7);
      float p0 = zpart(A), p1 = zpart(B), p2 = zpart(C), p3 = zpart(D);
#pragma unroll
      for (int o = 16; o > 0; o >>= 1) {
        p0 += __shfl_xor(p0, o, 32);
        p1 += __shfl_xor(p1, o, 32);
        p2 += __shfl_xor(p2, o, 32);
        p3 += __shfl_xor(p3, o, 32);
      }
      p0 = __expf(p0); p1 = __expf(p1); p2 = __expf(p2); p3 = __expf(p3);
      accum(A, p0); accum(B, p1); accum(C, p2); accum(D, p3);
      A = nA; B = nB; C = nC; D = nD;
      j += 4;
    }
    float p0 = zpart(A), p1 = zpart(B), p2 = zpart(C), p3 = zpart(D);
#pragma unroll
    for (int o = 16; o > 0; o >>= 1) {
      p0 += __shfl_xor(p0, o, 32);
      p1 += __shfl_xor(p1, o, 32);
      p2 += __shfl_xor(p2, o, 32);
      p3 += __shfl_xor(p3, o, 32);
    }
    p0 = __expf(p0); p1 = __expf(p1); p2 = __expf(p2); p3 = __expf(p3);
    accum(A, p0); accum(B, p1); accum(C, p2); accum(D, p3);
  }
  for (int t = full; t < deg; ++t) {
    Edge1 T = lde(t);
    float p = zpart(T);
#pragma unroll
    for (int o = 16; o > 0; o >>= 1) p += __shfl_xor(p, o, 32);
    accum(T, __expf(p));
  }

  float inv = 1.f / ((sacc + 1e-16f) * (float)(deg > 0 ? deg : 1));
  float4 o4;
  o4.x = acc.x * inv + bias[c4];
  o4.y = acc.y * inv + bias[c4 + 1];
  o4.z = acc.z * inv + bias[c4 + 2];
  o4.w = acc.w * inv + bias[c4 + 3];
  *(float4*)(out + (size_t)n * 256 + c4) = o4;
}

// ---------------- GATv2 layer 2: H=1, D=128 (fp16 xlr), one WAVE per node ----------------
struct Edge2 { unsigned raw; f16x2v e0h, e1h; };

__global__ __launch_bounds__(256) void gat2_kernel(
    const u16* __restrict__ xl, const u16* __restrict__ xr, int ldx,
    const int4* __restrict__ recs, const int* __restrict__ row_ptr,
    const float* __restrict__ We, const float* __restrict__ att,
    const float* __restrict__ bias, float* __restrict__ out, int Nn) {
  int n = __builtin_amdgcn_readfirstlane(blockIdx.x * 4 + (threadIdx.x >> 6));
  if (n >= Nn) return;
  int lane = threadIdx.x & 63;
  int c2 = lane * 2;
  const float2 we0f = *(const float2*)(We + c2);
  const float2 we1f = *(const float2*)(We + 128 + c2);
  const float2 atf = *(const float2*)(att + c2);
  const f16x2v we0a = mk2(we0f.x, we0f.y);
  const f16x2v we1a = mk2(we1f.x, we1f.y);
  const f16x2v atta = mk2(atf.x, atf.y);
  const f16x2v k02 = splat2(0.2f);
  unsigned xrr = *(const unsigned*)(xr + (size_t)n * ldx + c2);
  const f16x2v xra = bc2(xrr);
  int start = row_ptr[n];
  int deg = row_ptr[n + 1] - start;
  float2 acc = {0.f, 0.f};
  float sacc = 0.f;

  auto lde = [&](int i) {
    int4 r = recs[start + i];
    Edge2 t;
    int sv = __builtin_amdgcn_readfirstlane(r.x);
    t.e0h = splat2(__int_as_float(r.y));
    t.e1h = splat2(__int_as_float(r.z));
    t.raw = *(const unsigned*)(xl + (size_t)sv * ldx + c2);
    return t;
  };
  auto zpart = [&](const Edge2& t) {
    f16x2v ra = bc2(t.raw);
    f16x2v za = t.e1h * we1a + (t.e0h * we0a + (ra + xra));
    za = __builtin_elementwise_max(za, za * k02);
    return fdot2(za, atta, 0.f);
  };
  auto accum = [&](const Edge2& t, float p) {
    float2 xc = cvt_h2(t.raw);
    acc.x += p * xc.x;
    acc.y += p * xc.y;
    sacc += p;
  };

  int full = deg & ~3;
  if (full >= 4) {
    Edge2 A = lde(0), B = lde(1), C = lde(2), D = lde(3);
    int j = 0;
    while (j + 8 <= full) {
      Edge2 nA = lde(j + 4), nB = lde(j + 5), nC = lde(j + 6), nD = lde(j + 7);
      float p0 = zpart(A), p1 = zpart(B), p2 = zpart(C), p3 = zpart(D);
#pragma unroll
      for (int o = 32; o > 0; o >>= 1) {
        p0 += __shfl_xor(p0, o);
        p1 += __shfl_xor(p1, o);
        p2 += __shfl_xor(p2, o);
        p3 += __shfl_xor(p3, o);
      }
      p0 = __expf(p0); p1 = __expf(p1); p2 = __expf(p2); p3 = __expf(p3);
      accum(A, p0); accum(B, p1); accum(C, p2); accum(D, p3);
      A = nA; B = nB; C = nC; D = nD;
      j += 4;
    }
    float p0 = zpart(A), p1 = zpart(B), p2 = zpart(C), p3 = zpart(D);
#pragma unroll
    for (int o = 32; o > 0; o >>= 1) {
      p0 += __shfl_xor(p0, o);
      p1 += __shfl_xor(p1, o);
      p2 += __shfl_xor(p2, o);
      p3 += __shfl_xor(p3, o);
    }
    p0 = __expf(p0); p1 = __expf(p1); p2 = __expf(p2); p3 = __expf(p3);
    accum(A, p0); accum(B, p1); accum(C, p2); accum(D, p3);
  }
  for (int t = full; t < deg; ++t) {
    Edge2 T = lde(t);
    float p = zpart(T);
#pragma unroll
    for (int o = 32; o > 0; o >>= 1) p += __shfl_xor(p, o);
    accum(T, __expf(p));
  }

  float inv = 1.f / ((sacc + 1e-16f) * (float)(deg > 0 ? deg : 1));
  float2 o2;
  o2.x = acc.x * inv + bias[c2];
  o2.y = acc.y * inv + bias[c2 + 1];
  *(float2*)(out + (size_t)n * 128 + c2) = o2;
}

// ---------------- layer-3 (ch=1): one wave per node, edge-parallel lanes ----------------
__global__ void gat3_kernel(const float* __restrict__ xl, const float* __restrict__ xr,
                            const int4* __restrict__ recs, const int* __restrict__ row_ptr,
                            const float* __restrict__ We, const float* __restrict__ att,
                            const float* __restrict__ bias, float* __restrict__ out, int Nn) {
  int n = blockIdx.x * 4 + (threadIdx.x >> 6);
  int lane = threadIdx.x & 63;
  if (n >= Nn) return;
  float we0 = We[0], we1 = We[1], a = att[0];
  float xr_n = xr[n];
  int s0 = row_ptr[n], s1 = row_ptr[n + 1];
  float accp = 0.f, accs = 0.f;
  for (int i = s0 + lane; i < s1; i += 64) {
    int4 r = recs[i];
    float xls = xl[r.x];
    float z = xls + xr_n + __int_as_float(r.y) * we0 + __int_as_float(r.z) * we1;
    z = (z > 0.f) ? z : 0.2f * z;
    float p = __expf(z * a);
    accp += p * xls;
    accs += p;
  }
#pragma unroll
  for (int o = 32; o > 0; o >>= 1) {
    accp += __shfl_xor(accp, o);
    accs += __shfl_xor(accs, o);
  }
  int deg = s1 - s0;
  if (lane == 0) out[n] = accp / ((accs + 1e-16f) * (float)(deg > 0 ? deg : 1)) + bias[0];
}

// ---------------- dual row dot: o1[n]=A[n,:].w1, o2[n]=A[n,:].w2 (one A pass) ----------------
__global__ void rowdot2_kernel(const float* __restrict__ A,
                               const float* __restrict__ w1, const float* __restrict__ w2,
                               float* __restrict__ o1, float* __restrict__ o2, int Nn, int K) {
  int n = blockIdx.x * 4 + (threadIdx.x >> 6);
  int lane = threadIdx.x & 63;
  if (n >= Nn) return;
  float p = 0.f, q = 0.f;
  for (int k = lane; k < K; k += 64) {
    float a = A[(size_t)n * K + k];
    p += a * w1[k];
    q += a * w2[k];
  }
#pragma unroll
  for (int o = 32; o > 0; o >>= 1) {
    p += __shfl_xor(p, o);
    q += __shfl_xor(q, o);
  }
  if (lane == 0) { o1[n] = p; o2[n] = q; }
}

extern "C" void kernel_launch(void* const* d_in, const int* in_sizes, int n_in,
                              void* d_out, int out_size, void* d_ws, size_t ws_size,
                              hipStream_t stream) {
  const float* x     = (const float*)d_in[0];
  const int*   ei    = (const int*)d_in[1];
  const float* ea    = (const float*)d_in[2];
  const float* bn0_g = (const float*)d_in[3];
  const float* bn0_b = (const float*)d_in[4];
  const float* Wl1   = (const float*)d_in[5];
  const float* Wr1   = (const float*)d_in[6];
  const float* We1   = (const float*)d_in[7];
  const float* att1  = (const float*)d_in[8];
  const float* b1    = (const float*)d_in[9];
  const float* bn1_g = (const float*)d_in[10];
  const float* bn1_b = (const float*)d_in[11];
  const float* Wl2   = (const float*)d_in[12];
  const float* Wr2   = (const float*)d_in[13];
  const float* We2   = (const float*)d_in[14];
  const float* att2  = (const float*)d_in[15];
  const float* b2    = (const float*)d_in[16];
  const float* bn2_g = (const float*)d_in[17];
  const float* bn2_b = (const float*)d_in[18];
  const float* Wl3   = (const float*)d_in[19];
  const float* Wr3   = (const float*)d_in[20];
  const float* We3   = (const float*)d_in[21];
  const float* att3  = (const float*)d_in[22];
  const float* b3    = (const float*)d_in[23];

  const int F = 301;
  const int Kp1 = 320;
  const int N = in_sizes[0] / F;
  const int E = in_sizes[1] / 2;
  const int* srcv = ei;
  const int* dstv = ei + E;

  // ---- workspace layout, regions time-shared ----
  float* fws = (float*)d_ws;
  float* RA = fws;                              // N*320 f
  float* RB = RA + (size_t)N * 320;             // N*384 f
  float* stats = RB + (size_t)N * 384;          // 1024
  u16* wt1h = (u16*)(stats + 1024);             // 512*320
  u16* wt1l = wt1h + (size_t)512 * 320;
  u16* wt2h = wt1l + (size_t)512 * 320;         // 256*256
  u16* wt2l = wt2h + (size_t)256 * 256;
  float* xl3 = (float*)(wt2l + (size_t)256 * 256);
  float* xr3 = xl3 + N;
  char* pi = (char*)(xr3 + N);
  pi += (16 - ((size_t)pi & 15)) & 15;          // 16B-align records
  int4* recs = (int4*)pi;                       // E records
  int* row_ptr = (int*)(recs + E);              // N+1
  int* fill    = row_ptr + (N + 1);             // N
  int* bsum    = fill + N;                      // nb (<=64)
  int* bexc    = bsum + 64;                     // nb+1

  // region aliases along the timeline
  u16* Ahi = (u16*)RA;                          // N x 320 bf16
  u16* Alo = Ahi + (size_t)N * Kp1;
  u16* xlr1 = (u16*)RB;                         // N x 512 fp16 (xl1 | xr1)
  float* g1out = RA;                            // N x 256 f (gat1 out)
  u16* h1h = (u16*)RB;                          // N x 256 bf16
  u16* h1l = h1h + (size_t)N * 256;
  u16* xlr2 = h1l + (size_t)N * 256;            // N x 256 fp16 (xl2 | xr2)
  float* g2out = RA;                            // N x 128 f
  float* h2 = RA + (size_t)N * 128;             // N x 128 f

  // ---- CSR by dst (parallel 3-phase scan), edge records ----
  int nb = cdiv(N, 1024);
  hipMemsetAsync(fill, 0, (size_t)N * sizeof(int), stream);
  count_kernel<<<cdiv(E, 256), 256, 0, stream>>>(dstv, fill, E);
  scan_blk_kernel<<<nb, 1024, 0, stream>>>(fill, row_ptr, bsum, N);
  scan_kernel<<<1, 1024, 0, stream>>>(bsum, bexc, nb);
  scan_add_kernel<<<cdiv(N, 256), 256, 0, stream>>>(row_ptr, fill, bexc, N, nb);
  scatter_rec_kernel<<<cdiv(E, 256), 256, 0, stream>>>(dstv, srcv, ea, fill, recs, E);

  // ---- weight prep ----
  wt_split_kernel<<<cdiv(512 * Kp1, 256), 256, 0, stream>>>(Wl1, Wr1, wt1h, wt1l, F, Kp1, 256);
  wt_split_kernel<<<cdiv(256 * 256, 256), 256, 0, stream>>>(Wl2, Wr2, wt2h, wt2l, 256, 256, 128);

  int rows = cdiv(N, GRID_BN);  // high-occupancy BN grids

  // ---- BN0 -> split bf16 A planes ----
  hipMemsetAsync(stats, 0, 1024 * sizeof(float), stream);
  col_stats_kernel<<<GRID_BN, 320, 0, stream>>>(x, stats, N, F, rows);
  bn_split_kernel<<<GRID_BN, 320, 0, stream>>>(x, Ahi, Alo, stats, bn0_g, bn0_b, N, F, Kp1, rows, 0);

  // ---- layer 1: fused [xl|xr] MFMA GEMM (fp16 out) + edge pass ----
  gemm_mfma<u16><<<dim3(cdiv(N, 128), 4), 256, 0, stream>>>(Ahi, Alo, wt1h, wt1l, xlr1, N, Kp1, 512);
  gat1_kernel<<<cdiv(N, 4), 256, 0, stream>>>(xlr1, xlr1 + 256, 512, recs, row_ptr,
                                              We1, att1, b1, g1out, N);
  // ---- BN1 + relu -> split bf16 h1 planes ----
  hipMemsetAsync(stats, 0, 1024 * sizeof(float), stream);
  col_stats_kernel<<<GRID_BN, 256, 0, stream>>>(g1out, stats, N, 256, rows);
  bn_split_kernel<<<GRID_BN, 256, 0, stream>>>(g1out, h1h, h1l, stats, bn1_g, bn1_b, N, 256, 256, rows, 1);

  // ---- layer 2: fused [xl|xr] MFMA GEMM (fp16 out) + edge pass ----
  gemm_mfma<u16><<<dim3(cdiv(N, 128), 2), 256, 0, stream>>>(h1h, h1l, wt2h, wt2l, xlr2, N, 256, 256);
  gat2_kernel<<<cdiv(N, 4), 256, 0, stream>>>(xlr2, xlr2 + 128, 256, recs, row_ptr,
                                              We2, att2, b2, g2out, N);
  // ---- BN2 + relu -> fp32 h2 ----
  hipMemsetAsync(stats, 0, 1024 * sizeof(float), stream);
  col_stats_kernel<<<GRID_BN, 128, 0, stream>>>(g2out, stats, N, 128, rows);
  bn_apply_kernel<<<GRID_BN, 128, 0, stream>>>(g2out, h2, stats, bn2_g, bn2_b, N, 128, 128, rows, 1);

  // ---- layer 3 (ch=1) ----
  rowdot2_kernel<<<cdiv(N, 4), 256, 0, stream>>>(h2, Wl3, Wr3, xl3, xr3, N, 128);
  gat3_kernel<<<cdiv(N, 4), 256, 0, stream>>>(xl3, xr3, recs, row_ptr,
                                              We3, att3, b3, (float*)d_out, N);
}